// Round 1
// baseline (799.691 us; speedup 1.0000x reference)
//
#include <hip/hip_runtime.h>
#include <math.h>

#define SEQ 1024
#define NTOK 4096
#define DM 512
#define FF 2048
#define NE 8

__device__ __forceinline__ void fma44(const float4& a, const float4& b, float (&acc)[4][4]) {
  acc[0][0] += a.x*b.x; acc[0][1] += a.x*b.y; acc[0][2] += a.x*b.z; acc[0][3] += a.x*b.w;
  acc[1][0] += a.y*b.x; acc[1][1] += a.y*b.y; acc[1][2] += a.y*b.z; acc[1][3] += a.y*b.w;
  acc[2][0] += a.z*b.x; acc[2][1] += a.z*b.y; acc[2][2] += a.z*b.z; acc[2][3] += a.z*b.w;
  acc[3][0] += a.w*b.x; acc[3][1] += a.w*b.y; acc[3][2] += a.w*b.z; acc[3][3] += a.w*b.w;
}

// C[M,N] = A[M,K] @ B[N,K]^T + bias[N] (+ resid[M,N])
__global__ __launch_bounds__(256) void gemm_bt(const float* __restrict__ A, const float* __restrict__ B,
    const float* __restrict__ bias, const float* __restrict__ resid, float* __restrict__ C,
    int M, int N, int K) {
  __shared__ __align__(16) float As[16][68];
  __shared__ __align__(16) float Bs[16][68];
  const int tid = threadIdx.x;
  const int tx4 = (tid & 15) * 4, ty4 = (tid >> 4) * 4;
  const int n0 = blockIdx.x * 64, m0 = blockIdx.y * 64;
  const int lr = tid >> 2, lk4 = (tid & 3) * 4;
  float acc[4][4] = {};
  for (int kt = 0; kt < K; kt += 16) {
    float4 av = *reinterpret_cast<const float4*>(A + (size_t)(m0 + lr) * K + kt + lk4);
    float4 bv = *reinterpret_cast<const float4*>(B + (size_t)(n0 + lr) * K + kt + lk4);
    As[lk4+0][lr] = av.x; As[lk4+1][lr] = av.y; As[lk4+2][lr] = av.z; As[lk4+3][lr] = av.w;
    Bs[lk4+0][lr] = bv.x; Bs[lk4+1][lr] = bv.y; Bs[lk4+2][lr] = bv.z; Bs[lk4+3][lr] = bv.w;
    __syncthreads();
#pragma unroll
    for (int kk = 0; kk < 16; ++kk) {
      float4 a = *reinterpret_cast<const float4*>(&As[kk][ty4]);
      float4 b = *reinterpret_cast<const float4*>(&Bs[kk][tx4]);
      fma44(a, b, acc);
    }
    __syncthreads();
  }
  float4 bsv = *reinterpret_cast<const float4*>(bias + n0 + tx4);
#pragma unroll
  for (int i = 0; i < 4; ++i) {
    int row = m0 + ty4 + i;
    float4 v = make_float4(acc[i][0] + bsv.x, acc[i][1] + bsv.y, acc[i][2] + bsv.z, acc[i][3] + bsv.w);
    if (resid) {
      float4 r = *reinterpret_cast<const float4*>(resid + (size_t)row * N + n0 + tx4);
      v.x += r.x; v.y += r.y; v.z += r.z; v.w += r.w;
    }
    *reinterpret_cast<float4*>(C + (size_t)row * N + n0 + tx4) = v;
  }
}

// Flash-style fp32 attention. One block per (q-tile 64, head, batch).
__global__ __launch_bounds__(256) void attn_kernel(const float* __restrict__ qkv, float* __restrict__ o) {
  const int qt = blockIdx.x, hh = blockIdx.y, b = blockIdx.z;
  const int tid = threadIdx.x;
  const int tx4 = (tid & 15) * 4, ty4 = (tid >> 4) * 4;
  __shared__ __align__(16) float Qs[64][68];   // [d][r]
  __shared__ __align__(16) float KPs[64][68];  // K as [d][c], then P as [r][c]
  __shared__ __align__(16) float Vs[64][68];   // [c][d]
  const int ld = tid & 63, lw = tid >> 6;
  const size_t bb = (size_t)b * SEQ * 1536;
  const int hoff = hh * 64;
#pragma unroll
  for (int rr = 0; rr < 16; ++rr) {
    int r = rr * 4 + lw;
    Qs[ld][r] = qkv[bb + (size_t)(qt * 64 + r) * 1536 + hoff + ld];
  }
  float oacc[4][4] = {};
  float m_run[4], l_run[4];
#pragma unroll
  for (int i = 0; i < 4; ++i) { m_run[i] = -1e30f; l_run[i] = 0.f; }
  for (int kc = 0; kc < 16; ++kc) {
#pragma unroll
    for (int rr = 0; rr < 16; ++rr) {
      int c = rr * 4 + lw;
      size_t rowb = bb + (size_t)(kc * 64 + c) * 1536;
      KPs[ld][c] = qkv[rowb + 512 + hoff + ld];
      Vs[c][ld]  = qkv[rowb + 1024 + hoff + ld];
    }
    __syncthreads();
    float s[4][4] = {};
#pragma unroll 8
    for (int d = 0; d < 64; ++d) {
      float4 a  = *reinterpret_cast<const float4*>(&Qs[d][ty4]);
      float4 kv = *reinterpret_cast<const float4*>(&KPs[d][tx4]);
      fma44(a, kv, s);
    }
    __syncthreads();  // all done reading KPs before P overwrite
#pragma unroll
    for (int i = 0; i < 4; ++i) {
#pragma unroll
      for (int j = 0; j < 4; ++j) s[i][j] *= 0.125f;
      float mc = fmaxf(fmaxf(s[i][0], s[i][1]), fmaxf(s[i][2], s[i][3]));
#pragma unroll
      for (int msk = 1; msk < 16; msk <<= 1) mc = fmaxf(mc, __shfl_xor(mc, msk, 64));
      float mn = fmaxf(m_run[i], mc);
      float alpha = expf(m_run[i] - mn);
      float pl = 0.f;
#pragma unroll
      for (int j = 0; j < 4; ++j) { float p = expf(s[i][j] - mn); s[i][j] = p; pl += p; }
#pragma unroll
      for (int msk = 1; msk < 16; msk <<= 1) pl += __shfl_xor(pl, msk, 64);
      l_run[i] = l_run[i] * alpha + pl;
      m_run[i] = mn;
#pragma unroll
      for (int j = 0; j < 4; ++j) oacc[i][j] *= alpha;
    }
#pragma unroll
    for (int i = 0; i < 4; ++i)
      *reinterpret_cast<float4*>(&KPs[ty4 + i][tx4]) = make_float4(s[i][0], s[i][1], s[i][2], s[i][3]);
    __syncthreads();
#pragma unroll 8
    for (int kcol = 0; kcol < 64; ++kcol) {
      float4 vv = *reinterpret_cast<const float4*>(&Vs[kcol][tx4]);
      float a0 = KPs[ty4+0][kcol], a1 = KPs[ty4+1][kcol], a2 = KPs[ty4+2][kcol], a3 = KPs[ty4+3][kcol];
      oacc[0][0] += a0*vv.x; oacc[0][1] += a0*vv.y; oacc[0][2] += a0*vv.z; oacc[0][3] += a0*vv.w;
      oacc[1][0] += a1*vv.x; oacc[1][1] += a1*vv.y; oacc[1][2] += a1*vv.z; oacc[1][3] += a1*vv.w;
      oacc[2][0] += a2*vv.x; oacc[2][1] += a2*vv.y; oacc[2][2] += a2*vv.z; oacc[2][3] += a2*vv.w;
      oacc[3][0] += a3*vv.x; oacc[3][1] += a3*vv.y; oacc[3][2] += a3*vv.z; oacc[3][3] += a3*vv.w;
    }
    __syncthreads();
  }
#pragma unroll
  for (int i = 0; i < 4; ++i) {
    float inv = 1.f / l_run[i];
    size_t orow = ((size_t)b * SEQ + qt * 64 + ty4 + i) * DM + hoff + tx4;
    *reinterpret_cast<float4*>(o + orow) = make_float4(oacc[i][0]*inv, oacc[i][1]*inv, oacc[i][2]*inv, oacc[i][3]*inv);
  }
}

// LayerNorm over D=512; optional elementwise add (second residual). One wave per token.
__global__ __launch_bounds__(64) void ln_kernel(const float* __restrict__ x, const float* __restrict__ add,
    const float* __restrict__ g, const float* __restrict__ bta, float* __restrict__ y) {
  const int t = blockIdx.x, tid = threadIdx.x;
  const size_t base = (size_t)t * DM + tid * 8;
  float4 v0 = *reinterpret_cast<const float4*>(x + base);
  float4 v1 = *reinterpret_cast<const float4*>(x + base + 4);
  if (add) {
    float4 a0 = *reinterpret_cast<const float4*>(add + base);
    float4 a1 = *reinterpret_cast<const float4*>(add + base + 4);
    v0.x += a0.x; v0.y += a0.y; v0.z += a0.z; v0.w += a0.w;
    v1.x += a1.x; v1.y += a1.y; v1.z += a1.z; v1.w += a1.w;
  }
  float s = v0.x+v0.y+v0.z+v0.w + v1.x+v1.y+v1.z+v1.w;
  float q = v0.x*v0.x+v0.y*v0.y+v0.z*v0.z+v0.w*v0.w + v1.x*v1.x+v1.y*v1.y+v1.z*v1.z+v1.w*v1.w;
#pragma unroll
  for (int m = 1; m < 64; m <<= 1) { s += __shfl_xor(s, m, 64); q += __shfl_xor(q, m, 64); }
  float mean = s * (1.0f/512.0f);
  float var = q * (1.0f/512.0f) - mean * mean;
  float rs = rsqrtf(var + 1e-5f);
  float4 g0 = *reinterpret_cast<const float4*>(g + tid*8);
  float4 g1 = *reinterpret_cast<const float4*>(g + tid*8 + 4);
  float4 b0 = *reinterpret_cast<const float4*>(bta + tid*8);
  float4 b1 = *reinterpret_cast<const float4*>(bta + tid*8 + 4);
  float4 o0 = make_float4((v0.x-mean)*rs*g0.x+b0.x, (v0.y-mean)*rs*g0.y+b0.y,
                          (v0.z-mean)*rs*g0.z+b0.z, (v0.w-mean)*rs*g0.w+b0.w);
  float4 o1 = make_float4((v1.x-mean)*rs*g1.x+b1.x, (v1.y-mean)*rs*g1.y+b1.y,
                          (v1.z-mean)*rs*g1.z+b1.z, (v1.w-mean)*rs*g1.w+b1.w);
  *reinterpret_cast<float4*>(y + base) = o0;
  *reinterpret_cast<float4*>(y + base + 4) = o1;
}

// router logits: one thread per (token, expert)
__global__ __launch_bounds__(256) void router_kernel(const float* __restrict__ h, const float* __restrict__ rw,
    float* __restrict__ rlog) {
  int gidx = blockIdx.x * 256 + threadIdx.x;
  int t = gidx >> 3, e = gidx & 7;
  const float* hr = h + (size_t)t * DM;
  float acc = 0.f;
#pragma unroll 8
  for (int d = 0; d < DM; ++d) acc += hr[d] * rw[d * NE + e];
  rlog[gidx] = acc;
}

// softmax over E=8 + first-max argmax, one thread per token
__global__ __launch_bounds__(256) void smax_kernel(const float* __restrict__ rlog, float* __restrict__ probs,
    int* __restrict__ am) {
  int t = blockIdx.x * 256 + threadIdx.x;
  float v[8];
#pragma unroll
  for (int e = 0; e < 8; ++e) v[e] = rlog[t * 8 + e];
  int best = 0; float bv = v[0];
#pragma unroll
  for (int e = 1; e < 8; ++e) if (v[e] > bv) { bv = v[e]; best = e; }
  float ex[8]; float s = 0.f;
#pragma unroll
  for (int e = 0; e < 8; ++e) { ex[e] = expf(v[e] - bv); s += ex[e]; }
  float inv = 1.f / s;
#pragma unroll
  for (int e = 0; e < 8; ++e) probs[t * 8 + e] = ex[e] * inv;
  am[t] = best;
}

// per-(batch,expert) inclusive prefix scan of argmax flags -> queue position, expert_mask, kept count
__global__ __launch_bounds__(256) void scan_kernel(const int* __restrict__ am, const float* __restrict__ probs,
    const int* __restrict__ capp, float* __restrict__ emask, int* __restrict__ pos, int* __restrict__ cnt) {
  const int bx = blockIdx.x;
  const int b = bx >> 3, e = bx & 7;
  const int tid = threadIdx.x;
  const int cap = *capp;
  __shared__ int arr[256];
  const int s_base = tid * 4;
  int f[4], incl[4];
  int c = 0;
#pragma unroll
  for (int i = 0; i < 4; ++i) {
    f[i] = (am[b * SEQ + s_base + i] == e) ? 1 : 0;
    c += f[i]; incl[i] = c;
  }
  arr[tid] = c;
  __syncthreads();
  for (int off = 1; off < 256; off <<= 1) {
    int v = (tid >= off) ? arr[tid - off] : 0;
    __syncthreads();
    arr[tid] += v;
    __syncthreads();
  }
  int excl = arr[tid] - c;
  int tot = arr[255];
#pragma unroll
  for (int i = 0; i < 4; ++i) {
    int token = b * SEQ + s_base + i;
    int p = excl + incl[i];
    bool kept = f[i] && (p <= cap);
    emask[(size_t)token * NE + e] = kept ? probs[token * NE + e] : 0.f;
    if (f[i]) pos[token] = p;
  }
  if (tid == 0) cnt[bx] = (tot < cap) ? tot : cap;
}

__global__ __launch_bounds__(64) void offsets_kernel(const int* __restrict__ cnt, int* __restrict__ offbe,
    int* __restrict__ total) {
  int e = threadIdx.x;
  if (e < NE) {
    int run = 0;
    for (int b = 0; b < 4; ++b) { offbe[b * NE + e] = run; run += cnt[b * NE + e]; }
    total[e] = run;
  }
}

// gather kept tokens' h rows into per-expert contiguous buffers
__global__ __launch_bounds__(128) void gather_kernel(const float* __restrict__ h, const int* __restrict__ am,
    const int* __restrict__ pos, const int* __restrict__ capp, const int* __restrict__ offbe,
    const float* __restrict__ probs, float* __restrict__ G, int* __restrict__ tok, float* __restrict__ mscale) {
  const int t = blockIdx.x;
  const int b = t >> 10;
  const int e = am[t];
  const int p = pos[t];
  if (p > *capp) return;
  const int slot = offbe[b * NE + e] + p - 1;
  const int idx = e * 1024 + slot;
  if (threadIdx.x == 0) { tok[idx] = t; mscale[idx] = probs[t * NE + e]; }
  float4 v = *reinterpret_cast<const float4*>(h + (size_t)t * DM + threadIdx.x * 4);
  *reinterpret_cast<float4*>(G + (size_t)idx * DM + threadIdx.x * 4) = v;
}

// mid = gelu(G[e] @ wi[e]) ; A[M=1024,K=512] @ B[K=512,N=2048]
__global__ __launch_bounds__(256) void ffn1_kernel(const float* __restrict__ Gb, const float* __restrict__ wi,
    float* __restrict__ mid, const int* __restrict__ total) {
  const int e = blockIdx.z;
  const int tot = total[e];
  const int m0 = blockIdx.y * 64;
  if (m0 >= tot) return;
  const int n0 = blockIdx.x * 64;
  const float* A = Gb + (size_t)e * 1024 * DM;
  const float* B = wi + (size_t)e * DM * FF;
  float* C = mid + (size_t)e * 1024 * FF;
  __shared__ __align__(16) float As[16][68];
  __shared__ __align__(16) float Bs[16][68];
  const int tid = threadIdx.x;
  const int tx4 = (tid & 15) * 4, ty4 = (tid >> 4) * 4;
  const int lr = tid >> 2, lk4 = (tid & 3) * 4;
  const int bkk = tid >> 4, bn4 = (tid & 15) * 4;
  float acc[4][4] = {};
  for (int kt = 0; kt < DM; kt += 16) {
    float4 av = *reinterpret_cast<const float4*>(A + (size_t)(m0 + lr) * DM + kt + lk4);
    As[lk4+0][lr] = av.x; As[lk4+1][lr] = av.y; As[lk4+2][lr] = av.z; As[lk4+3][lr] = av.w;
    float4 bv = *reinterpret_cast<const float4*>(B + (size_t)(kt + bkk) * FF + n0 + bn4);
    *reinterpret_cast<float4*>(&Bs[bkk][bn4]) = bv;
    __syncthreads();
#pragma unroll
    for (int kk = 0; kk < 16; ++kk) {
      float4 a = *reinterpret_cast<const float4*>(&As[kk][ty4]);
      float4 b = *reinterpret_cast<const float4*>(&Bs[kk][tx4]);
      fma44(a, b, acc);
    }
    __syncthreads();
  }
#pragma unroll
  for (int i = 0; i < 4; ++i) {
    float v0 = acc[i][0], v1 = acc[i][1], v2 = acc[i][2], v3 = acc[i][3];
    float4 ov = make_float4(0.5f*v0*(1.f+erff(v0*0.70710678118654752f)),
                            0.5f*v1*(1.f+erff(v1*0.70710678118654752f)),
                            0.5f*v2*(1.f+erff(v2*0.70710678118654752f)),
                            0.5f*v3*(1.f+erff(v3*0.70710678118654752f)));
    *reinterpret_cast<float4*>(C + (size_t)(m0 + ty4 + i) * FF + n0 + tx4) = ov;
  }
}

// y = mid[e] @ wo[e], scaled-scatter to moebuf ; A[1024,2048] @ B[2048,512]
__global__ __launch_bounds__(256) void ffn2_kernel(const float* __restrict__ mid, const float* __restrict__ wo,
    const int* __restrict__ tok, const float* __restrict__ mscale, const int* __restrict__ total,
    float* __restrict__ moebuf) {
  const int e = blockIdx.z;
  const int tot = total[e];
  const int m0 = blockIdx.y * 64;
  if (m0 >= tot) return;
  const int n0 = blockIdx.x * 64;
  const float* A = mid + (size_t)e * 1024 * FF;
  const float* B = wo + (size_t)e * FF * DM;
  __shared__ __align__(16) float As[16][68];
  __shared__ __align__(16) float Bs[16][68];
  const int tid = threadIdx.x;
  const int tx4 = (tid & 15) * 4, ty4 = (tid >> 4) * 4;
  const int lr = tid >> 2, lk4 = (tid & 3) * 4;
  const int bkk = tid >> 4, bn4 = (tid & 15) * 4;
  float acc[4][4] = {};
  for (int kt = 0; kt < FF; kt += 16) {
    float4 av = *reinterpret_cast<const float4*>(A + (size_t)(m0 + lr) * FF + kt + lk4);
    As[lk4+0][lr] = av.x; As[lk4+1][lr] = av.y; As[lk4+2][lr] = av.z; As[lk4+3][lr] = av.w;
    float4 bv = *reinterpret_cast<const float4*>(B + (size_t)(kt + bkk) * DM + n0 + bn4);
    *reinterpret_cast<float4*>(&Bs[bkk][bn4]) = bv;
    __syncthreads();
#pragma unroll
    for (int kk = 0; kk < 16; ++kk) {
      float4 a = *reinterpret_cast<const float4*>(&As[kk][ty4]);
      float4 b = *reinterpret_cast<const float4*>(&Bs[kk][tx4]);
      fma44(a, b, acc);
    }
    __syncthreads();
  }
#pragma unroll
  for (int i = 0; i < 4; ++i) {
    int slot = m0 + ty4 + i;
    if (slot < tot) {
      int idx = e * 1024 + slot;
      int t = tok[idx];
      float sc = mscale[idx];
      *reinterpret_cast<float4*>(moebuf + (size_t)t * DM + n0 + tx4) =
          make_float4(sc*acc[i][0], sc*acc[i][1], sc*acc[i][2], sc*acc[i][3]);
    }
  }
}

extern "C" void kernel_launch(void* const* d_in, const int* in_sizes, int n_in,
                              void* d_out, int out_size, void* d_ws, size_t ws_size,
                              hipStream_t stream) {
  const float* x     = (const float*)d_in[0];
  const float* in_w  = (const float*)d_in[1];
  const float* in_b  = (const float*)d_in[2];
  const float* out_w = (const float*)d_in[3];
  const float* out_b = (const float*)d_in[4];
  const float* ln1g  = (const float*)d_in[5];
  const float* ln1b  = (const float*)d_in[6];
  const float* ln2g  = (const float*)d_in[7];
  const float* ln2b  = (const float*)d_in[8];
  const float* rw    = (const float*)d_in[9];
  const float* wi    = (const float*)d_in[10];
  const float* wo    = (const float*)d_in[11];
  const int*   capp  = (const int*)d_in[12];

  float* ws = (float*)d_ws;
  float* qkv    = ws;                    // 6291456 floats; reused as G after attention
  float* G      = ws;                    // 8*1024*512 = 4194304 (alias, safe: qkv dead)
  float* attn_o = ws + 6291456;          // 2097152; reused as moebuf after out-proj
  float* moebuf = attn_o;                // alias
  float* r1     = ws + 8388608;          // 2097152
  float* h      = ws + 10485760;         // 2097152
  float* probs  = ws + 12582912;         // 32768
  float* mid    = ws + 12615680;         // 8*1024*2048 = 16777216
  float* mscale = ws + 29392896;         // 8192
  int* am    = (int*)(ws + 29401088);    // 4096
  int* pos   = am + NTOK;                // 4096
  int* cnt   = pos + NTOK;               // 32
  int* offbe = cnt + 32;                 // 32
  int* total = offbe + 32;               // 8
  int* tok   = total + 8;                // 8192

  float* out   = (float*)d_out;          // 2097152
  float* rlog  = out + 2097152;          // 32768
  float* emask = rlog + 32768;           // 32768

  // 1. qkv = x @ in_proj_w^T + in_proj_b
  gemm_bt<<<dim3(24, 64), 256, 0, stream>>>(x, in_w, in_b, nullptr, qkv, NTOK, 1536, DM);
  // 2. attention
  attn_kernel<<<dim3(16, 8, 4), 256, 0, stream>>>(qkv, attn_o);
  // 3. r1 = attn_o @ out_proj_w^T + out_proj_b + x
  gemm_bt<<<dim3(8, 64), 256, 0, stream>>>(attn_o, out_w, out_b, x, r1, NTOK, DM, DM);
  // 4. h = LN1(r1)
  ln_kernel<<<NTOK, 64, 0, stream>>>(r1, nullptr, ln1g, ln1b, h);
  // 5. router logits (also an output)
  router_kernel<<<128, 256, 0, stream>>>(h, rw, rlog);
  // 6. softmax + argmax
  smax_kernel<<<16, 256, 0, stream>>>(rlog, probs, am);
  // 7. capacity scan + expert_mask output
  scan_kernel<<<32, 256, 0, stream>>>(am, probs, capp, emask, pos, cnt);
  // 8. per-expert offsets/totals
  offsets_kernel<<<1, 64, 0, stream>>>(cnt, offbe, total);
  // 9. zero moebuf (aliases attn_o — must come after step 3)
  hipMemsetAsync(moebuf, 0, (size_t)NTOK * DM * sizeof(float), stream);
  // 10. gather kept tokens (writes G, which aliases qkv — qkv dead after step 2)
  gather_kernel<<<NTOK, 128, 0, stream>>>(h, am, pos, capp, offbe, probs, G, tok, mscale);
  // 11. mid = gelu(G @ wi)
  ffn1_kernel<<<dim3(32, 16, 8), 256, 0, stream>>>(G, wi, mid, total);
  // 12. moebuf = scatter(mscale * (mid @ wo))
  ffn2_kernel<<<dim3(8, 16, 8), 256, 0, stream>>>(mid, wo, tok, mscale, total, moebuf);
  // 13. out = LN2(h + moebuf)
  ln_kernel<<<NTOK, 64, 0, stream>>>(h, moebuf, ln2g, ln2b, out);
}

// Round 3
// 561.709 us; speedup vs baseline: 1.4237x; 1.4237x over previous
//
#include <hip/hip_runtime.h>
#include <math.h>

#define SEQ 1024
#define NTOK 4096
#define DM 512
#define FF 2048
#define NE 8

typedef __attribute__((ext_vector_type(8))) short bf16x8;
typedef __attribute__((ext_vector_type(4))) float f32x4;

__device__ __forceinline__ short f2bf(float f) {
  unsigned u = __float_as_uint(f);
  unsigned r = (u + 0x7FFFu + ((u >> 16) & 1u)) >> 16;
  return (short)r;
}

#define GLOAD_LDS16(g, l) __builtin_amdgcn_global_load_lds( \
    (const __attribute__((address_space(1))) void*)(g),     \
    (__attribute__((address_space(3))) void*)(l), 16, 0, 0)

__device__ __forceinline__ void fma44(const float4& a, const float4& b, float (&acc)[4][4]) {
  acc[0][0] += a.x*b.x; acc[0][1] += a.x*b.y; acc[0][2] += a.x*b.z; acc[0][3] += a.x*b.w;
  acc[1][0] += a.y*b.x; acc[1][1] += a.y*b.y; acc[1][2] += a.y*b.z; acc[1][3] += a.y*b.w;
  acc[2][0] += a.z*b.x; acc[2][1] += a.z*b.y; acc[2][2] += a.z*b.z; acc[2][3] += a.z*b.w;
  acc[3][0] += a.w*b.x; acc[3][1] += a.w*b.y; acc[3][2] += a.w*b.z; acc[3][3] += a.w*b.w;
}

// ---------- fp32 path (router-critical) ----------

// C[M,N] = A[M,K] @ B[N,K]^T + bias[N] (+ resid[M,N])
__global__ __launch_bounds__(256) void gemm_bt(const float* __restrict__ A, const float* __restrict__ B,
    const float* __restrict__ bias, const float* __restrict__ resid, float* __restrict__ C,
    int M, int N, int K) {
  __shared__ __align__(16) float As[16][68];
  __shared__ __align__(16) float Bs[16][68];
  const int tid = threadIdx.x;
  const int tx4 = (tid & 15) * 4, ty4 = (tid >> 4) * 4;
  const int n0 = blockIdx.x * 64, m0 = blockIdx.y * 64;
  const int lr = tid >> 2, lk4 = (tid & 3) * 4;
  float acc[4][4] = {};
  for (int kt = 0; kt < K; kt += 16) {
    float4 av = *reinterpret_cast<const float4*>(A + (size_t)(m0 + lr) * K + kt + lk4);
    float4 bv = *reinterpret_cast<const float4*>(B + (size_t)(n0 + lr) * K + kt + lk4);
    As[lk4+0][lr] = av.x; As[lk4+1][lr] = av.y; As[lk4+2][lr] = av.z; As[lk4+3][lr] = av.w;
    Bs[lk4+0][lr] = bv.x; Bs[lk4+1][lr] = bv.y; Bs[lk4+2][lr] = bv.z; Bs[lk4+3][lr] = bv.w;
    __syncthreads();
#pragma unroll
    for (int kk = 0; kk < 16; ++kk) {
      float4 a = *reinterpret_cast<const float4*>(&As[kk][ty4]);
      float4 b = *reinterpret_cast<const float4*>(&Bs[kk][tx4]);
      fma44(a, b, acc);
    }
    __syncthreads();
  }
  float4 bsv = *reinterpret_cast<const float4*>(bias + n0 + tx4);
#pragma unroll
  for (int i = 0; i < 4; ++i) {
    int row = m0 + ty4 + i;
    float4 v = make_float4(acc[i][0] + bsv.x, acc[i][1] + bsv.y, acc[i][2] + bsv.z, acc[i][3] + bsv.w);
    if (resid) {
      float4 r = *reinterpret_cast<const float4*>(resid + (size_t)row * N + n0 + tx4);
      v.x += r.x; v.y += r.y; v.z += r.z; v.w += r.w;
    }
    *reinterpret_cast<float4*>(C + (size_t)row * N + n0 + tx4) = v;
  }
}

// Flash-style fp32 attention. One block per (q-tile 64, head, batch).
__global__ __launch_bounds__(256) void attn_kernel(const float* __restrict__ qkv, float* __restrict__ o) {
  const int qt = blockIdx.x, hh = blockIdx.y, b = blockIdx.z;
  const int tid = threadIdx.x;
  const int tx4 = (tid & 15) * 4, ty4 = (tid >> 4) * 4;
  __shared__ __align__(16) float Qs[64][68];
  __shared__ __align__(16) float KPs[64][68];
  __shared__ __align__(16) float Vs[64][68];
  const int ld = tid & 63, lw = tid >> 6;
  const size_t bb = (size_t)b * SEQ * 1536;
  const int hoff = hh * 64;
#pragma unroll
  for (int rr = 0; rr < 16; ++rr) {
    int r = rr * 4 + lw;
    Qs[ld][r] = qkv[bb + (size_t)(qt * 64 + r) * 1536 + hoff + ld];
  }
  float oacc[4][4] = {};
  float m_run[4], l_run[4];
#pragma unroll
  for (int i = 0; i < 4; ++i) { m_run[i] = -1e30f; l_run[i] = 0.f; }
  for (int kc = 0; kc < 16; ++kc) {
#pragma unroll
    for (int rr = 0; rr < 16; ++rr) {
      int c = rr * 4 + lw;
      size_t rowb = bb + (size_t)(kc * 64 + c) * 1536;
      KPs[ld][c] = qkv[rowb + 512 + hoff + ld];
      Vs[c][ld]  = qkv[rowb + 1024 + hoff + ld];
    }
    __syncthreads();
    float s[4][4] = {};
#pragma unroll 8
    for (int d = 0; d < 64; ++d) {
      float4 a  = *reinterpret_cast<const float4*>(&Qs[d][ty4]);
      float4 kv = *reinterpret_cast<const float4*>(&KPs[d][tx4]);
      fma44(a, kv, s);
    }
    __syncthreads();
#pragma unroll
    for (int i = 0; i < 4; ++i) {
#pragma unroll
      for (int j = 0; j < 4; ++j) s[i][j] *= 0.125f;
      float mc = fmaxf(fmaxf(s[i][0], s[i][1]), fmaxf(s[i][2], s[i][3]));
#pragma unroll
      for (int msk = 1; msk < 16; msk <<= 1) mc = fmaxf(mc, __shfl_xor(mc, msk, 64));
      float mn = fmaxf(m_run[i], mc);
      float alpha = expf(m_run[i] - mn);
      float pl = 0.f;
#pragma unroll
      for (int j = 0; j < 4; ++j) { float p = expf(s[i][j] - mn); s[i][j] = p; pl += p; }
#pragma unroll
      for (int msk = 1; msk < 16; msk <<= 1) pl += __shfl_xor(pl, msk, 64);
      l_run[i] = l_run[i] * alpha + pl;
      m_run[i] = mn;
#pragma unroll
      for (int j = 0; j < 4; ++j) oacc[i][j] *= alpha;
    }
#pragma unroll
    for (int i = 0; i < 4; ++i)
      *reinterpret_cast<float4*>(&KPs[ty4 + i][tx4]) = make_float4(s[i][0], s[i][1], s[i][2], s[i][3]);
    __syncthreads();
#pragma unroll 8
    for (int kcol = 0; kcol < 64; ++kcol) {
      float4 vv = *reinterpret_cast<const float4*>(&Vs[kcol][tx4]);
      float a0 = KPs[ty4+0][kcol], a1 = KPs[ty4+1][kcol], a2 = KPs[ty4+2][kcol], a3 = KPs[ty4+3][kcol];
      oacc[0][0] += a0*vv.x; oacc[0][1] += a0*vv.y; oacc[0][2] += a0*vv.z; oacc[0][3] += a0*vv.w;
      oacc[1][0] += a1*vv.x; oacc[1][1] += a1*vv.y; oacc[1][2] += a1*vv.z; oacc[1][3] += a1*vv.w;
      oacc[2][0] += a2*vv.x; oacc[2][1] += a2*vv.y; oacc[2][2] += a2*vv.z; oacc[2][3] += a2*vv.w;
      oacc[3][0] += a3*vv.x; oacc[3][1] += a3*vv.y; oacc[3][2] += a3*vv.z; oacc[3][3] += a3*vv.w;
    }
    __syncthreads();
  }
#pragma unroll
  for (int i = 0; i < 4; ++i) {
    float inv = 1.f / l_run[i];
    size_t orow = ((size_t)b * SEQ + qt * 64 + ty4 + i) * DM + hoff + tx4;
    *reinterpret_cast<float4*>(o + orow) = make_float4(oacc[i][0]*inv, oacc[i][1]*inv, oacc[i][2]*inv, oacc[i][3]*inv);
  }
}

__global__ __launch_bounds__(64) void ln_kernel(const float* __restrict__ x, const float* __restrict__ add,
    const float* __restrict__ g, const float* __restrict__ bta, float* __restrict__ y) {
  const int t = blockIdx.x, tid = threadIdx.x;
  const size_t base = (size_t)t * DM + tid * 8;
  float4 v0 = *reinterpret_cast<const float4*>(x + base);
  float4 v1 = *reinterpret_cast<const float4*>(x + base + 4);
  if (add) {
    float4 a0 = *reinterpret_cast<const float4*>(add + base);
    float4 a1 = *reinterpret_cast<const float4*>(add + base + 4);
    v0.x += a0.x; v0.y += a0.y; v0.z += a0.z; v0.w += a0.w;
    v1.x += a1.x; v1.y += a1.y; v1.z += a1.z; v1.w += a1.w;
  }
  float s = v0.x+v0.y+v0.z+v0.w + v1.x+v1.y+v1.z+v1.w;
  float q = v0.x*v0.x+v0.y*v0.y+v0.z*v0.z+v0.w*v0.w + v1.x*v1.x+v1.y*v1.y+v1.z*v1.z+v1.w*v1.w;
#pragma unroll
  for (int m = 1; m < 64; m <<= 1) { s += __shfl_xor(s, m, 64); q += __shfl_xor(q, m, 64); }
  float mean = s * (1.0f/512.0f);
  float var = q * (1.0f/512.0f) - mean * mean;
  float rs = rsqrtf(var + 1e-5f);
  float4 g0 = *reinterpret_cast<const float4*>(g + tid*8);
  float4 g1 = *reinterpret_cast<const float4*>(g + tid*8 + 4);
  float4 b0 = *reinterpret_cast<const float4*>(bta + tid*8);
  float4 b1 = *reinterpret_cast<const float4*>(bta + tid*8 + 4);
  float4 o0 = make_float4((v0.x-mean)*rs*g0.x+b0.x, (v0.y-mean)*rs*g0.y+b0.y,
                          (v0.z-mean)*rs*g0.z+b0.z, (v0.w-mean)*rs*g0.w+b0.w);
  float4 o1 = make_float4((v1.x-mean)*rs*g1.x+b1.x, (v1.y-mean)*rs*g1.y+b1.y,
                          (v1.z-mean)*rs*g1.z+b1.z, (v1.w-mean)*rs*g1.w+b1.w);
  *reinterpret_cast<float4*>(y + base) = o0;
  *reinterpret_cast<float4*>(y + base + 4) = o1;
}

__global__ __launch_bounds__(256) void router_kernel(const float* __restrict__ h, const float* __restrict__ rw,
    float* __restrict__ rlog) {
  int gidx = blockIdx.x * 256 + threadIdx.x;
  int t = gidx >> 3, e = gidx & 7;
  const float* hr = h + (size_t)t * DM;
  float acc = 0.f;
#pragma unroll 8
  for (int d = 0; d < DM; ++d) acc += hr[d] * rw[d * NE + e];
  rlog[gidx] = acc;
}

__global__ __launch_bounds__(256) void smax_kernel(const float* __restrict__ rlog, float* __restrict__ probs,
    int* __restrict__ am) {
  int t = blockIdx.x * 256 + threadIdx.x;
  float v[8];
#pragma unroll
  for (int e = 0; e < 8; ++e) v[e] = rlog[t * 8 + e];
  int best = 0; float bv = v[0];
#pragma unroll
  for (int e = 1; e < 8; ++e) if (v[e] > bv) { bv = v[e]; best = e; }
  float ex[8]; float s = 0.f;
#pragma unroll
  for (int e = 0; e < 8; ++e) { ex[e] = expf(v[e] - bv); s += ex[e]; }
  float inv = 1.f / s;
#pragma unroll
  for (int e = 0; e < 8; ++e) probs[t * 8 + e] = ex[e] * inv;
  am[t] = best;
}

__global__ __launch_bounds__(256) void scan_kernel(const int* __restrict__ am, const float* __restrict__ probs,
    const int* __restrict__ capp, float* __restrict__ emask, int* __restrict__ pos, int* __restrict__ cnt) {
  const int bx = blockIdx.x;
  const int b = bx >> 3, e = bx & 7;
  const int tid = threadIdx.x;
  const int cap = *capp;
  __shared__ int arr[256];
  const int s_base = tid * 4;
  int f[4], incl[4];
  int c = 0;
#pragma unroll
  for (int i = 0; i < 4; ++i) {
    f[i] = (am[b * SEQ + s_base + i] == e) ? 1 : 0;
    c += f[i]; incl[i] = c;
  }
  arr[tid] = c;
  __syncthreads();
  for (int off = 1; off < 256; off <<= 1) {
    int v = (tid >= off) ? arr[tid - off] : 0;
    __syncthreads();
    arr[tid] += v;
    __syncthreads();
  }
  int excl = arr[tid] - c;
  int tot = arr[255];
#pragma unroll
  for (int i = 0; i < 4; ++i) {
    int token = b * SEQ + s_base + i;
    int p = excl + incl[i];
    bool kept = f[i] && (p <= cap);
    emask[(size_t)token * NE + e] = kept ? probs[token * NE + e] : 0.f;
    if (f[i]) pos[token] = p;
  }
  if (tid == 0) cnt[bx] = (tot < cap) ? tot : cap;
}

__global__ __launch_bounds__(64) void offsets_kernel(const int* __restrict__ cnt, int* __restrict__ offbe,
    int* __restrict__ total) {
  int e = threadIdx.x;
  if (e < NE) {
    int run = 0;
    for (int b = 0; b < 4; ++b) { offbe[b * NE + e] = run; run += cnt[b * NE + e]; }
    total[e] = run;
  }
}

// ---------- bf16 MoE FFN path ----------

// W[e][K][N] fp32 -> Wt[e][N][K] bf16, 32x32 LDS-tiled transpose
__global__ __launch_bounds__(256) void transpose_bf16(const float* __restrict__ W, short* __restrict__ Wt,
    int K, int N) {
  __shared__ float T[32][33];
  const float* We = W + (size_t)blockIdx.z * K * N;
  short* Wte = Wt + (size_t)blockIdx.z * K * N;
  const int k0 = blockIdx.y * 32, n0 = blockIdx.x * 32;
  const int r = threadIdx.x >> 3, c4 = (threadIdx.x & 7) * 4;
  float4 v = *reinterpret_cast<const float4*>(&We[(size_t)(k0 + r) * N + n0 + c4]);
  T[r][c4+0] = v.x; T[r][c4+1] = v.y; T[r][c4+2] = v.z; T[r][c4+3] = v.w;
  __syncthreads();
  short4 o;
  o.x = f2bf(T[c4+0][r]); o.y = f2bf(T[c4+1][r]); o.z = f2bf(T[c4+2][r]); o.w = f2bf(T[c4+3][r]);
  *reinterpret_cast<short4*>(&Wte[(size_t)(n0 + r) * K + k0 + c4]) = o;
}

// gather kept tokens' h rows into per-expert contiguous bf16 buffers
__global__ __launch_bounds__(128) void gather_kernel(const float* __restrict__ h, const int* __restrict__ am,
    const int* __restrict__ pos, const int* __restrict__ capp, const int* __restrict__ offbe,
    const float* __restrict__ probs, short* __restrict__ Gb, int* __restrict__ tok, float* __restrict__ mscale) {
  const int t = blockIdx.x;
  const int b = t >> 10;
  const int e = am[t];
  const int p = pos[t];
  if (p > *capp) return;
  const int slot = offbe[b * NE + e] + p - 1;
  const int idx = e * 1024 + slot;
  if (threadIdx.x == 0) { tok[idx] = t; mscale[idx] = probs[t * NE + e]; }
  float4 v = *reinterpret_cast<const float4*>(h + (size_t)t * DM + threadIdx.x * 4);
  short4 o; o.x = f2bf(v.x); o.y = f2bf(v.y); o.z = f2bf(v.z); o.w = f2bf(v.w);
  *reinterpret_cast<short4*>(Gb + (size_t)idx * DM + threadIdx.x * 4) = o;
}

// mid = gelu(Gb[e] @ wi_t[e]^T) in bf16. A[M<=1024,K=512] bf16, Bt[N=2048,K=512] bf16.
// 128x128 tile, 4 waves, 16x16x32 MFMA, global_load_lds staging (m97 recipe).
__global__ __launch_bounds__(256) void ffn1_mfma(const short* __restrict__ Gb, const short* __restrict__ wi_t,
    short* __restrict__ mid, const int* __restrict__ total) {
  const int e = blockIdx.z;
  const int tot = total[e];
  const int m0 = blockIdx.y * 128;
  if (m0 >= tot) return;
  const int n0 = blockIdx.x * 128;
  __shared__ __align__(16) short As[128 * 32];
  __shared__ __align__(16) short Bs[128 * 32];
  const short* A = Gb + ((size_t)e * 1024 + m0) * DM;
  const short* B = wi_t + (size_t)e * FF * DM + (size_t)n0 * DM;
  const int tid = threadIdx.x;
  const int lane = tid & 63, w = tid >> 6;
  const int quad = lane >> 4, l15 = lane & 15;
  const int wm = (w & 1) * 64, wn = (w >> 1) * 64;
  const int sr = tid >> 2, sc = (tid & 3) * 8;   // staging row/col (elements)
  f32x4 acc[4][4];
#pragma unroll
  for (int i = 0; i < 4; ++i)
#pragma unroll
    for (int j = 0; j < 4; ++j) acc[i][j] = (f32x4){0.f, 0.f, 0.f, 0.f};
  for (int kt = 0; kt < DM; kt += 32) {
    GLOAD_LDS16(A + (size_t)sr * DM + kt + sc,        &As[tid * 8]);
    GLOAD_LDS16(A + (size_t)(sr + 64) * DM + kt + sc, &As[2048 + tid * 8]);
    GLOAD_LDS16(B + (size_t)sr * DM + kt + sc,        &Bs[tid * 8]);
    GLOAD_LDS16(B + (size_t)(sr + 64) * DM + kt + sc, &Bs[2048 + tid * 8]);
    __syncthreads();
    bf16x8 a[4], b[4];
#pragma unroll
    for (int i = 0; i < 4; ++i) a[i] = *reinterpret_cast<const bf16x8*>(&As[(wm + i * 16 + l15) * 32 + quad * 8]);
#pragma unroll
    for (int j = 0; j < 4; ++j) b[j] = *reinterpret_cast<const bf16x8*>(&Bs[(wn + j * 16 + l15) * 32 + quad * 8]);
#pragma unroll
    for (int i = 0; i < 4; ++i)
#pragma unroll
      for (int j = 0; j < 4; ++j)
        acc[i][j] = __builtin_amdgcn_mfma_f32_16x16x32_bf16(a[i], b[j], acc[i][j], 0, 0, 0);
    __syncthreads();
  }
  // epilogue: gelu -> bf16 store. C/D: col=l15, row=quad*4+reg
#pragma unroll
  for (int i = 0; i < 4; ++i) {
#pragma unroll
    for (int reg = 0; reg < 4; ++reg) {
      int row = m0 + wm + i * 16 + quad * 4 + reg;
      short* outr = mid + ((size_t)e * 1024 + row) * FF;
#pragma unroll
      for (int j = 0; j < 4; ++j) {
        float v = acc[i][j][reg];
        float gl = 0.5f * v * (1.f + erff(v * 0.70710678118654752f));
        outr[n0 + wn + j * 16 + l15] = f2bf(gl);
      }
    }
  }
}

// moebuf[token] = mscale * (mid[e] @ wo_t[e]^T). A[M,K=2048] bf16, Bt[N=512,K=2048] bf16.
__global__ __launch_bounds__(256) void ffn2_mfma(const short* __restrict__ mid, const short* __restrict__ wo_t,
    const int* __restrict__ tok, const float* __restrict__ mscale, const int* __restrict__ total,
    float* __restrict__ moebuf) {
  const int e = blockIdx.z;
  const int tot = total[e];
  const int m0 = blockIdx.y * 128;
  if (m0 >= tot) return;
  const int n0 = blockIdx.x * 128;
  __shared__ __align__(16) short As[128 * 32];
  __shared__ __align__(16) short Bs[128 * 32];
  const short* A = mid + ((size_t)e * 1024 + m0) * FF;
  const short* B = wo_t + (size_t)e * DM * FF + (size_t)n0 * FF;
  const int tid = threadIdx.x;
  const int lane = tid & 63, w = tid >> 6;
  const int quad = lane >> 4, l15 = lane & 15;
  const int wm = (w & 1) * 64, wn = (w >> 1) * 64;
  const int sr = tid >> 2, sc = (tid & 3) * 8;
  f32x4 acc[4][4];
#pragma unroll
  for (int i = 0; i < 4; ++i)
#pragma unroll
    for (int j = 0; j < 4; ++j) acc[i][j] = (f32x4){0.f, 0.f, 0.f, 0.f};
  for (int kt = 0; kt < FF; kt += 32) {
    GLOAD_LDS16(A + (size_t)sr * FF + kt + sc,        &As[tid * 8]);
    GLOAD_LDS16(A + (size_t)(sr + 64) * FF + kt + sc, &As[2048 + tid * 8]);
    GLOAD_LDS16(B + (size_t)sr * FF + kt + sc,        &Bs[tid * 8]);
    GLOAD_LDS16(B + (size_t)(sr + 64) * FF + kt + sc, &Bs[2048 + tid * 8]);
    __syncthreads();
    bf16x8 a[4], b[4];
#pragma unroll
    for (int i = 0; i < 4; ++i) a[i] = *reinterpret_cast<const bf16x8*>(&As[(wm + i * 16 + l15) * 32 + quad * 8]);
#pragma unroll
    for (int j = 0; j < 4; ++j) b[j] = *reinterpret_cast<const bf16x8*>(&Bs[(wn + j * 16 + l15) * 32 + quad * 8]);
#pragma unroll
    for (int i = 0; i < 4; ++i)
#pragma unroll
      for (int j = 0; j < 4; ++j)
        acc[i][j] = __builtin_amdgcn_mfma_f32_16x16x32_bf16(a[i], b[j], acc[i][j], 0, 0, 0);
    __syncthreads();
  }
#pragma unroll
  for (int i = 0; i < 4; ++i) {
#pragma unroll
    for (int reg = 0; reg < 4; ++reg) {
      int slot = m0 + wm + i * 16 + quad * 4 + reg;
      if (slot < tot) {
        int idx = e * 1024 + slot;
        int t = tok[idx];
        float scv = mscale[idx];
        float* outr = moebuf + (size_t)t * DM + n0 + wn;
#pragma unroll
        for (int j = 0; j < 4; ++j) outr[j * 16 + l15] = scv * acc[i][j][reg];
      }
    }
  }
}

extern "C" void kernel_launch(void* const* d_in, const int* in_sizes, int n_in,
                              void* d_out, int out_size, void* d_ws, size_t ws_size,
                              hipStream_t stream) {
  const float* x     = (const float*)d_in[0];
  const float* in_w  = (const float*)d_in[1];
  const float* in_b  = (const float*)d_in[2];
  const float* out_w = (const float*)d_in[3];
  const float* out_b = (const float*)d_in[4];
  const float* ln1g  = (const float*)d_in[5];
  const float* ln1b  = (const float*)d_in[6];
  const float* ln2g  = (const float*)d_in[7];
  const float* ln2b  = (const float*)d_in[8];
  const float* rw    = (const float*)d_in[9];
  const float* wi    = (const float*)d_in[10];
  const float* wo    = (const float*)d_in[11];
  const int*   capp  = (const int*)d_in[12];

  float* ws = (float*)d_ws;
  // qkv region [0, 6291456) floats; after attention it is reused by Gb16 + wi_t
  float* qkv    = ws;
  short* Gb16   = (short*)ws;                    // 8192*512 bf16 = 2097152 floats
  short* wi_t   = (short*)(ws + 2097152);        // 8*2048*512 bf16 = 4194304 floats
  float* attn_o = ws + 6291456;                  // 2097152; reused as moebuf
  float* moebuf = attn_o;
  float* r1     = ws + 8388608;                  // 2097152
  float* h      = ws + 10485760;                 // 2097152
  float* probs  = ws + 12582912;                 // 32768
  short* wo_t   = (short*)(ws + 12615680);       // 8*512*2048 bf16 = 4194304 floats
  short* mid16  = (short*)(ws + 16809984);       // 8*1024*2048 bf16 = 8388608 floats
  float* mscale = ws + 25198592;                 // 8192
  int* am    = (int*)(ws + 25206784);            // 4096
  int* pos   = am + NTOK;                        // 4096
  int* cnt   = pos + NTOK;                       // 32
  int* offbe = cnt + 32;                         // 32
  int* total = offbe + 32;                       // 8
  int* tok   = total + 8;                        // 8192

  float* out   = (float*)d_out;
  float* rlog  = out + 2097152;
  float* emask = rlog + 32768;

  // 1. qkv = x @ in_proj_w^T + in_proj_b
  gemm_bt<<<dim3(24, 64), 256, 0, stream>>>(x, in_w, in_b, nullptr, qkv, NTOK, 1536, DM);
  // 2. attention (last consumer of qkv region)
  attn_kernel<<<dim3(16, 8, 4), 256, 0, stream>>>(qkv, attn_o);
  // 3. r1 = attn_o @ out_proj_w^T + out_proj_b + x
  gemm_bt<<<dim3(8, 64), 256, 0, stream>>>(attn_o, out_w, out_b, x, r1, NTOK, DM, DM);
  // 4. weight convert+transpose (wi_t aliases qkv -> must follow step 2)
  transpose_bf16<<<dim3(64, 16, 8), 256, 0, stream>>>(wi, wi_t, DM, FF);
  transpose_bf16<<<dim3(16, 64, 8), 256, 0, stream>>>(wo, wo_t, FF, DM);
  // 5. h = LN1(r1)
  ln_kernel<<<NTOK, 64, 0, stream>>>(r1, nullptr, ln1g, ln1b, h);
  // 6. router logits
  router_kernel<<<128, 256, 0, stream>>>(h, rw, rlog);
  // 7. softmax + argmax
  smax_kernel<<<16, 256, 0, stream>>>(rlog, probs, am);
  // 8. capacity scan + expert_mask
  scan_kernel<<<32, 256, 0, stream>>>(am, probs, capp, emask, pos, cnt);
  // 9. offsets
  offsets_kernel<<<1, 64, 0, stream>>>(cnt, offbe, total);
  // 10. zero moebuf (aliases attn_o, dead after step 3)
  (void)hipMemsetAsync(moebuf, 0, (size_t)NTOK * DM * sizeof(float), stream);
  // 11. gather kept tokens -> bf16 (Gb16 aliases qkv, dead after step 2)
  gather_kernel<<<NTOK, 128, 0, stream>>>(h, am, pos, capp, offbe, probs, Gb16, tok, mscale);
  // 12. mid = gelu(G @ wi) in bf16 MFMA
  ffn1_mfma<<<dim3(16, 8, 8), 256, 0, stream>>>(Gb16, wi_t, mid16, total);
  // 13. moebuf = scatter(mscale * (mid @ wo)) in bf16 MFMA
  ffn2_mfma<<<dim3(4, 8, 8), 256, 0, stream>>>(mid16, wo_t, tok, mscale, total, moebuf);
  // 14. out = LN2(h + moebuf)
  ln_kernel<<<NTOK, 64, 0, stream>>>(h, moebuf, ln2g, ln2b, out);
}

// Round 4
// 478.540 us; speedup vs baseline: 1.6711x; 1.1738x over previous
//
#include <hip/hip_runtime.h>
#include <math.h>

#define SEQ 1024
#define NTOK 4096
#define DM 512
#define FF 2048
#define NE 8

typedef __attribute__((ext_vector_type(8))) short bf16x8;
typedef __attribute__((ext_vector_type(4))) float f32x4;

__device__ __forceinline__ short f2bf(float f) {
  unsigned u = __float_as_uint(f);
  unsigned r = (u + 0x7FFFu + ((u >> 16) & 1u)) >> 16;
  return (short)r;
}

#define GLOAD_LDS16(g, l) __builtin_amdgcn_global_load_lds( \
    (const __attribute__((address_space(1))) void*)(g),     \
    (__attribute__((address_space(3))) void*)(l), 16, 0, 0)

__device__ __forceinline__ void fma44(const float4& a, const float4& b, float (&acc)[4][4]) {
  acc[0][0] += a.x*b.x; acc[0][1] += a.x*b.y; acc[0][2] += a.x*b.z; acc[0][3] += a.x*b.w;
  acc[1][0] += a.y*b.x; acc[1][1] += a.y*b.y; acc[1][2] += a.y*b.z; acc[1][3] += a.y*b.w;
  acc[2][0] += a.z*b.x; acc[2][1] += a.z*b.y; acc[2][2] += a.z*b.z; acc[2][3] += a.z*b.w;
  acc[3][0] += a.w*b.x; acc[3][1] += a.w*b.y; acc[3][2] += a.w*b.z; acc[3][3] += a.w*b.w;
}

// ---------- split fp32 -> (hi, lo) bf16 planes ----------
__global__ __launch_bounds__(256) void split_kernel(const float* __restrict__ src,
    short* __restrict__ hi, short* __restrict__ lo) {
  const size_t base = ((size_t)blockIdx.x * 256 + threadIdx.x) * 8;
  float4 v0 = *reinterpret_cast<const float4*>(src + base);
  float4 v1 = *reinterpret_cast<const float4*>(src + base + 4);
  short h[8]; short l[8];
  float v[8] = {v0.x, v0.y, v0.z, v0.w, v1.x, v1.y, v1.z, v1.w};
#pragma unroll
  for (int i = 0; i < 8; ++i) {
    h[i] = f2bf(v[i]);
    float hf = __uint_as_float(((unsigned)(unsigned short)h[i]) << 16);
    l[i] = f2bf(v[i] - hf);
  }
  *reinterpret_cast<short4*>(hi + base)     = make_short4(h[0], h[1], h[2], h[3]);
  *reinterpret_cast<short4*>(hi + base + 4) = make_short4(h[4], h[5], h[6], h[7]);
  *reinterpret_cast<short4*>(lo + base)     = make_short4(l[0], l[1], l[2], l[3]);
  *reinterpret_cast<short4*>(lo + base + 4) = make_short4(l[4], l[5], l[6], l[7]);
}

// ---------- split-bf16 MFMA GEMM: C[M,N] = A[M,K] @ B[N,K]^T + bias (+resid) ----------
// 3-pass Markidis: a*b ~ a_lo*b_hi + a_hi*b_lo + a_hi*b_hi  (~1e-5 accurate)
// BM=128, BN=32*BNF, BK=32. 4 waves in 2x2 arrangement.
template<int BNF>
__global__ __launch_bounds__(256) void gemm_split(const short* __restrict__ Ah, const short* __restrict__ Al,
    const short* __restrict__ Bh, const short* __restrict__ Bl,
    const float* __restrict__ bias, const float* __restrict__ resid, float* __restrict__ C,
    int N, int K) {
  constexpr int BN = 32 * BNF;
  __shared__ __align__(16) short AsH[128 * 32];
  __shared__ __align__(16) short AsL[128 * 32];
  __shared__ __align__(16) short BsH[BN * 32];
  __shared__ __align__(16) short BsL[BN * 32];
  const int n0 = blockIdx.x * BN, m0 = blockIdx.y * 128;
  const int tid = threadIdx.x;
  const int lane = tid & 63, w = tid >> 6;
  const int quad = lane >> 4, l15 = lane & 15;
  const int wm = (w & 1) * 64, wn = (w >> 1) * 16 * BNF;
  const int sr = tid >> 2, sc = (tid & 3) * 8;
  const short* Ahp = Ah + (size_t)(m0 + sr) * K;
  const short* Alp = Al + (size_t)(m0 + sr) * K;
  const short* Bhp = Bh + (size_t)(n0 + sr) * K;
  const short* Blp = Bl + (size_t)(n0 + sr) * K;
  f32x4 acc[4][BNF];
#pragma unroll
  for (int i = 0; i < 4; ++i)
#pragma unroll
    for (int j = 0; j < BNF; ++j) acc[i][j] = (f32x4){0.f, 0.f, 0.f, 0.f};
  for (int kt = 0; kt < K; kt += 32) {
    GLOAD_LDS16(Ahp + kt + sc,                 &AsH[tid * 8]);
    GLOAD_LDS16(Ahp + (size_t)64 * K + kt + sc, &AsH[2048 + tid * 8]);
    GLOAD_LDS16(Alp + kt + sc,                 &AsL[tid * 8]);
    GLOAD_LDS16(Alp + (size_t)64 * K + kt + sc, &AsL[2048 + tid * 8]);
    GLOAD_LDS16(Bhp + kt + sc,                 &BsH[tid * 8]);
    GLOAD_LDS16(Blp + kt + sc,                 &BsL[tid * 8]);
    if (BNF == 4) {
      GLOAD_LDS16(Bhp + (size_t)64 * K + kt + sc, &BsH[2048 + tid * 8]);
      GLOAD_LDS16(Blp + (size_t)64 * K + kt + sc, &BsL[2048 + tid * 8]);
    }
    __syncthreads();
    bf16x8 ah[4], al[4], bh[BNF], bl[BNF];
#pragma unroll
    for (int i = 0; i < 4; ++i) {
      ah[i] = *reinterpret_cast<const bf16x8*>(&AsH[(wm + i * 16 + l15) * 32 + quad * 8]);
      al[i] = *reinterpret_cast<const bf16x8*>(&AsL[(wm + i * 16 + l15) * 32 + quad * 8]);
    }
#pragma unroll
    for (int j = 0; j < BNF; ++j) {
      bh[j] = *reinterpret_cast<const bf16x8*>(&BsH[(wn + j * 16 + l15) * 32 + quad * 8]);
      bl[j] = *reinterpret_cast<const bf16x8*>(&BsL[(wn + j * 16 + l15) * 32 + quad * 8]);
    }
#pragma unroll
    for (int i = 0; i < 4; ++i)
#pragma unroll
      for (int j = 0; j < BNF; ++j) {
        acc[i][j] = __builtin_amdgcn_mfma_f32_16x16x32_bf16(al[i], bh[j], acc[i][j], 0, 0, 0);
        acc[i][j] = __builtin_amdgcn_mfma_f32_16x16x32_bf16(ah[i], bl[j], acc[i][j], 0, 0, 0);
        acc[i][j] = __builtin_amdgcn_mfma_f32_16x16x32_bf16(ah[i], bh[j], acc[i][j], 0, 0, 0);
      }
    __syncthreads();
  }
#pragma unroll
  for (int i = 0; i < 4; ++i) {
#pragma unroll
    for (int reg = 0; reg < 4; ++reg) {
      const int row = m0 + wm + i * 16 + quad * 4 + reg;
#pragma unroll
      for (int j = 0; j < BNF; ++j) {
        const int col = n0 + wn + j * 16 + l15;
        float v = acc[i][j][reg] + bias[col];
        if (resid) v += resid[(size_t)row * N + col];
        C[(size_t)row * N + col] = v;
      }
    }
  }
}

// ---------- fp32 attention (router-critical, unchanged) ----------
__global__ __launch_bounds__(256) void attn_kernel(const float* __restrict__ qkv, float* __restrict__ o) {
  const int qt = blockIdx.x, hh = blockIdx.y, b = blockIdx.z;
  const int tid = threadIdx.x;
  const int tx4 = (tid & 15) * 4, ty4 = (tid >> 4) * 4;
  __shared__ __align__(16) float Qs[64][68];
  __shared__ __align__(16) float KPs[64][68];
  __shared__ __align__(16) float Vs[64][68];
  const int ld = tid & 63, lw = tid >> 6;
  const size_t bb = (size_t)b * SEQ * 1536;
  const int hoff = hh * 64;
#pragma unroll
  for (int rr = 0; rr < 16; ++rr) {
    int r = rr * 4 + lw;
    Qs[ld][r] = qkv[bb + (size_t)(qt * 64 + r) * 1536 + hoff + ld];
  }
  float oacc[4][4] = {};
  float m_run[4], l_run[4];
#pragma unroll
  for (int i = 0; i < 4; ++i) { m_run[i] = -1e30f; l_run[i] = 0.f; }
  for (int kc = 0; kc < 16; ++kc) {
#pragma unroll
    for (int rr = 0; rr < 16; ++rr) {
      int c = rr * 4 + lw;
      size_t rowb = bb + (size_t)(kc * 64 + c) * 1536;
      KPs[ld][c] = qkv[rowb + 512 + hoff + ld];
      Vs[c][ld]  = qkv[rowb + 1024 + hoff + ld];
    }
    __syncthreads();
    float s[4][4] = {};
#pragma unroll 8
    for (int d = 0; d < 64; ++d) {
      float4 a  = *reinterpret_cast<const float4*>(&Qs[d][ty4]);
      float4 kv = *reinterpret_cast<const float4*>(&KPs[d][tx4]);
      fma44(a, kv, s);
    }
    __syncthreads();
#pragma unroll
    for (int i = 0; i < 4; ++i) {
#pragma unroll
      for (int j = 0; j < 4; ++j) s[i][j] *= 0.125f;
      float mc = fmaxf(fmaxf(s[i][0], s[i][1]), fmaxf(s[i][2], s[i][3]));
#pragma unroll
      for (int msk = 1; msk < 16; msk <<= 1) mc = fmaxf(mc, __shfl_xor(mc, msk, 64));
      float mn = fmaxf(m_run[i], mc);
      float alpha = expf(m_run[i] - mn);
      float pl = 0.f;
#pragma unroll
      for (int j = 0; j < 4; ++j) { float p = expf(s[i][j] - mn); s[i][j] = p; pl += p; }
#pragma unroll
      for (int msk = 1; msk < 16; msk <<= 1) pl += __shfl_xor(pl, msk, 64);
      l_run[i] = l_run[i] * alpha + pl;
      m_run[i] = mn;
#pragma unroll
      for (int j = 0; j < 4; ++j) oacc[i][j] *= alpha;
    }
#pragma unroll
    for (int i = 0; i < 4; ++i)
      *reinterpret_cast<float4*>(&KPs[ty4 + i][tx4]) = make_float4(s[i][0], s[i][1], s[i][2], s[i][3]);
    __syncthreads();
#pragma unroll 8
    for (int kcol = 0; kcol < 64; ++kcol) {
      float4 vv = *reinterpret_cast<const float4*>(&Vs[kcol][tx4]);
      float a0 = KPs[ty4+0][kcol], a1 = KPs[ty4+1][kcol], a2 = KPs[ty4+2][kcol], a3 = KPs[ty4+3][kcol];
      oacc[0][0] += a0*vv.x; oacc[0][1] += a0*vv.y; oacc[0][2] += a0*vv.z; oacc[0][3] += a0*vv.w;
      oacc[1][0] += a1*vv.x; oacc[1][1] += a1*vv.y; oacc[1][2] += a1*vv.z; oacc[1][3] += a1*vv.w;
      oacc[2][0] += a2*vv.x; oacc[2][1] += a2*vv.y; oacc[2][2] += a2*vv.z; oacc[2][3] += a2*vv.w;
      oacc[3][0] += a3*vv.x; oacc[3][1] += a3*vv.y; oacc[3][2] += a3*vv.z; oacc[3][3] += a3*vv.w;
    }
    __syncthreads();
  }
#pragma unroll
  for (int i = 0; i < 4; ++i) {
    float inv = 1.f / l_run[i];
    size_t orow = ((size_t)b * SEQ + qt * 64 + ty4 + i) * DM + hoff + tx4;
    *reinterpret_cast<float4*>(o + orow) = make_float4(oacc[i][0]*inv, oacc[i][1]*inv, oacc[i][2]*inv, oacc[i][3]*inv);
  }
}

__global__ __launch_bounds__(64) void ln_kernel(const float* __restrict__ x, const float* __restrict__ add,
    const float* __restrict__ g, const float* __restrict__ bta, float* __restrict__ y) {
  const int t = blockIdx.x, tid = threadIdx.x;
  const size_t base = (size_t)t * DM + tid * 8;
  float4 v0 = *reinterpret_cast<const float4*>(x + base);
  float4 v1 = *reinterpret_cast<const float4*>(x + base + 4);
  if (add) {
    float4 a0 = *reinterpret_cast<const float4*>(add + base);
    float4 a1 = *reinterpret_cast<const float4*>(add + base + 4);
    v0.x += a0.x; v0.y += a0.y; v0.z += a0.z; v0.w += a0.w;
    v1.x += a1.x; v1.y += a1.y; v1.z += a1.z; v1.w += a1.w;
  }
  float s = v0.x+v0.y+v0.z+v0.w + v1.x+v1.y+v1.z+v1.w;
  float q = v0.x*v0.x+v0.y*v0.y+v0.z*v0.z+v0.w*v0.w + v1.x*v1.x+v1.y*v1.y+v1.z*v1.z+v1.w*v1.w;
#pragma unroll
  for (int m = 1; m < 64; m <<= 1) { s += __shfl_xor(s, m, 64); q += __shfl_xor(q, m, 64); }
  float mean = s * (1.0f/512.0f);
  float var = q * (1.0f/512.0f) - mean * mean;
  float rs = rsqrtf(var + 1e-5f);
  float4 g0 = *reinterpret_cast<const float4*>(g + tid*8);
  float4 g1 = *reinterpret_cast<const float4*>(g + tid*8 + 4);
  float4 b0 = *reinterpret_cast<const float4*>(bta + tid*8);
  float4 b1 = *reinterpret_cast<const float4*>(bta + tid*8 + 4);
  float4 o0 = make_float4((v0.x-mean)*rs*g0.x+b0.x, (v0.y-mean)*rs*g0.y+b0.y,
                          (v0.z-mean)*rs*g0.z+b0.z, (v0.w-mean)*rs*g0.w+b0.w);
  float4 o1 = make_float4((v1.x-mean)*rs*g1.x+b1.x, (v1.y-mean)*rs*g1.y+b1.y,
                          (v1.z-mean)*rs*g1.z+b1.z, (v1.w-mean)*rs*g1.w+b1.w);
  *reinterpret_cast<float4*>(y + base) = o0;
  *reinterpret_cast<float4*>(y + base + 4) = o1;
}

__global__ __launch_bounds__(256) void router_kernel(const float* __restrict__ h, const float* __restrict__ rw,
    float* __restrict__ rlog) {
  int gidx = blockIdx.x * 256 + threadIdx.x;
  int t = gidx >> 3, e = gidx & 7;
  const float* hr = h + (size_t)t * DM;
  float acc = 0.f;
#pragma unroll 8
  for (int d = 0; d < DM; ++d) acc += hr[d] * rw[d * NE + e];
  rlog[gidx] = acc;
}

__global__ __launch_bounds__(256) void smax_kernel(const float* __restrict__ rlog, float* __restrict__ probs,
    int* __restrict__ am) {
  int t = blockIdx.x * 256 + threadIdx.x;
  float v[8];
#pragma unroll
  for (int e = 0; e < 8; ++e) v[e] = rlog[t * 8 + e];
  int best = 0; float bv = v[0];
#pragma unroll
  for (int e = 1; e < 8; ++e) if (v[e] > bv) { bv = v[e]; best = e; }
  float ex[8]; float s = 0.f;
#pragma unroll
  for (int e = 0; e < 8; ++e) { ex[e] = expf(v[e] - bv); s += ex[e]; }
  float inv = 1.f / s;
#pragma unroll
  for (int e = 0; e < 8; ++e) probs[t * 8 + e] = ex[e] * inv;
  am[t] = best;
}

__global__ __launch_bounds__(256) void scan_kernel(const int* __restrict__ am, const float* __restrict__ probs,
    const int* __restrict__ capp, float* __restrict__ emask, int* __restrict__ pos, int* __restrict__ cnt) {
  const int bx = blockIdx.x;
  const int b = bx >> 3, e = bx & 7;
  const int tid = threadIdx.x;
  const int cap = *capp;
  __shared__ int arr[256];
  const int s_base = tid * 4;
  int f[4], incl[4];
  int c = 0;
#pragma unroll
  for (int i = 0; i < 4; ++i) {
    f[i] = (am[b * SEQ + s_base + i] == e) ? 1 : 0;
    c += f[i]; incl[i] = c;
  }
  arr[tid] = c;
  __syncthreads();
  for (int off = 1; off < 256; off <<= 1) {
    int v = (tid >= off) ? arr[tid - off] : 0;
    __syncthreads();
    arr[tid] += v;
    __syncthreads();
  }
  int excl = arr[tid] - c;
  int tot = arr[255];
#pragma unroll
  for (int i = 0; i < 4; ++i) {
    int token = b * SEQ + s_base + i;
    int p = excl + incl[i];
    bool kept = f[i] && (p <= cap);
    emask[(size_t)token * NE + e] = kept ? probs[token * NE + e] : 0.f;
    if (f[i]) pos[token] = p;
  }
  if (tid == 0) cnt[bx] = (tot < cap) ? tot : cap;
}

__global__ __launch_bounds__(64) void offsets_kernel(const int* __restrict__ cnt, int* __restrict__ offbe,
    int* __restrict__ total) {
  int e = threadIdx.x;
  if (e < NE) {
    int run = 0;
    for (int b = 0; b < 4; ++b) { offbe[b * NE + e] = run; run += cnt[b * NE + e]; }
    total[e] = run;
  }
}

// ---------- bf16 MoE FFN path ----------
__global__ __launch_bounds__(256) void transpose_bf16(const float* __restrict__ W, short* __restrict__ Wt,
    int K, int N) {
  __shared__ float T[32][33];
  const float* We = W + (size_t)blockIdx.z * K * N;
  short* Wte = Wt + (size_t)blockIdx.z * K * N;
  const int k0 = blockIdx.y * 32, n0 = blockIdx.x * 32;
  const int r = threadIdx.x >> 3, c4 = (threadIdx.x & 7) * 4;
  float4 v = *reinterpret_cast<const float4*>(&We[(size_t)(k0 + r) * N + n0 + c4]);
  T[r][c4+0] = v.x; T[r][c4+1] = v.y; T[r][c4+2] = v.z; T[r][c4+3] = v.w;
  __syncthreads();
  short4 o;
  o.x = f2bf(T[c4+0][r]); o.y = f2bf(T[c4+1][r]); o.z = f2bf(T[c4+2][r]); o.w = f2bf(T[c4+3][r]);
  *reinterpret_cast<short4*>(&Wte[(size_t)(n0 + r) * K + k0 + c4]) = o;
}

__global__ __launch_bounds__(128) void gather_kernel(const float* __restrict__ h, const int* __restrict__ am,
    const int* __restrict__ pos, const int* __restrict__ capp, const int* __restrict__ offbe,
    const float* __restrict__ probs, short* __restrict__ Gb, int* __restrict__ tok, float* __restrict__ mscale) {
  const int t = blockIdx.x;
  const int b = t >> 10;
  const int e = am[t];
  const int p = pos[t];
  if (p > *capp) return;
  const int slot = offbe[b * NE + e] + p - 1;
  const int idx = e * 1024 + slot;
  if (threadIdx.x == 0) { tok[idx] = t; mscale[idx] = probs[t * NE + e]; }
  float4 v = *reinterpret_cast<const float4*>(h + (size_t)t * DM + threadIdx.x * 4);
  short4 o; o.x = f2bf(v.x); o.y = f2bf(v.y); o.z = f2bf(v.z); o.w = f2bf(v.w);
  *reinterpret_cast<short4*>(Gb + (size_t)idx * DM + threadIdx.x * 4) = o;
}

__global__ __launch_bounds__(256) void ffn1_mfma(const short* __restrict__ Gb, const short* __restrict__ wi_t,
    short* __restrict__ mid, const int* __restrict__ total) {
  const int e = blockIdx.z;
  const int tot = total[e];
  const int m0 = blockIdx.y * 128;
  if (m0 >= tot) return;
  const int n0 = blockIdx.x * 128;
  __shared__ __align__(16) short As[128 * 32];
  __shared__ __align__(16) short Bs[128 * 32];
  const short* A = Gb + ((size_t)e * 1024 + m0) * DM;
  const short* B = wi_t + (size_t)e * FF * DM + (size_t)n0 * DM;
  const int tid = threadIdx.x;
  const int lane = tid & 63, w = tid >> 6;
  const int quad = lane >> 4, l15 = lane & 15;
  const int wm = (w & 1) * 64, wn = (w >> 1) * 64;
  const int sr = tid >> 2, sc = (tid & 3) * 8;
  f32x4 acc[4][4];
#pragma unroll
  for (int i = 0; i < 4; ++i)
#pragma unroll
    for (int j = 0; j < 4; ++j) acc[i][j] = (f32x4){0.f, 0.f, 0.f, 0.f};
  for (int kt = 0; kt < DM; kt += 32) {
    GLOAD_LDS16(A + (size_t)sr * DM + kt + sc,        &As[tid * 8]);
    GLOAD_LDS16(A + (size_t)(sr + 64) * DM + kt + sc, &As[2048 + tid * 8]);
    GLOAD_LDS16(B + (size_t)sr * DM + kt + sc,        &Bs[tid * 8]);
    GLOAD_LDS16(B + (size_t)(sr + 64) * DM + kt + sc, &Bs[2048 + tid * 8]);
    __syncthreads();
    bf16x8 a[4], b[4];
#pragma unroll
    for (int i = 0; i < 4; ++i) a[i] = *reinterpret_cast<const bf16x8*>(&As[(wm + i * 16 + l15) * 32 + quad * 8]);
#pragma unroll
    for (int j = 0; j < 4; ++j) b[j] = *reinterpret_cast<const bf16x8*>(&Bs[(wn + j * 16 + l15) * 32 + quad * 8]);
#pragma unroll
    for (int i = 0; i < 4; ++i)
#pragma unroll
      for (int j = 0; j < 4; ++j)
        acc[i][j] = __builtin_amdgcn_mfma_f32_16x16x32_bf16(a[i], b[j], acc[i][j], 0, 0, 0);
    __syncthreads();
  }
#pragma unroll
  for (int i = 0; i < 4; ++i) {
#pragma unroll
    for (int reg = 0; reg < 4; ++reg) {
      int row = m0 + wm + i * 16 + quad * 4 + reg;
      short* outr = mid + ((size_t)e * 1024 + row) * FF;
#pragma unroll
      for (int j = 0; j < 4; ++j) {
        float v = acc[i][j][reg];
        float gl = 0.5f * v * (1.f + erff(v * 0.70710678118654752f));
        outr[n0 + wn + j * 16 + l15] = f2bf(gl);
      }
    }
  }
}

__global__ __launch_bounds__(256) void ffn2_mfma(const short* __restrict__ mid, const short* __restrict__ wo_t,
    const int* __restrict__ tok, const float* __restrict__ mscale, const int* __restrict__ total,
    float* __restrict__ moebuf) {
  const int e = blockIdx.z;
  const int tot = total[e];
  const int m0 = blockIdx.y * 128;
  if (m0 >= tot) return;
  const int n0 = blockIdx.x * 128;
  __shared__ __align__(16) short As[128 * 32];
  __shared__ __align__(16) short Bs[128 * 32];
  const short* A = mid + ((size_t)e * 1024 + m0) * FF;
  const short* B = wo_t + (size_t)e * DM * FF + (size_t)n0 * FF;
  const int tid = threadIdx.x;
  const int lane = tid & 63, w = tid >> 6;
  const int quad = lane >> 4, l15 = lane & 15;
  const int wm = (w & 1) * 64, wn = (w >> 1) * 64;
  const int sr = tid >> 2, sc = (tid & 3) * 8;
  f32x4 acc[4][4];
#pragma unroll
  for (int i = 0; i < 4; ++i)
#pragma unroll
    for (int j = 0; j < 4; ++j) acc[i][j] = (f32x4){0.f, 0.f, 0.f, 0.f};
  for (int kt = 0; kt < FF; kt += 32) {
    GLOAD_LDS16(A + (size_t)sr * FF + kt + sc,        &As[tid * 8]);
    GLOAD_LDS16(A + (size_t)(sr + 64) * FF + kt + sc, &As[2048 + tid * 8]);
    GLOAD_LDS16(B + (size_t)sr * FF + kt + sc,        &Bs[tid * 8]);
    GLOAD_LDS16(B + (size_t)(sr + 64) * FF + kt + sc, &Bs[2048 + tid * 8]);
    __syncthreads();
    bf16x8 a[4], b[4];
#pragma unroll
    for (int i = 0; i < 4; ++i) a[i] = *reinterpret_cast<const bf16x8*>(&As[(wm + i * 16 + l15) * 32 + quad * 8]);
#pragma unroll
    for (int j = 0; j < 4; ++j) b[j] = *reinterpret_cast<const bf16x8*>(&Bs[(wn + j * 16 + l15) * 32 + quad * 8]);
#pragma unroll
    for (int i = 0; i < 4; ++i)
#pragma unroll
      for (int j = 0; j < 4; ++j)
        acc[i][j] = __builtin_amdgcn_mfma_f32_16x16x32_bf16(a[i], b[j], acc[i][j], 0, 0, 0);
    __syncthreads();
  }
#pragma unroll
  for (int i = 0; i < 4; ++i) {
#pragma unroll
    for (int reg = 0; reg < 4; ++reg) {
      int slot = m0 + wm + i * 16 + quad * 4 + reg;
      if (slot < tot) {
        int idx = e * 1024 + slot;
        int t = tok[idx];
        float scv = mscale[idx];
        float* outr = moebuf + (size_t)t * DM + n0 + wn;
#pragma unroll
        for (int j = 0; j < 4; ++j) outr[j * 16 + l15] = scv * acc[i][j][reg];
      }
    }
  }
}

extern "C" void kernel_launch(void* const* d_in, const int* in_sizes, int n_in,
                              void* d_out, int out_size, void* d_ws, size_t ws_size,
                              hipStream_t stream) {
  const float* x     = (const float*)d_in[0];
  const float* in_w  = (const float*)d_in[1];
  const float* in_b  = (const float*)d_in[2];
  const float* out_w = (const float*)d_in[3];
  const float* out_b = (const float*)d_in[4];
  const float* ln1g  = (const float*)d_in[5];
  const float* ln1b  = (const float*)d_in[6];
  const float* ln2g  = (const float*)d_in[7];
  const float* ln2b  = (const float*)d_in[8];
  const float* rw    = (const float*)d_in[9];
  const float* wi    = (const float*)d_in[10];
  const float* wo    = (const float*)d_in[11];
  const int*   capp  = (const int*)d_in[12];

  float* ws = (float*)d_ws;
  float* qkv    = ws;                            // 6291456 floats
  short* Gb16   = (short*)ws;                    // aliases qkv (dead after attention)
  short* wi_t   = (short*)(ws + 2097152);        // aliases qkv tail
  float* attn_o = ws + 6291456;                  // 2097152; reused as moebuf
  float* moebuf = attn_o;
  float* r1     = ws + 8388608;                  // 2097152
  float* h      = ws + 10485760;                 // 2097152
  float* probs  = ws + 12582912;                 // 32768
  short* wo_t   = (short*)(ws + 12615680);       // 4194304 floats as bf16
  short* mid16  = (short*)(ws + 16809984);       // 8388608 floats as bf16
  float* mscale = ws + 25198592;                 // 8192
  int* am    = (int*)(ws + 25206784);            // 4096
  int* pos   = am + NTOK;                        // 4096
  int* cnt   = pos + NTOK;                       // 32
  int* offbe = cnt + 32;                         // 32
  int* total = offbe + 32;                       // 8
  int* tok   = total + 8;                        // 8192
  // split scratch (reused for qkv-GEMM then out-proj-GEMM)
  short* sAh = (short*)(ws + 25231360);          // 2097152 shorts (4096x512)
  short* sAl = sAh + 2097152;
  short* sBh = sAl + 2097152;                    // 786432 shorts (1536x512)
  short* sBl = sBh + 786432;
  // end: ws + 25231360 + 2883584 floats = 28114944 floats (~112.5 MB)

  float* out   = (float*)d_out;
  float* rlog  = out + 2097152;
  float* emask = rlog + 32768;

  // 1. split x and in_proj_w to (hi,lo) bf16 planes
  split_kernel<<<1024, 256, 0, stream>>>(x, sAh, sAl);
  split_kernel<<<384, 256, 0, stream>>>(in_w, sBh, sBl);
  // 2. qkv = x @ in_w^T + in_b  (split-bf16 MFMA, 3-pass)
  gemm_split<4><<<dim3(12, 32), 256, 0, stream>>>(sAh, sAl, sBh, sBl, in_b, nullptr, qkv, 1536, DM);
  // 3. attention (fp32; last consumer of qkv)
  attn_kernel<<<dim3(16, 8, 4), 256, 0, stream>>>(qkv, attn_o);
  // 4. split attn_o and out_proj_w (reuse scratch)
  split_kernel<<<1024, 256, 0, stream>>>(attn_o, sAh, sAl);
  split_kernel<<<128, 256, 0, stream>>>(out_w, sBh, sBl);
  // 5. r1 = attn_o @ out_w^T + out_b + x  (split-bf16 MFMA, BN=64 -> 256 blocks)
  gemm_split<2><<<dim3(8, 32), 256, 0, stream>>>(sAh, sAl, sBh, sBl, out_b, x, r1, DM, DM);
  // 6. weight convert+transpose for FFN (wi_t aliases qkv tail; qkv dead after step 3)
  transpose_bf16<<<dim3(64, 16, 8), 256, 0, stream>>>(wi, wi_t, DM, FF);
  transpose_bf16<<<dim3(16, 64, 8), 256, 0, stream>>>(wo, wo_t, FF, DM);
  // 7. h = LN1(r1)
  ln_kernel<<<NTOK, 64, 0, stream>>>(r1, nullptr, ln1g, ln1b, h);
  // 8. router logits
  router_kernel<<<128, 256, 0, stream>>>(h, rw, rlog);
  // 9. softmax + argmax
  smax_kernel<<<16, 256, 0, stream>>>(rlog, probs, am);
  // 10. capacity scan + expert_mask
  scan_kernel<<<32, 256, 0, stream>>>(am, probs, capp, emask, pos, cnt);
  // 11. offsets
  offsets_kernel<<<1, 64, 0, stream>>>(cnt, offbe, total);
  // 12. zero moebuf (aliases attn_o, dead after step 5)
  (void)hipMemsetAsync(moebuf, 0, (size_t)NTOK * DM * sizeof(float), stream);
  // 13. gather kept tokens -> bf16 (Gb16 aliases qkv head, dead after step 3)
  gather_kernel<<<NTOK, 128, 0, stream>>>(h, am, pos, capp, offbe, probs, Gb16, tok, mscale);
  // 14. mid = gelu(G @ wi) bf16 MFMA
  ffn1_mfma<<<dim3(16, 8, 8), 256, 0, stream>>>(Gb16, wi_t, mid16, total);
  // 15. moebuf = scatter(mscale * (mid @ wo)) bf16 MFMA
  ffn2_mfma<<<dim3(4, 8, 8), 256, 0, stream>>>(mid16, wo_t, tok, mscale, total, moebuf);
  // 16. out = LN2(h + moebuf)
  ln_kernel<<<NTOK, 64, 0, stream>>>(h, moebuf, ln2g, ln2b, out);
}

// Round 5
// 406.909 us; speedup vs baseline: 1.9653x; 1.1760x over previous
//
#include <hip/hip_runtime.h>
#include <math.h>

#define SEQ 1024
#define NTOK 4096
#define DM 512
#define FF 2048
#define NE 8

typedef __attribute__((ext_vector_type(8))) short bf16x8;
typedef __attribute__((ext_vector_type(4))) float f32x4;

__device__ __forceinline__ short f2bf(float f) {
  unsigned u = __float_as_uint(f);
  unsigned r = (u + 0x7FFFu + ((u >> 16) & 1u)) >> 16;
  return (short)r;
}
__device__ __forceinline__ float bf2f(short h) {
  return __uint_as_float(((unsigned)(unsigned short)h) << 16);
}

#define GLOAD_LDS16(g, l) __builtin_amdgcn_global_load_lds( \
    (const __attribute__((address_space(1))) void*)(g),     \
    (__attribute__((address_space(3))) void*)(l), 16, 0, 0)

// ---------- split fp32 -> (hi, lo) bf16 planes ----------
__global__ __launch_bounds__(256) void split_kernel(const float* __restrict__ src,
    short* __restrict__ hi, short* __restrict__ lo) {
  const size_t base = ((size_t)blockIdx.x * 256 + threadIdx.x) * 8;
  float4 v0 = *reinterpret_cast<const float4*>(src + base);
  float4 v1 = *reinterpret_cast<const float4*>(src + base + 4);
  short h[8]; short l[8];
  float v[8] = {v0.x, v0.y, v0.z, v0.w, v1.x, v1.y, v1.z, v1.w};
#pragma unroll
  for (int i = 0; i < 8; ++i) {
    h[i] = f2bf(v[i]);
    l[i] = f2bf(v[i] - bf2f(h[i]));
  }
  *reinterpret_cast<short4*>(hi + base)     = make_short4(h[0], h[1], h[2], h[3]);
  *reinterpret_cast<short4*>(hi + base + 4) = make_short4(h[4], h[5], h[6], h[7]);
  *reinterpret_cast<short4*>(lo + base)     = make_short4(l[0], l[1], l[2], l[3]);
  *reinterpret_cast<short4*>(lo + base + 4) = make_short4(l[4], l[5], l[6], l[7]);
}

// ---------- split-bf16 MFMA GEMM (generic): C = A@B^T + bias (+resid) ----------
template<int BNF>
__global__ __launch_bounds__(256) void gemm_split(const short* __restrict__ Ah, const short* __restrict__ Al,
    const short* __restrict__ Bh, const short* __restrict__ Bl,
    const float* __restrict__ bias, const float* __restrict__ resid, float* __restrict__ C,
    int N, int K) {
  constexpr int BN = 32 * BNF;
  __shared__ __align__(16) short AsH[128 * 32];
  __shared__ __align__(16) short AsL[128 * 32];
  __shared__ __align__(16) short BsH[BN * 32];
  __shared__ __align__(16) short BsL[BN * 32];
  const int n0 = blockIdx.x * BN, m0 = blockIdx.y * 128;
  const int tid = threadIdx.x;
  const int lane = tid & 63, w = tid >> 6;
  const int quad = lane >> 4, l15 = lane & 15;
  const int wm = (w & 1) * 64, wn = (w >> 1) * 16 * BNF;
  const int sr = tid >> 2, sc = (tid & 3) * 8;
  const short* Ahp = Ah + (size_t)(m0 + sr) * K;
  const short* Alp = Al + (size_t)(m0 + sr) * K;
  const short* Bhp = Bh + (size_t)(n0 + sr) * K;
  const short* Blp = Bl + (size_t)(n0 + sr) * K;
  f32x4 acc[4][BNF];
#pragma unroll
  for (int i = 0; i < 4; ++i)
#pragma unroll
    for (int j = 0; j < BNF; ++j) acc[i][j] = (f32x4){0.f, 0.f, 0.f, 0.f};
  for (int kt = 0; kt < K; kt += 32) {
    GLOAD_LDS16(Ahp + kt + sc,                  &AsH[tid * 8]);
    GLOAD_LDS16(Ahp + (size_t)64 * K + kt + sc, &AsH[2048 + tid * 8]);
    GLOAD_LDS16(Alp + kt + sc,                  &AsL[tid * 8]);
    GLOAD_LDS16(Alp + (size_t)64 * K + kt + sc, &AsL[2048 + tid * 8]);
    GLOAD_LDS16(Bhp + kt + sc,                  &BsH[tid * 8]);
    GLOAD_LDS16(Blp + kt + sc,                  &BsL[tid * 8]);
    if (BNF == 4) {
      GLOAD_LDS16(Bhp + (size_t)64 * K + kt + sc, &BsH[2048 + tid * 8]);
      GLOAD_LDS16(Blp + (size_t)64 * K + kt + sc, &BsL[2048 + tid * 8]);
    }
    __syncthreads();
    bf16x8 ah[4], al[4], bh[BNF], bl[BNF];
#pragma unroll
    for (int i = 0; i < 4; ++i) {
      ah[i] = *reinterpret_cast<const bf16x8*>(&AsH[(wm + i * 16 + l15) * 32 + quad * 8]);
      al[i] = *reinterpret_cast<const bf16x8*>(&AsL[(wm + i * 16 + l15) * 32 + quad * 8]);
    }
#pragma unroll
    for (int j = 0; j < BNF; ++j) {
      bh[j] = *reinterpret_cast<const bf16x8*>(&BsH[(wn + j * 16 + l15) * 32 + quad * 8]);
      bl[j] = *reinterpret_cast<const bf16x8*>(&BsL[(wn + j * 16 + l15) * 32 + quad * 8]);
    }
#pragma unroll
    for (int i = 0; i < 4; ++i)
#pragma unroll
      for (int j = 0; j < BNF; ++j) {
        acc[i][j] = __builtin_amdgcn_mfma_f32_16x16x32_bf16(al[i], bh[j], acc[i][j], 0, 0, 0);
        acc[i][j] = __builtin_amdgcn_mfma_f32_16x16x32_bf16(ah[i], bl[j], acc[i][j], 0, 0, 0);
        acc[i][j] = __builtin_amdgcn_mfma_f32_16x16x32_bf16(ah[i], bh[j], acc[i][j], 0, 0, 0);
      }
    __syncthreads();
  }
#pragma unroll
  for (int i = 0; i < 4; ++i) {
#pragma unroll
    for (int reg = 0; reg < 4; ++reg) {
      const int row = m0 + wm + i * 16 + quad * 4 + reg;
#pragma unroll
      for (int j = 0; j < BNF; ++j) {
        const int col = n0 + wn + j * 16 + l15;
        float v = acc[i][j][reg] + bias[col];
        if (resid) v += resid[(size_t)row * N + col];
        C[(size_t)row * N + col] = v;
      }
    }
  }
}

// ---------- qkv GEMM: same core, epilogue emits split planes ----------
// cols 0..1023 -> qk planes [token][1024]; cols 1024..1535 -> vt planes [b*8+h][64 d][1024 s]
__global__ __launch_bounds__(256) void gemm_split_qkv(const short* __restrict__ Ah, const short* __restrict__ Al,
    const short* __restrict__ Bh, const short* __restrict__ Bl, const float* __restrict__ bias,
    short* __restrict__ qkh, short* __restrict__ qkl, short* __restrict__ vh, short* __restrict__ vl) {
  const int K = DM;
  __shared__ __align__(16) short AsH[128 * 32];
  __shared__ __align__(16) short AsL[128 * 32];
  __shared__ __align__(16) short BsH[128 * 32];
  __shared__ __align__(16) short BsL[128 * 32];
  const int n0 = blockIdx.x * 128, m0 = blockIdx.y * 128;
  const int tid = threadIdx.x;
  const int lane = tid & 63, w = tid >> 6;
  const int quad = lane >> 4, l15 = lane & 15;
  const int wm = (w & 1) * 64, wn = (w >> 1) * 64;
  const int sr = tid >> 2, sc = (tid & 3) * 8;
  const short* Ahp = Ah + (size_t)(m0 + sr) * K;
  const short* Alp = Al + (size_t)(m0 + sr) * K;
  const short* Bhp = Bh + (size_t)(n0 + sr) * K;
  const short* Blp = Bl + (size_t)(n0 + sr) * K;
  f32x4 acc[4][4];
#pragma unroll
  for (int i = 0; i < 4; ++i)
#pragma unroll
    for (int j = 0; j < 4; ++j) acc[i][j] = (f32x4){0.f, 0.f, 0.f, 0.f};
  for (int kt = 0; kt < K; kt += 32) {
    GLOAD_LDS16(Ahp + kt + sc,                  &AsH[tid * 8]);
    GLOAD_LDS16(Ahp + (size_t)64 * K + kt + sc, &AsH[2048 + tid * 8]);
    GLOAD_LDS16(Alp + kt + sc,                  &AsL[tid * 8]);
    GLOAD_LDS16(Alp + (size_t)64 * K + kt + sc, &AsL[2048 + tid * 8]);
    GLOAD_LDS16(Bhp + kt + sc,                  &BsH[tid * 8]);
    GLOAD_LDS16(Bhp + (size_t)64 * K + kt + sc, &BsH[2048 + tid * 8]);
    GLOAD_LDS16(Blp + kt + sc,                  &BsL[tid * 8]);
    GLOAD_LDS16(Blp + (size_t)64 * K + kt + sc, &BsL[2048 + tid * 8]);
    __syncthreads();
    bf16x8 ah[4], al[4], bh[4], bl[4];
#pragma unroll
    for (int i = 0; i < 4; ++i) {
      ah[i] = *reinterpret_cast<const bf16x8*>(&AsH[(wm + i * 16 + l15) * 32 + quad * 8]);
      al[i] = *reinterpret_cast<const bf16x8*>(&AsL[(wm + i * 16 + l15) * 32 + quad * 8]);
      bh[i] = *reinterpret_cast<const bf16x8*>(&BsH[(wn + i * 16 + l15) * 32 + quad * 8]);
      bl[i] = *reinterpret_cast<const bf16x8*>(&BsL[(wn + i * 16 + l15) * 32 + quad * 8]);
    }
#pragma unroll
    for (int i = 0; i < 4; ++i)
#pragma unroll
      for (int j = 0; j < 4; ++j) {
        acc[i][j] = __builtin_amdgcn_mfma_f32_16x16x32_bf16(al[i], bh[j], acc[i][j], 0, 0, 0);
        acc[i][j] = __builtin_amdgcn_mfma_f32_16x16x32_bf16(ah[i], bl[j], acc[i][j], 0, 0, 0);
        acc[i][j] = __builtin_amdgcn_mfma_f32_16x16x32_bf16(ah[i], bh[j], acc[i][j], 0, 0, 0);
      }
    __syncthreads();
  }
  if (blockIdx.x < 8) {
    // Q/K part -> qk planes [token][1024]
#pragma unroll
    for (int i = 0; i < 4; ++i) {
#pragma unroll
      for (int reg = 0; reg < 4; ++reg) {
        const int row = m0 + wm + i * 16 + quad * 4 + reg;
#pragma unroll
        for (int j = 0; j < 4; ++j) {
          const int col = n0 + wn + j * 16 + l15;
          float v = acc[i][j][reg] + bias[col];
          short hv = f2bf(v);
          size_t ad = (size_t)row * 1024 + col;
          qkh[ad] = hv;
          qkl[ad] = f2bf(v - bf2f(hv));
        }
      }
    }
  } else {
    // V part -> transposed planes vt[(b*8+h)*64 + d][1024 tokens], short4 over 4 consecutive s
#pragma unroll
    for (int i = 0; i < 4; ++i) {
      const int row0 = m0 + wm + i * 16 + quad * 4;
      const int bb = row0 >> 10, s0 = row0 & 1023;
#pragma unroll
      for (int j = 0; j < 4; ++j) {
        const int col = n0 + wn + j * 16 + l15;
        const int c2 = col - 1024;
        const int hhd = c2 >> 6, d = c2 & 63;
        const float bc = bias[col];
        float v0 = acc[i][j][0] + bc, v1 = acc[i][j][1] + bc, v2 = acc[i][j][2] + bc, v3 = acc[i][j][3] + bc;
        short4 hv = make_short4(f2bf(v0), f2bf(v1), f2bf(v2), f2bf(v3));
        short4 lv = make_short4(f2bf(v0 - bf2f(hv.x)), f2bf(v1 - bf2f(hv.y)),
                                f2bf(v2 - bf2f(hv.z)), f2bf(v3 - bf2f(hv.w)));
        size_t ad = ((size_t)(bb * 8 + hhd) * 64 + d) * 1024 + s0;
        *reinterpret_cast<short4*>(vh + ad) = hv;
        *reinterpret_cast<short4*>(vl + ad) = lv;
      }
    }
  }
}

// ---------- MFMA flash attention, split-bf16 QK^T and PV ----------
// grid (16 qt, 8 h, 4 b), 256 thr. Output: split planes oh/ol [token][512].
__global__ __launch_bounds__(256) void attn_mfma(const short* __restrict__ qkh, const short* __restrict__ qkl,
    const short* __restrict__ vth, const short* __restrict__ vtl,
    short* __restrict__ oh, short* __restrict__ ol) {
  const int qt = blockIdx.x, hh = blockIdx.y, b = blockIdx.z;
  __shared__ __align__(16) short Qh[4096], Ql[4096], Kh[4096], Kl[4096], Vh[4096], Vl[4096];
  const int tid = threadIdx.x;
  const int lane = tid & 63, w = tid >> 6;
  const int quad = lane >> 4, l15 = lane & 15;
  const int tok0 = b * SEQ + qt * 64;
  const int srow = tid >> 2, schunk = (tid & 3) * 8;
  {
    const size_t qa = (size_t)(tok0 + srow) * 1024 + hh * 64 + schunk;
    GLOAD_LDS16(qkh + qa,      &Qh[tid * 8]);
    GLOAD_LDS16(qkh + qa + 32, &Qh[2048 + tid * 8]);
    GLOAD_LDS16(qkl + qa,      &Ql[tid * 8]);
    GLOAD_LDS16(qkl + qa + 32, &Ql[2048 + tid * 8]);
  }
  __syncthreads();
  bf16x8 qfh[2], qfl[2];
#pragma unroll
  for (int ks = 0; ks < 2; ++ks) {
    qfh[ks] = *reinterpret_cast<const bf16x8*>(&Qh[ks * 2048 + (w * 16 + l15) * 32 + quad * 8]);
    qfl[ks] = *reinterpret_cast<const bf16x8*>(&Ql[ks * 2048 + (w * 16 + l15) * 32 + quad * 8]);
  }
  f32x4 oacc[4];
  float m_run[4], l_run[4];
#pragma unroll
  for (int r = 0; r < 4; ++r) { oacc[r] = (f32x4){0.f, 0.f, 0.f, 0.f}; m_run[r] = -1e30f; l_run[r] = 0.f; }
  const size_t kbase = (size_t)(b * SEQ) * 1024 + 512 + hh * 64;
  const size_t vbase = (size_t)(b * 8 + hh) * 64 * 1024;
  for (int kc = 0; kc < 16; ++kc) {
    const size_t ka = kbase + (size_t)(kc * 64 + srow) * 1024 + schunk;
    GLOAD_LDS16(qkh + ka,      &Kh[tid * 8]);
    GLOAD_LDS16(qkh + ka + 32, &Kh[2048 + tid * 8]);
    GLOAD_LDS16(qkl + ka,      &Kl[tid * 8]);
    GLOAD_LDS16(qkl + ka + 32, &Kl[2048 + tid * 8]);
    const size_t va = vbase + (size_t)srow * 1024 + kc * 64 + schunk;
    GLOAD_LDS16(vth + va,      &Vh[tid * 8]);
    GLOAD_LDS16(vth + va + 32, &Vh[2048 + tid * 8]);
    GLOAD_LDS16(vtl + va,      &Vl[tid * 8]);
    GLOAD_LDS16(vtl + va + 32, &Vl[2048 + tid * 8]);
    __syncthreads();
    // S = Q @ K^T (3-pass split)
    f32x4 s[4];
#pragma unroll
    for (int j = 0; j < 4; ++j) s[j] = (f32x4){0.f, 0.f, 0.f, 0.f};
#pragma unroll
    for (int ks = 0; ks < 2; ++ks)
#pragma unroll
      for (int j = 0; j < 4; ++j) {
        bf16x8 kfh = *reinterpret_cast<const bf16x8*>(&Kh[ks * 2048 + (j * 16 + l15) * 32 + quad * 8]);
        bf16x8 kfl = *reinterpret_cast<const bf16x8*>(&Kl[ks * 2048 + (j * 16 + l15) * 32 + quad * 8]);
        s[j] = __builtin_amdgcn_mfma_f32_16x16x32_bf16(qfl[ks], kfh, s[j], 0, 0, 0);
        s[j] = __builtin_amdgcn_mfma_f32_16x16x32_bf16(qfh[ks], kfl, s[j], 0, 0, 0);
        s[j] = __builtin_amdgcn_mfma_f32_16x16x32_bf16(qfh[ks], kfh, s[j], 0, 0, 0);
      }
    __syncthreads();  // all K-frag reads done before P overwrites Kh/Kl
    // online softmax (rows m = w*16 + quad*4 + reg; cols c = j*16 + l15)
    float pv[4][4], alpha[4];
#pragma unroll
    for (int reg = 0; reg < 4; ++reg) {
      float mc = fmaxf(fmaxf(s[0][reg], s[1][reg]), fmaxf(s[2][reg], s[3][reg]));
#pragma unroll
      for (int msk = 1; msk < 16; msk <<= 1) mc = fmaxf(mc, __shfl_xor(mc, msk, 64));
      mc *= 0.125f;
      float mn = fmaxf(m_run[reg], mc);
      alpha[reg] = expf(m_run[reg] - mn);
      m_run[reg] = mn;
      float pl = 0.f;
#pragma unroll
      for (int j = 0; j < 4; ++j) { float pp = expf(s[j][reg] * 0.125f - mn); pv[j][reg] = pp; pl += pp; }
#pragma unroll
      for (int msk = 1; msk < 16; msk <<= 1) pl += __shfl_xor(pl, msk, 64);
      l_run[reg] = l_run[reg] * alpha[reg] + pl;
    }
#pragma unroll
    for (int j = 0; j < 4; ++j) {
      oacc[j][0] *= alpha[0]; oacc[j][1] *= alpha[1]; oacc[j][2] *= alpha[2]; oacc[j][3] *= alpha[3];
    }
    // write split P over Kh/Kl (rows w*16..w*16+15: own wave only -> no barrier needed)
#pragma unroll
    for (int j = 0; j < 4; ++j) {
      const int cad = (j >> 1) * 2048 + (j & 1) * 16 + l15;
#pragma unroll
      for (int reg = 0; reg < 4; ++reg) {
        const int ad = cad + (w * 16 + quad * 4 + reg) * 32;
        float p = pv[j][reg];
        short hp = f2bf(p);
        Kh[ad] = hp;
        Kl[ad] = f2bf(p - bf2f(hp));
      }
    }
    // O += P @ V (3-pass split); A = P[m][c], B = Vt[d][c]
#pragma unroll
    for (int ks = 0; ks < 2; ++ks) {
      bf16x8 pfh = *reinterpret_cast<const bf16x8*>(&Kh[ks * 2048 + (w * 16 + l15) * 32 + quad * 8]);
      bf16x8 pfl = *reinterpret_cast<const bf16x8*>(&Kl[ks * 2048 + (w * 16 + l15) * 32 + quad * 8]);
#pragma unroll
      for (int j = 0; j < 4; ++j) {
        bf16x8 vfh = *reinterpret_cast<const bf16x8*>(&Vh[ks * 2048 + (j * 16 + l15) * 32 + quad * 8]);
        bf16x8 vfl = *reinterpret_cast<const bf16x8*>(&Vl[ks * 2048 + (j * 16 + l15) * 32 + quad * 8]);
        oacc[j] = __builtin_amdgcn_mfma_f32_16x16x32_bf16(pfl, vfh, oacc[j], 0, 0, 0);
        oacc[j] = __builtin_amdgcn_mfma_f32_16x16x32_bf16(pfh, vfl, oacc[j], 0, 0, 0);
        oacc[j] = __builtin_amdgcn_mfma_f32_16x16x32_bf16(pfh, vfh, oacc[j], 0, 0, 0);
      }
    }
    __syncthreads();  // P/V reads done before next-iter staging
  }
  // epilogue: normalize and emit split planes for the out-proj GEMM
#pragma unroll
  for (int reg = 0; reg < 4; ++reg) {
    float inv = 1.f / l_run[reg];
#pragma unroll
    for (int j = 0; j < 4; ++j) {
      float v = oacc[j][reg] * inv;
      size_t ad = (size_t)(tok0 + w * 16 + quad * 4 + reg) * 512 + hh * 64 + j * 16 + l15;
      short hv = f2bf(v);
      oh[ad] = hv;
      ol[ad] = f2bf(v - bf2f(hv));
    }
  }
}

__global__ __launch_bounds__(64) void ln_kernel(const float* __restrict__ x, const float* __restrict__ add,
    const float* __restrict__ g, const float* __restrict__ bta, float* __restrict__ y) {
  const int t = blockIdx.x, tid = threadIdx.x;
  const size_t base = (size_t)t * DM + tid * 8;
  float4 v0 = *reinterpret_cast<const float4*>(x + base);
  float4 v1 = *reinterpret_cast<const float4*>(x + base + 4);
  if (add) {
    float4 a0 = *reinterpret_cast<const float4*>(add + base);
    float4 a1 = *reinterpret_cast<const float4*>(add + base + 4);
    v0.x += a0.x; v0.y += a0.y; v0.z += a0.z; v0.w += a0.w;
    v1.x += a1.x; v1.y += a1.y; v1.z += a1.z; v1.w += a1.w;
  }
  float s = v0.x+v0.y+v0.z+v0.w + v1.x+v1.y+v1.z+v1.w;
  float q = v0.x*v0.x+v0.y*v0.y+v0.z*v0.z+v0.w*v0.w + v1.x*v1.x+v1.y*v1.y+v1.z*v1.z+v1.w*v1.w;
#pragma unroll
  for (int m = 1; m < 64; m <<= 1) { s += __shfl_xor(s, m, 64); q += __shfl_xor(q, m, 64); }
  float mean = s * (1.0f/512.0f);
  float var = q * (1.0f/512.0f) - mean * mean;
  float rs = rsqrtf(var + 1e-5f);
  float4 g0 = *reinterpret_cast<const float4*>(g + tid*8);
  float4 g1 = *reinterpret_cast<const float4*>(g + tid*8 + 4);
  float4 b0 = *reinterpret_cast<const float4*>(bta + tid*8);
  float4 b1 = *reinterpret_cast<const float4*>(bta + tid*8 + 4);
  float4 o0 = make_float4((v0.x-mean)*rs*g0.x+b0.x, (v0.y-mean)*rs*g0.y+b0.y,
                          (v0.z-mean)*rs*g0.z+b0.z, (v0.w-mean)*rs*g0.w+b0.w);
  float4 o1 = make_float4((v1.x-mean)*rs*g1.x+b1.x, (v1.y-mean)*rs*g1.y+b1.y,
                          (v1.z-mean)*rs*g1.z+b1.z, (v1.w-mean)*rs*g1.w+b1.w);
  *reinterpret_cast<float4*>(y + base) = o0;
  *reinterpret_cast<float4*>(y + base + 4) = o1;
}

__global__ __launch_bounds__(256) void router_kernel(const float* __restrict__ h, const float* __restrict__ rw,
    float* __restrict__ rlog) {
  int gidx = blockIdx.x * 256 + threadIdx.x;
  int t = gidx >> 3, e = gidx & 7;
  const float* hr = h + (size_t)t * DM;
  float acc = 0.f;
#pragma unroll 8
  for (int d = 0; d < DM; ++d) acc += hr[d] * rw[d * NE + e];
  rlog[gidx] = acc;
}

__global__ __launch_bounds__(256) void smax_kernel(const float* __restrict__ rlog, float* __restrict__ probs,
    int* __restrict__ am) {
  int t = blockIdx.x * 256 + threadIdx.x;
  float v[8];
#pragma unroll
  for (int e = 0; e < 8; ++e) v[e] = rlog[t * 8 + e];
  int best = 0; float bv = v[0];
#pragma unroll
  for (int e = 1; e < 8; ++e) if (v[e] > bv) { bv = v[e]; best = e; }
  float ex[8]; float s = 0.f;
#pragma unroll
  for (int e = 0; e < 8; ++e) { ex[e] = expf(v[e] - bv); s += ex[e]; }
  float inv = 1.f / s;
#pragma unroll
  for (int e = 0; e < 8; ++e) probs[t * 8 + e] = ex[e] * inv;
  am[t] = best;
}

__global__ __launch_bounds__(256) void scan_kernel(const int* __restrict__ am, const float* __restrict__ probs,
    const int* __restrict__ capp, float* __restrict__ emask, int* __restrict__ pos, int* __restrict__ cnt) {
  const int bx = blockIdx.x;
  const int b = bx >> 3, e = bx & 7;
  const int tid = threadIdx.x;
  const int cap = *capp;
  __shared__ int arr[256];
  const int s_base = tid * 4;
  int f[4], incl[4];
  int c = 0;
#pragma unroll
  for (int i = 0; i < 4; ++i) {
    f[i] = (am[b * SEQ + s_base + i] == e) ? 1 : 0;
    c += f[i]; incl[i] = c;
  }
  arr[tid] = c;
  __syncthreads();
  for (int off = 1; off < 256; off <<= 1) {
    int v = (tid >= off) ? arr[tid - off] : 0;
    __syncthreads();
    arr[tid] += v;
    __syncthreads();
  }
  int excl = arr[tid] - c;
  int tot = arr[255];
#pragma unroll
  for (int i = 0; i < 4; ++i) {
    int token = b * SEQ + s_base + i;
    int p = excl + incl[i];
    bool kept = f[i] && (p <= cap);
    emask[(size_t)token * NE + e] = kept ? probs[token * NE + e] : 0.f;
    if (f[i]) pos[token] = p;
  }
  if (tid == 0) cnt[bx] = (tot < cap) ? tot : cap;
}

__global__ __launch_bounds__(64) void offsets_kernel(const int* __restrict__ cnt, int* __restrict__ offbe,
    int* __restrict__ total) {
  int e = threadIdx.x;
  if (e < NE) {
    int run = 0;
    for (int b = 0; b < 4; ++b) { offbe[b * NE + e] = run; run += cnt[b * NE + e]; }
    total[e] = run;
  }
}

// ---------- bf16 MoE FFN path ----------
__global__ __launch_bounds__(256) void transpose_bf16(const float* __restrict__ W, short* __restrict__ Wt,
    int K, int N) {
  __shared__ float T[32][33];
  const float* We = W + (size_t)blockIdx.z * K * N;
  short* Wte = Wt + (size_t)blockIdx.z * K * N;
  const int k0 = blockIdx.y * 32, n0 = blockIdx.x * 32;
  const int r = threadIdx.x >> 3, c4 = (threadIdx.x & 7) * 4;
  float4 v = *reinterpret_cast<const float4*>(&We[(size_t)(k0 + r) * N + n0 + c4]);
  T[r][c4+0] = v.x; T[r][c4+1] = v.y; T[r][c4+2] = v.z; T[r][c4+3] = v.w;
  __syncthreads();
  short4 o;
  o.x = f2bf(T[c4+0][r]); o.y = f2bf(T[c4+1][r]); o.z = f2bf(T[c4+2][r]); o.w = f2bf(T[c4+3][r]);
  *reinterpret_cast<short4*>(&Wte[(size_t)(n0 + r) * K + k0 + c4]) = o;
}

__global__ __launch_bounds__(128) void gather_kernel(const float* __restrict__ h, const int* __restrict__ am,
    const int* __restrict__ pos, const int* __restrict__ capp, const int* __restrict__ offbe,
    const float* __restrict__ probs, short* __restrict__ Gb, int* __restrict__ tok, float* __restrict__ mscale) {
  const int t = blockIdx.x;
  const int b = t >> 10;
  const int e = am[t];
  const int p = pos[t];
  if (p > *capp) return;
  const int slot = offbe[b * NE + e] + p - 1;
  const int idx = e * 1024 + slot;
  if (threadIdx.x == 0) { tok[idx] = t; mscale[idx] = probs[t * NE + e]; }
  float4 v = *reinterpret_cast<const float4*>(h + (size_t)t * DM + threadIdx.x * 4);
  short4 o; o.x = f2bf(v.x); o.y = f2bf(v.y); o.z = f2bf(v.z); o.w = f2bf(v.w);
  *reinterpret_cast<short4*>(Gb + (size_t)idx * DM + threadIdx.x * 4) = o;
}

__global__ __launch_bounds__(256) void ffn1_mfma(const short* __restrict__ Gb, const short* __restrict__ wi_t,
    short* __restrict__ mid, const int* __restrict__ total) {
  const int e = blockIdx.z;
  const int tot = total[e];
  const int m0 = blockIdx.y * 128;
  if (m0 >= tot) return;
  const int n0 = blockIdx.x * 128;
  __shared__ __align__(16) short As[128 * 32];
  __shared__ __align__(16) short Bs[128 * 32];
  const short* A = Gb + ((size_t)e * 1024 + m0) * DM;
  const short* B = wi_t + (size_t)e * FF * DM + (size_t)n0 * DM;
  const int tid = threadIdx.x;
  const int lane = tid & 63, w = tid >> 6;
  const int quad = lane >> 4, l15 = lane & 15;
  const int wm = (w & 1) * 64, wn = (w >> 1) * 64;
  const int sr = tid >> 2, sc = (tid & 3) * 8;
  f32x4 acc[4][4];
#pragma unroll
  for (int i = 0; i < 4; ++i)
#pragma unroll
    for (int j = 0; j < 4; ++j) acc[i][j] = (f32x4){0.f, 0.f, 0.f, 0.f};
  for (int kt = 0; kt < DM; kt += 32) {
    GLOAD_LDS16(A + (size_t)sr * DM + kt + sc,        &As[tid * 8]);
    GLOAD_LDS16(A + (size_t)(sr + 64) * DM + kt + sc, &As[2048 + tid * 8]);
    GLOAD_LDS16(B + (size_t)sr * DM + kt + sc,        &Bs[tid * 8]);
    GLOAD_LDS16(B + (size_t)(sr + 64) * DM + kt + sc, &Bs[2048 + tid * 8]);
    __syncthreads();
    bf16x8 a[4], b[4];
#pragma unroll
    for (int i = 0; i < 4; ++i) a[i] = *reinterpret_cast<const bf16x8*>(&As[(wm + i * 16 + l15) * 32 + quad * 8]);
#pragma unroll
    for (int j = 0; j < 4; ++j) b[j] = *reinterpret_cast<const bf16x8*>(&Bs[(wn + j * 16 + l15) * 32 + quad * 8]);
#pragma unroll
    for (int i = 0; i < 4; ++i)
#pragma unroll
      for (int j = 0; j < 4; ++j)
        acc[i][j] = __builtin_amdgcn_mfma_f32_16x16x32_bf16(a[i], b[j], acc[i][j], 0, 0, 0);
    __syncthreads();
  }
#pragma unroll
  for (int i = 0; i < 4; ++i) {
#pragma unroll
    for (int reg = 0; reg < 4; ++reg) {
      int row = m0 + wm + i * 16 + quad * 4 + reg;
      short* outr = mid + ((size_t)e * 1024 + row) * FF;
#pragma unroll
      for (int j = 0; j < 4; ++j) {
        float v = acc[i][j][reg];
        float gl = 0.5f * v * (1.f + erff(v * 0.70710678118654752f));
        outr[n0 + wn + j * 16 + l15] = f2bf(gl);
      }
    }
  }
}

__global__ __launch_bounds__(256) void ffn2_mfma(const short* __restrict__ mid, const short* __restrict__ wo_t,
    const int* __restrict__ tok, const float* __restrict__ mscale, const int* __restrict__ total,
    float* __restrict__ moebuf) {
  const int e = blockIdx.z;
  const int tot = total[e];
  const int m0 = blockIdx.y * 128;
  if (m0 >= tot) return;
  const int n0 = blockIdx.x * 128;
  __shared__ __align__(16) short As[128 * 32];
  __shared__ __align__(16) short Bs[128 * 32];
  const short* A = mid + ((size_t)e * 1024 + m0) * FF;
  const short* B = wo_t + (size_t)e * DM * FF + (size_t)n0 * FF;
  const int tid = threadIdx.x;
  const int lane = tid & 63, w = tid >> 6;
  const int quad = lane >> 4, l15 = lane & 15;
  const int wm = (w & 1) * 64, wn = (w >> 1) * 64;
  const int sr = tid >> 2, sc = (tid & 3) * 8;
  f32x4 acc[4][4];
#pragma unroll
  for (int i = 0; i < 4; ++i)
#pragma unroll
    for (int j = 0; j < 4; ++j) acc[i][j] = (f32x4){0.f, 0.f, 0.f, 0.f};
  for (int kt = 0; kt < FF; kt += 32) {
    GLOAD_LDS16(A + (size_t)sr * FF + kt + sc,        &As[tid * 8]);
    GLOAD_LDS16(A + (size_t)(sr + 64) * FF + kt + sc, &As[2048 + tid * 8]);
    GLOAD_LDS16(B + (size_t)sr * FF + kt + sc,        &Bs[tid * 8]);
    GLOAD_LDS16(B + (size_t)(sr + 64) * FF + kt + sc, &Bs[2048 + tid * 8]);
    __syncthreads();
    bf16x8 a[4], b[4];
#pragma unroll
    for (int i = 0; i < 4; ++i) a[i] = *reinterpret_cast<const bf16x8*>(&As[(wm + i * 16 + l15) * 32 + quad * 8]);
#pragma unroll
    for (int j = 0; j < 4; ++j) b[j] = *reinterpret_cast<const bf16x8*>(&Bs[(wn + j * 16 + l15) * 32 + quad * 8]);
#pragma unroll
    for (int i = 0; i < 4; ++i)
#pragma unroll
      for (int j = 0; j < 4; ++j)
        acc[i][j] = __builtin_amdgcn_mfma_f32_16x16x32_bf16(a[i], b[j], acc[i][j], 0, 0, 0);
    __syncthreads();
  }
#pragma unroll
  for (int i = 0; i < 4; ++i) {
#pragma unroll
    for (int reg = 0; reg < 4; ++reg) {
      int slot = m0 + wm + i * 16 + quad * 4 + reg;
      if (slot < tot) {
        int idx = e * 1024 + slot;
        int t = tok[idx];
        float scv = mscale[idx];
        float* outr = moebuf + (size_t)t * DM + n0 + wn;
#pragma unroll
        for (int j = 0; j < 4; ++j) outr[j * 16 + l15] = scv * acc[i][j][reg];
      }
    }
  }
}

extern "C" void kernel_launch(void* const* d_in, const int* in_sizes, int n_in,
                              void* d_out, int out_size, void* d_ws, size_t ws_size,
                              hipStream_t stream) {
  const float* x     = (const float*)d_in[0];
  const float* in_w  = (const float*)d_in[1];
  const float* in_b  = (const float*)d_in[2];
  const float* out_w = (const float*)d_in[3];
  const float* out_b = (const float*)d_in[4];
  const float* ln1g  = (const float*)d_in[5];
  const float* ln1b  = (const float*)d_in[6];
  const float* ln2g  = (const float*)d_in[7];
  const float* ln2b  = (const float*)d_in[8];
  const float* rw    = (const float*)d_in[9];
  const float* wi    = (const float*)d_in[10];
  const float* wo    = (const float*)d_in[11];
  const int*   capp  = (const int*)d_in[12];

  float* ws = (float*)d_ws;
  // region [0, 6291456): qk/vt split planes; dead after attn -> reused by Gb16/wi_t
  short* qkh  = (short*)ws;                      // 4096x1024 shorts (2,097,152 floats)
  short* qkl  = (short*)(ws + 2097152);
  short* vth  = (short*)(ws + 4194304);          // 32x64x1024 shorts (1,048,576 floats)
  short* vtl  = (short*)(ws + 5242880);
  short* Gb16 = (short*)ws;                      // aliases qkh (post-attn)
  short* wi_t = (short*)(ws + 2097152);          // aliases qkl+vt (post-attn)
  float* moebuf = ws + 6291456;                  // 2,097,152
  float* r1     = ws + 8388608;                  // 2,097,152
  float* h      = ws + 10485760;                 // 2,097,152
  float* probs  = ws + 12582912;                 // 32,768
  short* wo_t   = (short*)(ws + 12615680);       // 8,388,608 shorts
  short* mid16  = (short*)(ws + 16809984);       // 16,777,216 shorts
  float* mscale = ws + 25198592;                 // 8,192
  int* am    = (int*)(ws + 25206784);
  int* pos   = am + NTOK;
  int* cnt   = pos + NTOK;
  int* offbe = cnt + 32;
  int* total = offbe + 32;
  int* tok   = total + 8;
  short* sAh = (short*)(ws + 25231360);          // 4096x512 shorts
  short* sAl = sAh + 2097152;
  short* sBh = sAl + 2097152;                    // 1536x512 shorts
  short* sBl = sBh + 786432;

  float* out   = (float*)d_out;
  float* rlog  = out + 2097152;
  float* emask = rlog + 32768;

  // 1. split x and in_proj_w
  split_kernel<<<1024, 256, 0, stream>>>(x, sAh, sAl);
  split_kernel<<<384, 256, 0, stream>>>(in_w, sBh, sBl);
  // 2. qkv GEMM -> split planes (Q/K row-major, V transposed)
  gemm_split_qkv<<<dim3(12, 32), 256, 0, stream>>>(sAh, sAl, sBh, sBl, in_b, qkh, qkl, vth, vtl);
  // 3. MFMA attention -> split attn_o planes into sAh/sAl (x-split dead after step 2)
  attn_mfma<<<dim3(16, 8, 4), 256, 0, stream>>>(qkh, qkl, vth, vtl, sAh, sAl);
  // 4. split out_proj_w (in_w split dead)
  split_kernel<<<128, 256, 0, stream>>>(out_w, sBh, sBl);
  // 5. r1 = attn_o @ out_w^T + out_b + x
  gemm_split<2><<<dim3(8, 32), 256, 0, stream>>>(sAh, sAl, sBh, sBl, out_b, x, r1, DM, DM);
  // 6. FFN weight transposes (overwrite qk/vt planes; attn done)
  transpose_bf16<<<dim3(64, 16, 8), 256, 0, stream>>>(wi, wi_t, DM, FF);
  transpose_bf16<<<dim3(16, 64, 8), 256, 0, stream>>>(wo, wo_t, FF, DM);
  // 7. h = LN1(r1)
  ln_kernel<<<NTOK, 64, 0, stream>>>(r1, nullptr, ln1g, ln1b, h);
  // 8-11. router chain
  router_kernel<<<128, 256, 0, stream>>>(h, rw, rlog);
  smax_kernel<<<16, 256, 0, stream>>>(rlog, probs, am);
  scan_kernel<<<32, 256, 0, stream>>>(am, probs, capp, emask, pos, cnt);
  offsets_kernel<<<1, 64, 0, stream>>>(cnt, offbe, total);
  // 12. zero moebuf
  (void)hipMemsetAsync(moebuf, 0, (size_t)NTOK * DM * sizeof(float), stream);
  // 13. gather kept tokens -> bf16
  gather_kernel<<<NTOK, 128, 0, stream>>>(h, am, pos, capp, offbe, probs, Gb16, tok, mscale);
  // 14-15. expert FFN
  ffn1_mfma<<<dim3(16, 8, 8), 256, 0, stream>>>(Gb16, wi_t, mid16, total);
  ffn2_mfma<<<dim3(4, 8, 8), 256, 0, stream>>>(mid16, wo_t, tok, mscale, total, moebuf);
  // 16. out = LN2(h + moebuf)
  ln_kernel<<<NTOK, 64, 0, stream>>>(h, moebuf, ln2g, ln2b, out);
}

// Round 6
// 372.211 us; speedup vs baseline: 2.1485x; 1.0932x over previous
//
#include <hip/hip_runtime.h>
#include <math.h>

#define SEQ 1024
#define NTOK 4096
#define DM 512
#define FF 2048
#define NE 8

typedef __attribute__((ext_vector_type(8))) short bf16x8;
typedef __attribute__((ext_vector_type(4))) float f32x4;

__device__ __forceinline__ short f2bf(float f) {
  unsigned u = __float_as_uint(f);
  unsigned r = (u + 0x7FFFu + ((u >> 16) & 1u)) >> 16;
  return (short)r;
}
__device__ __forceinline__ float bf2f(short h) {
  return __uint_as_float(((unsigned)(unsigned short)h) << 16);
}

#define GLOAD_LDS16(g, l) __builtin_amdgcn_global_load_lds( \
    (const __attribute__((address_space(1))) void*)(g),     \
    (__attribute__((address_space(3))) void*)(l), 16, 0, 0)

// ---------- split fp32 -> (hi, lo) bf16 planes ----------
__global__ __launch_bounds__(256) void split_kernel(const float* __restrict__ src,
    short* __restrict__ hi, short* __restrict__ lo) {
  const size_t base = ((size_t)blockIdx.x * 256 + threadIdx.x) * 8;
  float4 v0 = *reinterpret_cast<const float4*>(src + base);
  float4 v1 = *reinterpret_cast<const float4*>(src + base + 4);
  short h[8]; short l[8];
  float v[8] = {v0.x, v0.y, v0.z, v0.w, v1.x, v1.y, v1.z, v1.w};
#pragma unroll
  for (int i = 0; i < 8; ++i) {
    h[i] = f2bf(v[i]);
    l[i] = f2bf(v[i] - bf2f(h[i]));
  }
  *reinterpret_cast<short4*>(hi + base)     = make_short4(h[0], h[1], h[2], h[3]);
  *reinterpret_cast<short4*>(hi + base + 4) = make_short4(h[4], h[5], h[6], h[7]);
  *reinterpret_cast<short4*>(lo + base)     = make_short4(l[0], l[1], l[2], l[3]);
  *reinterpret_cast<short4*>(lo + base + 4) = make_short4(l[4], l[5], l[6], l[7]);
}

// ---------- split-bf16 MFMA GEMM (generic): C = A@B^T + bias (+resid) ----------
template<int BNF>
__global__ __launch_bounds__(256) void gemm_split(const short* __restrict__ Ah, const short* __restrict__ Al,
    const short* __restrict__ Bh, const short* __restrict__ Bl,
    const float* __restrict__ bias, const float* __restrict__ resid, float* __restrict__ C,
    int N, int K) {
  constexpr int BN = 32 * BNF;
  __shared__ __align__(16) short AsH[128 * 32];
  __shared__ __align__(16) short AsL[128 * 32];
  __shared__ __align__(16) short BsH[BN * 32];
  __shared__ __align__(16) short BsL[BN * 32];
  const int n0 = blockIdx.x * BN, m0 = blockIdx.y * 128;
  const int tid = threadIdx.x;
  const int lane = tid & 63, w = tid >> 6;
  const int quad = lane >> 4, l15 = lane & 15;
  const int wm = (w & 1) * 64, wn = (w >> 1) * 16 * BNF;
  const int sr = tid >> 2, sc = (tid & 3) * 8;
  const short* Ahp = Ah + (size_t)(m0 + sr) * K;
  const short* Alp = Al + (size_t)(m0 + sr) * K;
  const short* Bhp = Bh + (size_t)(n0 + sr) * K;
  const short* Blp = Bl + (size_t)(n0 + sr) * K;
  f32x4 acc[4][BNF];
#pragma unroll
  for (int i = 0; i < 4; ++i)
#pragma unroll
    for (int j = 0; j < BNF; ++j) acc[i][j] = (f32x4){0.f, 0.f, 0.f, 0.f};
  for (int kt = 0; kt < K; kt += 32) {
    GLOAD_LDS16(Ahp + kt + sc,                  &AsH[tid * 8]);
    GLOAD_LDS16(Ahp + (size_t)64 * K + kt + sc, &AsH[2048 + tid * 8]);
    GLOAD_LDS16(Alp + kt + sc,                  &AsL[tid * 8]);
    GLOAD_LDS16(Alp + (size_t)64 * K + kt + sc, &AsL[2048 + tid * 8]);
    GLOAD_LDS16(Bhp + kt + sc,                  &BsH[tid * 8]);
    GLOAD_LDS16(Blp + kt + sc,                  &BsL[tid * 8]);
    if (BNF == 4) {
      GLOAD_LDS16(Bhp + (size_t)64 * K + kt + sc, &BsH[2048 + tid * 8]);
      GLOAD_LDS16(Blp + (size_t)64 * K + kt + sc, &BsL[2048 + tid * 8]);
    }
    __syncthreads();
    bf16x8 ah[4], al[4], bh[BNF], bl[BNF];
#pragma unroll
    for (int i = 0; i < 4; ++i) {
      ah[i] = *reinterpret_cast<const bf16x8*>(&AsH[(wm + i * 16 + l15) * 32 + quad * 8]);
      al[i] = *reinterpret_cast<const bf16x8*>(&AsL[(wm + i * 16 + l15) * 32 + quad * 8]);
    }
#pragma unroll
    for (int j = 0; j < BNF; ++j) {
      bh[j] = *reinterpret_cast<const bf16x8*>(&BsH[(wn + j * 16 + l15) * 32 + quad * 8]);
      bl[j] = *reinterpret_cast<const bf16x8*>(&BsL[(wn + j * 16 + l15) * 32 + quad * 8]);
    }
#pragma unroll
    for (int i = 0; i < 4; ++i)
#pragma unroll
      for (int j = 0; j < BNF; ++j) {
        acc[i][j] = __builtin_amdgcn_mfma_f32_16x16x32_bf16(al[i], bh[j], acc[i][j], 0, 0, 0);
        acc[i][j] = __builtin_amdgcn_mfma_f32_16x16x32_bf16(ah[i], bl[j], acc[i][j], 0, 0, 0);
        acc[i][j] = __builtin_amdgcn_mfma_f32_16x16x32_bf16(ah[i], bh[j], acc[i][j], 0, 0, 0);
      }
    __syncthreads();
  }
#pragma unroll
  for (int i = 0; i < 4; ++i) {
#pragma unroll
    for (int reg = 0; reg < 4; ++reg) {
      const int row = m0 + wm + i * 16 + quad * 4 + reg;
#pragma unroll
      for (int j = 0; j < BNF; ++j) {
        const int col = n0 + wn + j * 16 + l15;
        float v = acc[i][j][reg] + bias[col];
        if (resid) v += resid[(size_t)row * N + col];
        C[(size_t)row * N + col] = v;
      }
    }
  }
}

// ---------- qkv GEMM: BM=128, BN=64, epilogue emits split planes ----------
// cols 0..1023 -> qk planes [token][1024]; cols 1024..1535 -> vt planes [(b*8+h)][64 d][1024 s]
__global__ __launch_bounds__(256) void gemm_split_qkv(const short* __restrict__ Ah, const short* __restrict__ Al,
    const short* __restrict__ Bh, const short* __restrict__ Bl, const float* __restrict__ bias,
    short* __restrict__ qkh, short* __restrict__ qkl, short* __restrict__ vh, short* __restrict__ vl) {
  const int K = DM;
  __shared__ __align__(16) short AsH[128 * 32];
  __shared__ __align__(16) short AsL[128 * 32];
  __shared__ __align__(16) short BsH[64 * 32];
  __shared__ __align__(16) short BsL[64 * 32];
  const int n0 = blockIdx.x * 64, m0 = blockIdx.y * 128;
  const int tid = threadIdx.x;
  const int lane = tid & 63, w = tid >> 6;
  const int quad = lane >> 4, l15 = lane & 15;
  const int wm = (w & 1) * 64, wn = (w >> 1) * 32;
  const int sr = tid >> 2, sc = (tid & 3) * 8;
  const short* Ahp = Ah + (size_t)(m0 + sr) * K;
  const short* Alp = Al + (size_t)(m0 + sr) * K;
  const short* Bhp = Bh + (size_t)(n0 + sr) * K;
  const short* Blp = Bl + (size_t)(n0 + sr) * K;
  f32x4 acc[4][2];
#pragma unroll
  for (int i = 0; i < 4; ++i)
#pragma unroll
    for (int j = 0; j < 2; ++j) acc[i][j] = (f32x4){0.f, 0.f, 0.f, 0.f};
  for (int kt = 0; kt < K; kt += 32) {
    GLOAD_LDS16(Ahp + kt + sc,                  &AsH[tid * 8]);
    GLOAD_LDS16(Ahp + (size_t)64 * K + kt + sc, &AsH[2048 + tid * 8]);
    GLOAD_LDS16(Alp + kt + sc,                  &AsL[tid * 8]);
    GLOAD_LDS16(Alp + (size_t)64 * K + kt + sc, &AsL[2048 + tid * 8]);
    GLOAD_LDS16(Bhp + kt + sc,                  &BsH[tid * 8]);
    GLOAD_LDS16(Blp + kt + sc,                  &BsL[tid * 8]);
    __syncthreads();
    bf16x8 ah[4], al[4], bh[2], bl[2];
#pragma unroll
    for (int i = 0; i < 4; ++i) {
      ah[i] = *reinterpret_cast<const bf16x8*>(&AsH[(wm + i * 16 + l15) * 32 + quad * 8]);
      al[i] = *reinterpret_cast<const bf16x8*>(&AsL[(wm + i * 16 + l15) * 32 + quad * 8]);
    }
#pragma unroll
    for (int j = 0; j < 2; ++j) {
      bh[j] = *reinterpret_cast<const bf16x8*>(&BsH[(wn + j * 16 + l15) * 32 + quad * 8]);
      bl[j] = *reinterpret_cast<const bf16x8*>(&BsL[(wn + j * 16 + l15) * 32 + quad * 8]);
    }
#pragma unroll
    for (int i = 0; i < 4; ++i)
#pragma unroll
      for (int j = 0; j < 2; ++j) {
        acc[i][j] = __builtin_amdgcn_mfma_f32_16x16x32_bf16(al[i], bh[j], acc[i][j], 0, 0, 0);
        acc[i][j] = __builtin_amdgcn_mfma_f32_16x16x32_bf16(ah[i], bl[j], acc[i][j], 0, 0, 0);
        acc[i][j] = __builtin_amdgcn_mfma_f32_16x16x32_bf16(ah[i], bh[j], acc[i][j], 0, 0, 0);
      }
    __syncthreads();
  }
  if (n0 < 1024) {
    // Q/K -> qk planes [token][1024]
#pragma unroll
    for (int i = 0; i < 4; ++i) {
#pragma unroll
      for (int reg = 0; reg < 4; ++reg) {
        const int row = m0 + wm + i * 16 + quad * 4 + reg;
#pragma unroll
        for (int j = 0; j < 2; ++j) {
          const int col = n0 + wn + j * 16 + l15;
          float v = acc[i][j][reg] + bias[col];
          short hv = f2bf(v);
          size_t ad = (size_t)row * 1024 + col;
          qkh[ad] = hv;
          qkl[ad] = f2bf(v - bf2f(hv));
        }
      }
    }
  } else {
    // V -> transposed planes vt[(b*8+h)*64 + d][1024 s]
#pragma unroll
    for (int i = 0; i < 4; ++i) {
      const int row0 = m0 + wm + i * 16 + quad * 4;
      const int bb = row0 >> 10, s0 = row0 & 1023;
#pragma unroll
      for (int j = 0; j < 2; ++j) {
        const int col = n0 + wn + j * 16 + l15;
        const int c2 = col - 1024;
        const int hhd = c2 >> 6, d = c2 & 63;
        const float bc = bias[col];
        float v0 = acc[i][j][0] + bc, v1 = acc[i][j][1] + bc, v2 = acc[i][j][2] + bc, v3 = acc[i][j][3] + bc;
        short4 hv = make_short4(f2bf(v0), f2bf(v1), f2bf(v2), f2bf(v3));
        short4 lv = make_short4(f2bf(v0 - bf2f(hv.x)), f2bf(v1 - bf2f(hv.y)),
                                f2bf(v2 - bf2f(hv.z)), f2bf(v3 - bf2f(hv.w)));
        size_t ad = ((size_t)(bb * 8 + hhd) * 64 + d) * 1024 + s0;
        *reinterpret_cast<short4*>(vh + ad) = hv;
        *reinterpret_cast<short4*>(vl + ad) = lv;
      }
    }
  }
}

// ---------- MFMA flash attention, split-S over KV. grid (16 qt, 8 h, 8 = b*2+ks) ----------
// Writes unnormalized partial O (fp32) + (m,l) per row.
__global__ __launch_bounds__(256) void attn_mfma(const short* __restrict__ qkh, const short* __restrict__ qkl,
    const short* __restrict__ vth, const short* __restrict__ vtl,
    float* __restrict__ opart, float* __restrict__ ml) {
  const int qt = blockIdx.x, hh = blockIdx.y;
  const int b = blockIdx.z >> 1, ks = blockIdx.z & 1;
  __shared__ __align__(16) short Qh[4096], Ql[4096], Kh[4096], Kl[4096], Vh[4096], Vl[4096];
  const int tid = threadIdx.x;
  const int lane = tid & 63, w = tid >> 6;
  const int quad = lane >> 4, l15 = lane & 15;
  const int tok0 = b * SEQ + qt * 64;
  const int srow = tid >> 2, schunk = (tid & 3) * 8;
  {
    const size_t qa = (size_t)(tok0 + srow) * 1024 + hh * 64 + schunk;
    GLOAD_LDS16(qkh + qa,      &Qh[tid * 8]);
    GLOAD_LDS16(qkh + qa + 32, &Qh[2048 + tid * 8]);
    GLOAD_LDS16(qkl + qa,      &Ql[tid * 8]);
    GLOAD_LDS16(qkl + qa + 32, &Ql[2048 + tid * 8]);
  }
  __syncthreads();
  bf16x8 qfh[2], qfl[2];
#pragma unroll
  for (int kk = 0; kk < 2; ++kk) {
    qfh[kk] = *reinterpret_cast<const bf16x8*>(&Qh[kk * 2048 + (w * 16 + l15) * 32 + quad * 8]);
    qfl[kk] = *reinterpret_cast<const bf16x8*>(&Ql[kk * 2048 + (w * 16 + l15) * 32 + quad * 8]);
  }
  f32x4 oacc[4];
  float m_run[4], l_run[4];
#pragma unroll
  for (int r = 0; r < 4; ++r) { oacc[r] = (f32x4){0.f, 0.f, 0.f, 0.f}; m_run[r] = -1e30f; l_run[r] = 0.f; }
  const size_t kbase = (size_t)(b * SEQ) * 1024 + 512 + hh * 64;
  const size_t vbase = (size_t)(b * 8 + hh) * 64 * 1024;
  for (int kc = ks * 8; kc < ks * 8 + 8; ++kc) {
    const size_t ka = kbase + (size_t)(kc * 64 + srow) * 1024 + schunk;
    GLOAD_LDS16(qkh + ka,      &Kh[tid * 8]);
    GLOAD_LDS16(qkh + ka + 32, &Kh[2048 + tid * 8]);
    GLOAD_LDS16(qkl + ka,      &Kl[tid * 8]);
    GLOAD_LDS16(qkl + ka + 32, &Kl[2048 + tid * 8]);
    const size_t va = vbase + (size_t)srow * 1024 + kc * 64 + schunk;
    GLOAD_LDS16(vth + va,      &Vh[tid * 8]);
    GLOAD_LDS16(vth + va + 32, &Vh[2048 + tid * 8]);
    GLOAD_LDS16(vtl + va,      &Vl[tid * 8]);
    GLOAD_LDS16(vtl + va + 32, &Vl[2048 + tid * 8]);
    __syncthreads();
    f32x4 s[4];
#pragma unroll
    for (int j = 0; j < 4; ++j) s[j] = (f32x4){0.f, 0.f, 0.f, 0.f};
#pragma unroll
    for (int kk = 0; kk < 2; ++kk)
#pragma unroll
      for (int j = 0; j < 4; ++j) {
        bf16x8 kfh = *reinterpret_cast<const bf16x8*>(&Kh[kk * 2048 + (j * 16 + l15) * 32 + quad * 8]);
        bf16x8 kfl = *reinterpret_cast<const bf16x8*>(&Kl[kk * 2048 + (j * 16 + l15) * 32 + quad * 8]);
        s[j] = __builtin_amdgcn_mfma_f32_16x16x32_bf16(qfl[kk], kfh, s[j], 0, 0, 0);
        s[j] = __builtin_amdgcn_mfma_f32_16x16x32_bf16(qfh[kk], kfl, s[j], 0, 0, 0);
        s[j] = __builtin_amdgcn_mfma_f32_16x16x32_bf16(qfh[kk], kfh, s[j], 0, 0, 0);
      }
    __syncthreads();
    float pv[4][4], alpha[4];
#pragma unroll
    for (int reg = 0; reg < 4; ++reg) {
      float mc = fmaxf(fmaxf(s[0][reg], s[1][reg]), fmaxf(s[2][reg], s[3][reg]));
#pragma unroll
      for (int msk = 1; msk < 16; msk <<= 1) mc = fmaxf(mc, __shfl_xor(mc, msk, 64));
      mc *= 0.125f;
      float mn = fmaxf(m_run[reg], mc);
      alpha[reg] = expf(m_run[reg] - mn);
      m_run[reg] = mn;
      float pl = 0.f;
#pragma unroll
      for (int j = 0; j < 4; ++j) { float pp = expf(s[j][reg] * 0.125f - mn); pv[j][reg] = pp; pl += pp; }
#pragma unroll
      for (int msk = 1; msk < 16; msk <<= 1) pl += __shfl_xor(pl, msk, 64);
      l_run[reg] = l_run[reg] * alpha[reg] + pl;
    }
#pragma unroll
    for (int j = 0; j < 4; ++j) {
      oacc[j][0] *= alpha[0]; oacc[j][1] *= alpha[1]; oacc[j][2] *= alpha[2]; oacc[j][3] *= alpha[3];
    }
#pragma unroll
    for (int j = 0; j < 4; ++j) {
      const int cad = (j >> 1) * 2048 + (j & 1) * 16 + l15;
#pragma unroll
      for (int reg = 0; reg < 4; ++reg) {
        const int ad = cad + (w * 16 + quad * 4 + reg) * 32;
        float p = pv[j][reg];
        short hp = f2bf(p);
        Kh[ad] = hp;
        Kl[ad] = f2bf(p - bf2f(hp));
      }
    }
#pragma unroll
    for (int kk = 0; kk < 2; ++kk) {
      bf16x8 pfh = *reinterpret_cast<const bf16x8*>(&Kh[kk * 2048 + (w * 16 + l15) * 32 + quad * 8]);
      bf16x8 pfl = *reinterpret_cast<const bf16x8*>(&Kl[kk * 2048 + (w * 16 + l15) * 32 + quad * 8]);
#pragma unroll
      for (int j = 0; j < 4; ++j) {
        bf16x8 vfh = *reinterpret_cast<const bf16x8*>(&Vh[kk * 2048 + (j * 16 + l15) * 32 + quad * 8]);
        bf16x8 vfl = *reinterpret_cast<const bf16x8*>(&Vl[kk * 2048 + (j * 16 + l15) * 32 + quad * 8]);
        oacc[j] = __builtin_amdgcn_mfma_f32_16x16x32_bf16(pfl, vfh, oacc[j], 0, 0, 0);
        oacc[j] = __builtin_amdgcn_mfma_f32_16x16x32_bf16(pfh, vfl, oacc[j], 0, 0, 0);
        oacc[j] = __builtin_amdgcn_mfma_f32_16x16x32_bf16(pfh, vfh, oacc[j], 0, 0, 0);
      }
    }
    __syncthreads();
  }
  float* op = opart + (size_t)ks * 2097152;
#pragma unroll
  for (int reg = 0; reg < 4; ++reg) {
    const int rloc = w * 16 + quad * 4 + reg;
#pragma unroll
    for (int j = 0; j < 4; ++j)
      op[(size_t)(tok0 + rloc) * 512 + hh * 64 + j * 16 + l15] = oacc[j][reg];
    if (l15 == 0) {
      size_t mli = (((size_t)ks * 32 + b * 8 + hh) * 1024 + qt * 64 + rloc) * 2;
      ml[mli] = m_run[reg];
      ml[mli + 1] = l_run[reg];
    }
  }
}

// combine the two KV-half partials -> split attn_o planes
__global__ __launch_bounds__(64) void combine_attn(const float* __restrict__ opart, const float* __restrict__ ml,
    short* __restrict__ oh, short* __restrict__ ol) {
  const int t = blockIdx.x;
  const int b = t >> 10, s = t & 1023;
  const int tid = threadIdx.x;
#pragma unroll
  for (int hh = 0; hh < 8; ++hh) {
    size_t mli = (((size_t)(b * 8 + hh)) * 1024 + s) * 2;
    float m0 = ml[mli], l0 = ml[mli + 1];
    float m1 = ml[65536 + mli], l1 = ml[65536 + mli + 1];
    float mm = fmaxf(m0, m1);
    float a0 = expf(m0 - mm), a1 = expf(m1 - mm);
    float inv = 1.f / (l0 * a0 + l1 * a1);
    size_t ad = (size_t)t * 512 + hh * 64 + tid;
    float v = (opart[ad] * a0 + opart[2097152 + ad] * a1) * inv;
    short hv = f2bf(v);
    oh[ad] = hv;
    ol[ad] = f2bf(v - bf2f(hv));
  }
}

// ---------- fused LN1 + router logits + softmax + argmax. one wave per token ----------
__global__ __launch_bounds__(64) void ln_router(const float* __restrict__ r1,
    const float* __restrict__ g, const float* __restrict__ bta, const float* __restrict__ rw,
    float* __restrict__ h, float* __restrict__ rlog, float* __restrict__ probs, int* __restrict__ am) {
  const int t = blockIdx.x, tid = threadIdx.x;
  const size_t base = (size_t)t * DM + tid * 8;
  float4 v0 = *reinterpret_cast<const float4*>(r1 + base);
  float4 v1 = *reinterpret_cast<const float4*>(r1 + base + 4);
  float s = v0.x+v0.y+v0.z+v0.w + v1.x+v1.y+v1.z+v1.w;
  float q = v0.x*v0.x+v0.y*v0.y+v0.z*v0.z+v0.w*v0.w + v1.x*v1.x+v1.y*v1.y+v1.z*v1.z+v1.w*v1.w;
#pragma unroll
  for (int m = 1; m < 64; m <<= 1) { s += __shfl_xor(s, m, 64); q += __shfl_xor(q, m, 64); }
  float mean = s * (1.0f/512.0f);
  float var = q * (1.0f/512.0f) - mean * mean;
  float rs = rsqrtf(var + 1e-5f);
  float4 g0 = *reinterpret_cast<const float4*>(g + tid*8);
  float4 g1 = *reinterpret_cast<const float4*>(g + tid*8 + 4);
  float4 b0 = *reinterpret_cast<const float4*>(bta + tid*8);
  float4 b1 = *reinterpret_cast<const float4*>(bta + tid*8 + 4);
  float hv[8];
  hv[0] = (v0.x-mean)*rs*g0.x+b0.x; hv[1] = (v0.y-mean)*rs*g0.y+b0.y;
  hv[2] = (v0.z-mean)*rs*g0.z+b0.z; hv[3] = (v0.w-mean)*rs*g0.w+b0.w;
  hv[4] = (v1.x-mean)*rs*g1.x+b1.x; hv[5] = (v1.y-mean)*rs*g1.y+b1.y;
  hv[6] = (v1.z-mean)*rs*g1.z+b1.z; hv[7] = (v1.w-mean)*rs*g1.w+b1.w;
  *reinterpret_cast<float4*>(h + base)     = make_float4(hv[0], hv[1], hv[2], hv[3]);
  *reinterpret_cast<float4*>(h + base + 4) = make_float4(hv[4], hv[5], hv[6], hv[7]);
  // logits: lane owns rows tid*8..tid*8+7 of rw [512][8]
  float lg[8] = {0.f,0.f,0.f,0.f,0.f,0.f,0.f,0.f};
  const float* rwp = rw + tid * 64;
#pragma unroll
  for (int r = 0; r < 8; ++r) {
    float4 w0 = *reinterpret_cast<const float4*>(rwp + r * 8);
    float4 w1 = *reinterpret_cast<const float4*>(rwp + r * 8 + 4);
    float hr = hv[r];
    lg[0] += hr * w0.x; lg[1] += hr * w0.y; lg[2] += hr * w0.z; lg[3] += hr * w0.w;
    lg[4] += hr * w1.x; lg[5] += hr * w1.y; lg[6] += hr * w1.z; lg[7] += hr * w1.w;
  }
#pragma unroll
  for (int m = 1; m < 64; m <<= 1) {
#pragma unroll
    for (int e = 0; e < 8; ++e) lg[e] += __shfl_xor(lg[e], m, 64);
  }
  int best = 0; float bv = lg[0];
#pragma unroll
  for (int e = 1; e < 8; ++e) if (lg[e] > bv) { bv = lg[e]; best = e; }
  float se = 0.f;
#pragma unroll
  for (int e = 0; e < 8; ++e) se += expf(lg[e] - bv);
  float inv = 1.f / se;
  if (tid < 8) {
    rlog[t * 8 + tid] = lg[tid];
    probs[t * 8 + tid] = expf(lg[tid] - bv) * inv;
  }
  if (tid == 0) am[t] = best;
}

// LN2 with capacity-guarded MoE add (replaces memset on moebuf)
__global__ __launch_bounds__(64) void ln2_kernel(const float* __restrict__ x, const float* __restrict__ add,
    const int* __restrict__ pos, const int* __restrict__ capp,
    const float* __restrict__ g, const float* __restrict__ bta, float* __restrict__ y) {
  const int t = blockIdx.x, tid = threadIdx.x;
  const size_t base = (size_t)t * DM + tid * 8;
  float4 v0 = *reinterpret_cast<const float4*>(x + base);
  float4 v1 = *reinterpret_cast<const float4*>(x + base + 4);
  if (pos[t] <= *capp) {
    float4 a0 = *reinterpret_cast<const float4*>(add + base);
    float4 a1 = *reinterpret_cast<const float4*>(add + base + 4);
    v0.x += a0.x; v0.y += a0.y; v0.z += a0.z; v0.w += a0.w;
    v1.x += a1.x; v1.y += a1.y; v1.z += a1.z; v1.w += a1.w;
  }
  float s = v0.x+v0.y+v0.z+v0.w + v1.x+v1.y+v1.z+v1.w;
  float q = v0.x*v0.x+v0.y*v0.y+v0.z*v0.z+v0.w*v0.w + v1.x*v1.x+v1.y*v1.y+v1.z*v1.z+v1.w*v1.w;
#pragma unroll
  for (int m = 1; m < 64; m <<= 1) { s += __shfl_xor(s, m, 64); q += __shfl_xor(q, m, 64); }
  float mean = s * (1.0f/512.0f);
  float var = q * (1.0f/512.0f) - mean * mean;
  float rs = rsqrtf(var + 1e-5f);
  float4 g0 = *reinterpret_cast<const float4*>(g + tid*8);
  float4 g1 = *reinterpret_cast<const float4*>(g + tid*8 + 4);
  float4 b0 = *reinterpret_cast<const float4*>(bta + tid*8);
  float4 b1 = *reinterpret_cast<const float4*>(bta + tid*8 + 4);
  float4 o0 = make_float4((v0.x-mean)*rs*g0.x+b0.x, (v0.y-mean)*rs*g0.y+b0.y,
                          (v0.z-mean)*rs*g0.z+b0.z, (v0.w-mean)*rs*g0.w+b0.w);
  float4 o1 = make_float4((v1.x-mean)*rs*g1.x+b1.x, (v1.y-mean)*rs*g1.y+b1.y,
                          (v1.z-mean)*rs*g1.z+b1.z, (v1.w-mean)*rs*g1.w+b1.w);
  *reinterpret_cast<float4*>(y + base) = o0;
  *reinterpret_cast<float4*>(y + base + 4) = o1;
}

__global__ __launch_bounds__(256) void scan_kernel(const int* __restrict__ am, const float* __restrict__ probs,
    const int* __restrict__ capp, float* __restrict__ emask, int* __restrict__ pos, int* __restrict__ cnt) {
  const int bx = blockIdx.x;
  const int b = bx >> 3, e = bx & 7;
  const int tid = threadIdx.x;
  const int cap = *capp;
  __shared__ int arr[256];
  const int s_base = tid * 4;
  int f[4], incl[4];
  int c = 0;
#pragma unroll
  for (int i = 0; i < 4; ++i) {
    f[i] = (am[b * SEQ + s_base + i] == e) ? 1 : 0;
    c += f[i]; incl[i] = c;
  }
  arr[tid] = c;
  __syncthreads();
  for (int off = 1; off < 256; off <<= 1) {
    int v = (tid >= off) ? arr[tid - off] : 0;
    __syncthreads();
    arr[tid] += v;
    __syncthreads();
  }
  int excl = arr[tid] - c;
  int tot = arr[255];
#pragma unroll
  for (int i = 0; i < 4; ++i) {
    int token = b * SEQ + s_base + i;
    int p = excl + incl[i];
    bool kept = f[i] && (p <= cap);
    emask[(size_t)token * NE + e] = kept ? probs[token * NE + e] : 0.f;
    if (f[i]) pos[token] = p;
  }
  if (tid == 0) cnt[bx] = (tot < cap) ? tot : cap;
}

__global__ __launch_bounds__(64) void offsets_kernel(const int* __restrict__ cnt, int* __restrict__ offbe,
    int* __restrict__ total) {
  int e = threadIdx.x;
  if (e < NE) {
    int run = 0;
    for (int b = 0; b < 4; ++b) { offbe[b * NE + e] = run; run += cnt[b * NE + e]; }
    total[e] = run;
  }
}

// ---------- bf16 MoE FFN path ----------
__global__ __launch_bounds__(256) void transpose_bf16(const float* __restrict__ W, short* __restrict__ Wt,
    int K, int N) {
  __shared__ float T[32][33];
  const float* We = W + (size_t)blockIdx.z * K * N;
  short* Wte = Wt + (size_t)blockIdx.z * K * N;
  const int k0 = blockIdx.y * 32, n0 = blockIdx.x * 32;
  const int r = threadIdx.x >> 3, c4 = (threadIdx.x & 7) * 4;
  float4 v = *reinterpret_cast<const float4*>(&We[(size_t)(k0 + r) * N + n0 + c4]);
  T[r][c4+0] = v.x; T[r][c4+1] = v.y; T[r][c4+2] = v.z; T[r][c4+3] = v.w;
  __syncthreads();
  short4 o;
  o.x = f2bf(T[c4+0][r]); o.y = f2bf(T[c4+1][r]); o.z = f2bf(T[c4+2][r]); o.w = f2bf(T[c4+3][r]);
  *reinterpret_cast<short4*>(&Wte[(size_t)(n0 + r) * K + k0 + c4]) = o;
}

__global__ __launch_bounds__(128) void gather_kernel(const float* __restrict__ h, const int* __restrict__ am,
    const int* __restrict__ pos, const int* __restrict__ capp, const int* __restrict__ offbe,
    const float* __restrict__ probs, short* __restrict__ Gb, int* __restrict__ tok, float* __restrict__ mscale) {
  const int t = blockIdx.x;
  const int b = t >> 10;
  const int e = am[t];
  const int p = pos[t];
  if (p > *capp) return;
  const int slot = offbe[b * NE + e] + p - 1;
  const int idx = e * 1024 + slot;
  if (threadIdx.x == 0) { tok[idx] = t; mscale[idx] = probs[t * NE + e]; }
  float4 v = *reinterpret_cast<const float4*>(h + (size_t)t * DM + threadIdx.x * 4);
  short4 o; o.x = f2bf(v.x); o.y = f2bf(v.y); o.z = f2bf(v.z); o.w = f2bf(v.w);
  *reinterpret_cast<short4*>(Gb + (size_t)idx * DM + threadIdx.x * 4) = o;
}

__global__ __launch_bounds__(256) void ffn1_mfma(const short* __restrict__ Gb, const short* __restrict__ wi_t,
    short* __restrict__ mid, const int* __restrict__ total) {
  const int e = blockIdx.z;
  const int tot = total[e];
  const int m0 = blockIdx.y * 128;
  if (m0 >= tot) return;
  const int n0 = blockIdx.x * 128;
  __shared__ __align__(16) short As[128 * 32];
  __shared__ __align__(16) short Bs[128 * 32];
  const short* A = Gb + ((size_t)e * 1024 + m0) * DM;
  const short* B = wi_t + (size_t)e * FF * DM + (size_t)n0 * DM;
  const int tid = threadIdx.x;
  const int lane = tid & 63, w = tid >> 6;
  const int quad = lane >> 4, l15 = lane & 15;
  const int wm = (w & 1) * 64, wn = (w >> 1) * 64;
  const int sr = tid >> 2, sc = (tid & 3) * 8;
  f32x4 acc[4][4];
#pragma unroll
  for (int i = 0; i < 4; ++i)
#pragma unroll
    for (int j = 0; j < 4; ++j) acc[i][j] = (f32x4){0.f, 0.f, 0.f, 0.f};
  for (int kt = 0; kt < DM; kt += 32) {
    GLOAD_LDS16(A + (size_t)sr * DM + kt + sc,        &As[tid * 8]);
    GLOAD_LDS16(A + (size_t)(sr + 64) * DM + kt + sc, &As[2048 + tid * 8]);
    GLOAD_LDS16(B + (size_t)sr * DM + kt + sc,        &Bs[tid * 8]);
    GLOAD_LDS16(B + (size_t)(sr + 64) * DM + kt + sc, &Bs[2048 + tid * 8]);
    __syncthreads();
    bf16x8 a[4], b[4];
#pragma unroll
    for (int i = 0; i < 4; ++i) a[i] = *reinterpret_cast<const bf16x8*>(&As[(wm + i * 16 + l15) * 32 + quad * 8]);
#pragma unroll
    for (int j = 0; j < 4; ++j) b[j] = *reinterpret_cast<const bf16x8*>(&Bs[(wn + j * 16 + l15) * 32 + quad * 8]);
#pragma unroll
    for (int i = 0; i < 4; ++i)
#pragma unroll
      for (int j = 0; j < 4; ++j)
        acc[i][j] = __builtin_amdgcn_mfma_f32_16x16x32_bf16(a[i], b[j], acc[i][j], 0, 0, 0);
    __syncthreads();
  }
#pragma unroll
  for (int i = 0; i < 4; ++i) {
#pragma unroll
    for (int reg = 0; reg < 4; ++reg) {
      int row = m0 + wm + i * 16 + quad * 4 + reg;
      short* outr = mid + ((size_t)e * 1024 + row) * FF;
#pragma unroll
      for (int j = 0; j < 4; ++j) {
        float v = acc[i][j][reg];
        float gl = 0.5f * v * (1.f + erff(v * 0.70710678118654752f));
        outr[n0 + wn + j * 16 + l15] = f2bf(gl);
      }
    }
  }
}

__global__ __launch_bounds__(256) void ffn2_mfma(const short* __restrict__ mid, const short* __restrict__ wo_t,
    const int* __restrict__ tok, const float* __restrict__ mscale, const int* __restrict__ total,
    float* __restrict__ moebuf) {
  const int e = blockIdx.z;
  const int tot = total[e];
  const int m0 = blockIdx.y * 128;
  if (m0 >= tot) return;
  const int n0 = blockIdx.x * 128;
  __shared__ __align__(16) short As[128 * 32];
  __shared__ __align__(16) short Bs[128 * 32];
  const short* A = mid + ((size_t)e * 1024 + m0) * FF;
  const short* B = wo_t + (size_t)e * DM * FF + (size_t)n0 * FF;
  const int tid = threadIdx.x;
  const int lane = tid & 63, w = tid >> 6;
  const int quad = lane >> 4, l15 = lane & 15;
  const int wm = (w & 1) * 64, wn = (w >> 1) * 64;
  const int sr = tid >> 2, sc = (tid & 3) * 8;
  f32x4 acc[4][4];
#pragma unroll
  for (int i = 0; i < 4; ++i)
#pragma unroll
    for (int j = 0; j < 4; ++j) acc[i][j] = (f32x4){0.f, 0.f, 0.f, 0.f};
  for (int kt = 0; kt < FF; kt += 32) {
    GLOAD_LDS16(A + (size_t)sr * FF + kt + sc,        &As[tid * 8]);
    GLOAD_LDS16(A + (size_t)(sr + 64) * FF + kt + sc, &As[2048 + tid * 8]);
    GLOAD_LDS16(B + (size_t)sr * FF + kt + sc,        &Bs[tid * 8]);
    GLOAD_LDS16(B + (size_t)(sr + 64) * FF + kt + sc, &Bs[2048 + tid * 8]);
    __syncthreads();
    bf16x8 a[4], b[4];
#pragma unroll
    for (int i = 0; i < 4; ++i) a[i] = *reinterpret_cast<const bf16x8*>(&As[(wm + i * 16 + l15) * 32 + quad * 8]);
#pragma unroll
    for (int j = 0; j < 4; ++j) b[j] = *reinterpret_cast<const bf16x8*>(&Bs[(wn + j * 16 + l15) * 32 + quad * 8]);
#pragma unroll
    for (int i = 0; i < 4; ++i)
#pragma unroll
      for (int j = 0; j < 4; ++j)
        acc[i][j] = __builtin_amdgcn_mfma_f32_16x16x32_bf16(a[i], b[j], acc[i][j], 0, 0, 0);
    __syncthreads();
  }
#pragma unroll
  for (int i = 0; i < 4; ++i) {
#pragma unroll
    for (int reg = 0; reg < 4; ++reg) {
      int slot = m0 + wm + i * 16 + quad * 4 + reg;
      if (slot < tot) {
        int idx = e * 1024 + slot;
        int t = tok[idx];
        float scv = mscale[idx];
        float* outr = moebuf + (size_t)t * DM + n0 + wn;
#pragma unroll
        for (int j = 0; j < 4; ++j) outr[j * 16 + l15] = scv * acc[i][j][reg];
      }
    }
  }
}

extern "C" void kernel_launch(void* const* d_in, const int* in_sizes, int n_in,
                              void* d_out, int out_size, void* d_ws, size_t ws_size,
                              hipStream_t stream) {
  const float* x     = (const float*)d_in[0];
  const float* in_w  = (const float*)d_in[1];
  const float* in_b  = (const float*)d_in[2];
  const float* out_w = (const float*)d_in[3];
  const float* out_b = (const float*)d_in[4];
  const float* ln1g  = (const float*)d_in[5];
  const float* ln1b  = (const float*)d_in[6];
  const float* ln2g  = (const float*)d_in[7];
  const float* ln2b  = (const float*)d_in[8];
  const float* rw    = (const float*)d_in[9];
  const float* wi    = (const float*)d_in[10];
  const float* wo    = (const float*)d_in[11];
  const int*   capp  = (const int*)d_in[12];

  float* ws = (float*)d_ws;
  short* qkh  = (short*)ws;                      // [0, 6291456) floats: qk/vt split planes
  short* qkl  = (short*)(ws + 2097152);
  short* vth  = (short*)(ws + 4194304);
  short* vtl  = (short*)(ws + 5242880);
  short* Gb16 = (short*)ws;                      // aliases qkh (post-attn)
  short* wi_t = (short*)(ws + 2097152);          // aliases qkl/vt (post-attn)
  float* moebuf = ws + 6291456;                  // 2,097,152
  float* r1     = ws + 8388608;                  // 2,097,152
  float* h      = ws + 10485760;                 // 2,097,152
  float* probs  = ws + 12582912;                 // 32,768
  short* wo_t   = (short*)(ws + 12615680);       // 8,388,608 shorts
  float* opart  = ws + 16809984;                 // 2 x 2,097,152 fp32 (aliases mid16 region, pre-FFN)
  float* mlbuf  = ws + 16809984 + 4194304;       // 131,072 fp32
  short* mid16  = (short*)(ws + 16809984);       // 16,777,216 shorts (FFN phase)
  float* mscale = ws + 25198592;
  int* am    = (int*)(ws + 25206784);
  int* pos   = am + NTOK;
  int* cnt   = pos + NTOK;
  int* offbe = cnt + 32;
  int* total = offbe + 32;
  int* tok   = total + 8;
  short* sAh = (short*)(ws + 25231360);          // 4096x512 shorts
  short* sAl = sAh + 2097152;
  short* sBh = sAl + 2097152;                    // 1536x512 shorts
  short* sBl = sBh + 786432;

  float* out   = (float*)d_out;
  float* rlog  = out + 2097152;
  float* emask = rlog + 32768;

  // 1. split x and in_proj_w
  split_kernel<<<1024, 256, 0, stream>>>(x, sAh, sAl);
  split_kernel<<<384, 256, 0, stream>>>(in_w, sBh, sBl);
  // 2. qkv GEMM -> split planes (BN=64, 768 blocks)
  gemm_split_qkv<<<dim3(24, 32), 256, 0, stream>>>(sAh, sAl, sBh, sBl, in_b, qkh, qkl, vth, vtl);
  // 3. split-S MFMA attention -> partials
  attn_mfma<<<dim3(16, 8, 8), 256, 0, stream>>>(qkh, qkl, vth, vtl, opart, mlbuf);
  // 4. combine partials -> split attn_o planes (sAh/sAl; x-split dead after step 2)
  combine_attn<<<NTOK, 64, 0, stream>>>(opart, mlbuf, sAh, sAl);
  // 5. split out_proj_w
  split_kernel<<<128, 256, 0, stream>>>(out_w, sBh, sBl);
  // 6. r1 = attn_o @ out_w^T + out_b + x
  gemm_split<2><<<dim3(8, 32), 256, 0, stream>>>(sAh, sAl, sBh, sBl, out_b, x, r1, DM, DM);
  // 7. FFN weight transposes (overwrite qk/vt planes; attn done)
  transpose_bf16<<<dim3(64, 16, 8), 256, 0, stream>>>(wi, wi_t, DM, FF);
  transpose_bf16<<<dim3(16, 64, 8), 256, 0, stream>>>(wo, wo_t, FF, DM);
  // 8. fused LN1 + router + softmax + argmax
  ln_router<<<NTOK, 64, 0, stream>>>(r1, ln1g, ln1b, rw, h, rlog, probs, am);
  // 9-10. capacity scan + offsets
  scan_kernel<<<32, 256, 0, stream>>>(am, probs, capp, emask, pos, cnt);
  offsets_kernel<<<1, 64, 0, stream>>>(cnt, offbe, total);
  // 11. gather kept tokens -> bf16
  gather_kernel<<<NTOK, 128, 0, stream>>>(h, am, pos, capp, offbe, probs, Gb16, tok, mscale);
  // 12-13. expert FFN (mid16 overwrites opart region; combine done)
  ffn1_mfma<<<dim3(16, 8, 8), 256, 0, stream>>>(Gb16, wi_t, mid16, total);
  ffn2_mfma<<<dim3(4, 8, 8), 256, 0, stream>>>(mid16, wo_t, tok, mscale, total, moebuf);
  // 14. out = LN2(h + kept?moebuf:0) — no memset needed
  ln2_kernel<<<NTOK, 64, 0, stream>>>(h, moebuf, pos, capp, ln2g, ln2b, out);
}

// Round 7
// 349.216 us; speedup vs baseline: 2.2900x; 1.0658x over previous
//
#include <hip/hip_runtime.h>
#include <math.h>

#define SEQ 1024
#define NTOK 4096
#define DM 512
#define FF 2048
#define NE 8

typedef __attribute__((ext_vector_type(8))) short bf16x8;
typedef __attribute__((ext_vector_type(4))) float f32x4;

__device__ __forceinline__ short f2bf(float f) {
  unsigned u = __float_as_uint(f);
  unsigned r = (u + 0x7FFFu + ((u >> 16) & 1u)) >> 16;
  return (short)r;
}
__device__ __forceinline__ float bf2f(short h) {
  return __uint_as_float(((unsigned)(unsigned short)h) << 16);
}

#define GLOAD_LDS16(g, l) __builtin_amdgcn_global_load_lds( \
    (const __attribute__((address_space(1))) void*)(g),     \
    (__attribute__((address_space(3))) void*)(l), 16, 0, 0)

// ---------- fused split of x, in_proj_w, out_proj_w -> (hi,lo) bf16 planes ----------
__global__ __launch_bounds__(256) void split3_kernel(
    const float* __restrict__ x, short* __restrict__ xh, short* __restrict__ xl,
    const float* __restrict__ w1, short* __restrict__ w1h, short* __restrict__ w1l,
    const float* __restrict__ w2, short* __restrict__ w2h, short* __restrict__ w2l) {
  const int bid = blockIdx.x;
  const float* src; short* hi; short* lo; size_t off;
  if (bid < 1024)      { src = x;  hi = xh;  lo = xl;  off = (size_t)bid * 2048; }
  else if (bid < 1408) { src = w1; hi = w1h; lo = w1l; off = (size_t)(bid - 1024) * 2048; }
  else                 { src = w2; hi = w2h; lo = w2l; off = (size_t)(bid - 1408) * 2048; }
  const size_t base = off + threadIdx.x * 8;
  float4 v0 = *reinterpret_cast<const float4*>(src + base);
  float4 v1 = *reinterpret_cast<const float4*>(src + base + 4);
  short h[8]; short l[8];
  float v[8] = {v0.x, v0.y, v0.z, v0.w, v1.x, v1.y, v1.z, v1.w};
#pragma unroll
  for (int i = 0; i < 8; ++i) {
    h[i] = f2bf(v[i]);
    l[i] = f2bf(v[i] - bf2f(h[i]));
  }
  *reinterpret_cast<short4*>(hi + base)     = make_short4(h[0], h[1], h[2], h[3]);
  *reinterpret_cast<short4*>(hi + base + 4) = make_short4(h[4], h[5], h[6], h[7]);
  *reinterpret_cast<short4*>(lo + base)     = make_short4(l[0], l[1], l[2], l[3]);
  *reinterpret_cast<short4*>(lo + base + 4) = make_short4(l[4], l[5], l[6], l[7]);
}

// ---------- split-bf16 MFMA GEMM: C = A@B^T + bias (+resid). BN = 32*BNF ----------
template<int BNF>
__global__ __launch_bounds__(256) void gemm_split(const short* __restrict__ Ah, const short* __restrict__ Al,
    const short* __restrict__ Bh, const short* __restrict__ Bl,
    const float* __restrict__ bias, const float* __restrict__ resid, float* __restrict__ C,
    int N, int K) {
  constexpr int BN = 32 * BNF;
  __shared__ __align__(16) short AsH[128 * 32];
  __shared__ __align__(16) short AsL[128 * 32];
  __shared__ __align__(16) short BsH[BN * 32];
  __shared__ __align__(16) short BsL[BN * 32];
  const int n0 = blockIdx.x * BN, m0 = blockIdx.y * 128;
  const int tid = threadIdx.x;
  const int lane = tid & 63, w = tid >> 6;
  const int quad = lane >> 4, l15 = lane & 15;
  const int wm = (w & 1) * 64, wn = (w >> 1) * 16 * BNF;
  const int sr = tid >> 2, sc = (tid & 3) * 8;
  const short* Ahp = Ah + (size_t)(m0 + sr) * K;
  const short* Alp = Al + (size_t)(m0 + sr) * K;
  const short* Bhp = Bh + (size_t)(n0 + sr) * K;
  const short* Blp = Bl + (size_t)(n0 + sr) * K;
  f32x4 acc[4][BNF];
#pragma unroll
  for (int i = 0; i < 4; ++i)
#pragma unroll
    for (int j = 0; j < BNF; ++j) acc[i][j] = (f32x4){0.f, 0.f, 0.f, 0.f};
  for (int kt = 0; kt < K; kt += 32) {
    GLOAD_LDS16(Ahp + kt + sc,                  &AsH[tid * 8]);
    GLOAD_LDS16(Ahp + (size_t)64 * K + kt + sc, &AsH[2048 + tid * 8]);
    GLOAD_LDS16(Alp + kt + sc,                  &AsL[tid * 8]);
    GLOAD_LDS16(Alp + (size_t)64 * K + kt + sc, &AsL[2048 + tid * 8]);
    if (BNF >= 2 || tid < 128) {
      GLOAD_LDS16(Bhp + kt + sc,                &BsH[tid * 8]);
      GLOAD_LDS16(Blp + kt + sc,                &BsL[tid * 8]);
    }
    if (BNF == 4) {
      GLOAD_LDS16(Bhp + (size_t)64 * K + kt + sc, &BsH[2048 + tid * 8]);
      GLOAD_LDS16(Blp + (size_t)64 * K + kt + sc, &BsL[2048 + tid * 8]);
    }
    __syncthreads();
    bf16x8 ah[4], al[4], bh[BNF], bl[BNF];
#pragma unroll
    for (int i = 0; i < 4; ++i) {
      ah[i] = *reinterpret_cast<const bf16x8*>(&AsH[(wm + i * 16 + l15) * 32 + quad * 8]);
      al[i] = *reinterpret_cast<const bf16x8*>(&AsL[(wm + i * 16 + l15) * 32 + quad * 8]);
    }
#pragma unroll
    for (int j = 0; j < BNF; ++j) {
      bh[j] = *reinterpret_cast<const bf16x8*>(&BsH[(wn + j * 16 + l15) * 32 + quad * 8]);
      bl[j] = *reinterpret_cast<const bf16x8*>(&BsL[(wn + j * 16 + l15) * 32 + quad * 8]);
    }
#pragma unroll
    for (int i = 0; i < 4; ++i)
#pragma unroll
      for (int j = 0; j < BNF; ++j) {
        acc[i][j] = __builtin_amdgcn_mfma_f32_16x16x32_bf16(al[i], bh[j], acc[i][j], 0, 0, 0);
        acc[i][j] = __builtin_amdgcn_mfma_f32_16x16x32_bf16(ah[i], bl[j], acc[i][j], 0, 0, 0);
        acc[i][j] = __builtin_amdgcn_mfma_f32_16x16x32_bf16(ah[i], bh[j], acc[i][j], 0, 0, 0);
      }
    __syncthreads();
  }
#pragma unroll
  for (int i = 0; i < 4; ++i) {
#pragma unroll
    for (int reg = 0; reg < 4; ++reg) {
      const int row = m0 + wm + i * 16 + quad * 4 + reg;
#pragma unroll
      for (int j = 0; j < BNF; ++j) {
        const int col = n0 + wn + j * 16 + l15;
        float v = acc[i][j][reg] + bias[col];
        if (resid) v += resid[(size_t)row * N + col];
        C[(size_t)row * N + col] = v;
      }
    }
  }
}

// ---------- qkv GEMM: BM=128, BN=64, epilogue emits split planes ----------
__global__ __launch_bounds__(256) void gemm_split_qkv(const short* __restrict__ Ah, const short* __restrict__ Al,
    const short* __restrict__ Bh, const short* __restrict__ Bl, const float* __restrict__ bias,
    short* __restrict__ qkh, short* __restrict__ qkl, short* __restrict__ vh, short* __restrict__ vl) {
  const int K = DM;
  __shared__ __align__(16) short AsH[128 * 32];
  __shared__ __align__(16) short AsL[128 * 32];
  __shared__ __align__(16) short BsH[64 * 32];
  __shared__ __align__(16) short BsL[64 * 32];
  const int n0 = blockIdx.x * 64, m0 = blockIdx.y * 128;
  const int tid = threadIdx.x;
  const int lane = tid & 63, w = tid >> 6;
  const int quad = lane >> 4, l15 = lane & 15;
  const int wm = (w & 1) * 64, wn = (w >> 1) * 32;
  const int sr = tid >> 2, sc = (tid & 3) * 8;
  const short* Ahp = Ah + (size_t)(m0 + sr) * K;
  const short* Alp = Al + (size_t)(m0 + sr) * K;
  const short* Bhp = Bh + (size_t)(n0 + sr) * K;
  const short* Blp = Bl + (size_t)(n0 + sr) * K;
  f32x4 acc[4][2];
#pragma unroll
  for (int i = 0; i < 4; ++i)
#pragma unroll
    for (int j = 0; j < 2; ++j) acc[i][j] = (f32x4){0.f, 0.f, 0.f, 0.f};
  for (int kt = 0; kt < K; kt += 32) {
    GLOAD_LDS16(Ahp + kt + sc,                  &AsH[tid * 8]);
    GLOAD_LDS16(Ahp + (size_t)64 * K + kt + sc, &AsH[2048 + tid * 8]);
    GLOAD_LDS16(Alp + kt + sc,                  &AsL[tid * 8]);
    GLOAD_LDS16(Alp + (size_t)64 * K + kt + sc, &AsL[2048 + tid * 8]);
    GLOAD_LDS16(Bhp + kt + sc,                  &BsH[tid * 8]);
    GLOAD_LDS16(Blp + kt + sc,                  &BsL[tid * 8]);
    __syncthreads();
    bf16x8 ah[4], al[4], bh[2], bl[2];
#pragma unroll
    for (int i = 0; i < 4; ++i) {
      ah[i] = *reinterpret_cast<const bf16x8*>(&AsH[(wm + i * 16 + l15) * 32 + quad * 8]);
      al[i] = *reinterpret_cast<const bf16x8*>(&AsL[(wm + i * 16 + l15) * 32 + quad * 8]);
    }
#pragma unroll
    for (int j = 0; j < 2; ++j) {
      bh[j] = *reinterpret_cast<const bf16x8*>(&BsH[(wn + j * 16 + l15) * 32 + quad * 8]);
      bl[j] = *reinterpret_cast<const bf16x8*>(&BsL[(wn + j * 16 + l15) * 32 + quad * 8]);
    }
#pragma unroll
    for (int i = 0; i < 4; ++i)
#pragma unroll
      for (int j = 0; j < 2; ++j) {
        acc[i][j] = __builtin_amdgcn_mfma_f32_16x16x32_bf16(al[i], bh[j], acc[i][j], 0, 0, 0);
        acc[i][j] = __builtin_amdgcn_mfma_f32_16x16x32_bf16(ah[i], bl[j], acc[i][j], 0, 0, 0);
        acc[i][j] = __builtin_amdgcn_mfma_f32_16x16x32_bf16(ah[i], bh[j], acc[i][j], 0, 0, 0);
      }
    __syncthreads();
  }
  if (n0 < 1024) {
#pragma unroll
    for (int i = 0; i < 4; ++i) {
#pragma unroll
      for (int reg = 0; reg < 4; ++reg) {
        const int row = m0 + wm + i * 16 + quad * 4 + reg;
#pragma unroll
        for (int j = 0; j < 2; ++j) {
          const int col = n0 + wn + j * 16 + l15;
          float v = acc[i][j][reg] + bias[col];
          short hv = f2bf(v);
          size_t ad = (size_t)row * 1024 + col;
          qkh[ad] = hv;
          qkl[ad] = f2bf(v - bf2f(hv));
        }
      }
    }
  } else {
#pragma unroll
    for (int i = 0; i < 4; ++i) {
      const int row0 = m0 + wm + i * 16 + quad * 4;
      const int bb = row0 >> 10, s0 = row0 & 1023;
#pragma unroll
      for (int j = 0; j < 2; ++j) {
        const int col = n0 + wn + j * 16 + l15;
        const int c2 = col - 1024;
        const int hhd = c2 >> 6, d = c2 & 63;
        const float bc = bias[col];
        float v0 = acc[i][j][0] + bc, v1 = acc[i][j][1] + bc, v2 = acc[i][j][2] + bc, v3 = acc[i][j][3] + bc;
        short4 hv = make_short4(f2bf(v0), f2bf(v1), f2bf(v2), f2bf(v3));
        short4 lv = make_short4(f2bf(v0 - bf2f(hv.x)), f2bf(v1 - bf2f(hv.y)),
                                f2bf(v2 - bf2f(hv.z)), f2bf(v3 - bf2f(hv.w)));
        size_t ad = ((size_t)(bb * 8 + hhd) * 64 + d) * 1024 + s0;
        *reinterpret_cast<short4*>(vh + ad) = hv;
        *reinterpret_cast<short4*>(vl + ad) = lv;
      }
    }
  }
}

// ---------- MFMA flash attention, split-S over KV, Q in registers (32 KB LDS) ----------
__global__ __launch_bounds__(256) void attn_mfma(const short* __restrict__ qkh, const short* __restrict__ qkl,
    const short* __restrict__ vth, const short* __restrict__ vtl,
    float* __restrict__ opart, float* __restrict__ ml) {
  const int qt = blockIdx.x, hh = blockIdx.y;
  const int b = blockIdx.z >> 1, ks = blockIdx.z & 1;
  __shared__ __align__(16) short Kh[4096], Kl[4096], Vh[4096], Vl[4096];
  const int tid = threadIdx.x;
  const int lane = tid & 63, w = tid >> 6;
  const int quad = lane >> 4, l15 = lane & 15;
  const int tok0 = b * SEQ + qt * 64;
  const int srow = tid >> 2, schunk = (tid & 3) * 8;
  // Q fragments straight from global (reused across all KV tiles)
  bf16x8 qfh[2], qfl[2];
  {
    const size_t qa = (size_t)(tok0 + w * 16 + l15) * 1024 + hh * 64 + quad * 8;
    qfh[0] = *reinterpret_cast<const bf16x8*>(qkh + qa);
    qfh[1] = *reinterpret_cast<const bf16x8*>(qkh + qa + 32);
    qfl[0] = *reinterpret_cast<const bf16x8*>(qkl + qa);
    qfl[1] = *reinterpret_cast<const bf16x8*>(qkl + qa + 32);
  }
  f32x4 oacc[4];
  float m_run[4], l_run[4];
#pragma unroll
  for (int r = 0; r < 4; ++r) { oacc[r] = (f32x4){0.f, 0.f, 0.f, 0.f}; m_run[r] = -1e30f; l_run[r] = 0.f; }
  const size_t kbase = (size_t)(b * SEQ) * 1024 + 512 + hh * 64;
  const size_t vbase = (size_t)(b * 8 + hh) * 64 * 1024;
  for (int kc = ks * 8; kc < ks * 8 + 8; ++kc) {
    const size_t ka = kbase + (size_t)(kc * 64 + srow) * 1024 + schunk;
    GLOAD_LDS16(qkh + ka,      &Kh[tid * 8]);
    GLOAD_LDS16(qkh + ka + 32, &Kh[2048 + tid * 8]);
    GLOAD_LDS16(qkl + ka,      &Kl[tid * 8]);
    GLOAD_LDS16(qkl + ka + 32, &Kl[2048 + tid * 8]);
    const size_t va = vbase + (size_t)srow * 1024 + kc * 64 + schunk;
    GLOAD_LDS16(vth + va,      &Vh[tid * 8]);
    GLOAD_LDS16(vth + va + 32, &Vh[2048 + tid * 8]);
    GLOAD_LDS16(vtl + va,      &Vl[tid * 8]);
    GLOAD_LDS16(vtl + va + 32, &Vl[2048 + tid * 8]);
    __syncthreads();
    f32x4 s[4];
#pragma unroll
    for (int j = 0; j < 4; ++j) s[j] = (f32x4){0.f, 0.f, 0.f, 0.f};
#pragma unroll
    for (int kk = 0; kk < 2; ++kk)
#pragma unroll
      for (int j = 0; j < 4; ++j) {
        bf16x8 kfh = *reinterpret_cast<const bf16x8*>(&Kh[kk * 2048 + (j * 16 + l15) * 32 + quad * 8]);
        bf16x8 kfl = *reinterpret_cast<const bf16x8*>(&Kl[kk * 2048 + (j * 16 + l15) * 32 + quad * 8]);
        s[j] = __builtin_amdgcn_mfma_f32_16x16x32_bf16(qfl[kk], kfh, s[j], 0, 0, 0);
        s[j] = __builtin_amdgcn_mfma_f32_16x16x32_bf16(qfh[kk], kfl, s[j], 0, 0, 0);
        s[j] = __builtin_amdgcn_mfma_f32_16x16x32_bf16(qfh[kk], kfh, s[j], 0, 0, 0);
      }
    __syncthreads();
    float pv[4][4], alpha[4];
#pragma unroll
    for (int reg = 0; reg < 4; ++reg) {
      float mc = fmaxf(fmaxf(s[0][reg], s[1][reg]), fmaxf(s[2][reg], s[3][reg]));
#pragma unroll
      for (int msk = 1; msk < 16; msk <<= 1) mc = fmaxf(mc, __shfl_xor(mc, msk, 64));
      mc *= 0.125f;
      float mn = fmaxf(m_run[reg], mc);
      alpha[reg] = expf(m_run[reg] - mn);
      m_run[reg] = mn;
      float pl = 0.f;
#pragma unroll
      for (int j = 0; j < 4; ++j) { float pp = expf(s[j][reg] * 0.125f - mn); pv[j][reg] = pp; pl += pp; }
#pragma unroll
      for (int msk = 1; msk < 16; msk <<= 1) pl += __shfl_xor(pl, msk, 64);
      l_run[reg] = l_run[reg] * alpha[reg] + pl;
    }
#pragma unroll
    for (int j = 0; j < 4; ++j) {
      oacc[j][0] *= alpha[0]; oacc[j][1] *= alpha[1]; oacc[j][2] *= alpha[2]; oacc[j][3] *= alpha[3];
    }
#pragma unroll
    for (int j = 0; j < 4; ++j) {
      const int cad = (j >> 1) * 2048 + (j & 1) * 16 + l15;
#pragma unroll
      for (int reg = 0; reg < 4; ++reg) {
        const int ad = cad + (w * 16 + quad * 4 + reg) * 32;
        float p = pv[j][reg];
        short hp = f2bf(p);
        Kh[ad] = hp;
        Kl[ad] = f2bf(p - bf2f(hp));
      }
    }
#pragma unroll
    for (int kk = 0; kk < 2; ++kk) {
      bf16x8 pfh = *reinterpret_cast<const bf16x8*>(&Kh[kk * 2048 + (w * 16 + l15) * 32 + quad * 8]);
      bf16x8 pfl = *reinterpret_cast<const bf16x8*>(&Kl[kk * 2048 + (w * 16 + l15) * 32 + quad * 8]);
#pragma unroll
      for (int j = 0; j < 4; ++j) {
        bf16x8 vfh = *reinterpret_cast<const bf16x8*>(&Vh[kk * 2048 + (j * 16 + l15) * 32 + quad * 8]);
        bf16x8 vfl = *reinterpret_cast<const bf16x8*>(&Vl[kk * 2048 + (j * 16 + l15) * 32 + quad * 8]);
        oacc[j] = __builtin_amdgcn_mfma_f32_16x16x32_bf16(pfl, vfh, oacc[j], 0, 0, 0);
        oacc[j] = __builtin_amdgcn_mfma_f32_16x16x32_bf16(pfh, vfl, oacc[j], 0, 0, 0);
        oacc[j] = __builtin_amdgcn_mfma_f32_16x16x32_bf16(pfh, vfh, oacc[j], 0, 0, 0);
      }
    }
    __syncthreads();
  }
  float* op = opart + (size_t)ks * 2097152;
#pragma unroll
  for (int reg = 0; reg < 4; ++reg) {
    const int rloc = w * 16 + quad * 4 + reg;
#pragma unroll
    for (int j = 0; j < 4; ++j)
      op[(size_t)(tok0 + rloc) * 512 + hh * 64 + j * 16 + l15] = oacc[j][reg];
    if (l15 == 0) {
      size_t mli = (((size_t)ks * 32 + b * 8 + hh) * 1024 + qt * 64 + rloc) * 2;
      ml[mli] = m_run[reg];
      ml[mli + 1] = l_run[reg];
    }
  }
}

// combine the two KV-half partials -> split attn_o planes
__global__ __launch_bounds__(64) void combine_attn(const float* __restrict__ opart, const float* __restrict__ ml,
    short* __restrict__ oh, short* __restrict__ ol) {
  const int t = blockIdx.x;
  const int b = t >> 10, s = t & 1023;
  const int tid = threadIdx.x;
#pragma unroll
  for (int hh = 0; hh < 8; ++hh) {
    size_t mli = (((size_t)(b * 8 + hh)) * 1024 + s) * 2;
    float m0 = ml[mli], l0 = ml[mli + 1];
    float m1 = ml[65536 + mli], l1 = ml[65536 + mli + 1];
    float mm = fmaxf(m0, m1);
    float a0 = expf(m0 - mm), a1 = expf(m1 - mm);
    float inv = 1.f / (l0 * a0 + l1 * a1);
    size_t ad = (size_t)t * 512 + hh * 64 + tid;
    float v = (opart[ad] * a0 + opart[2097152 + ad] * a1) * inv;
    short hv = f2bf(v);
    oh[ad] = hv;
    ol[ad] = f2bf(v - bf2f(hv));
  }
}

// ---------- fused LN1 + router logits + softmax + argmax ----------
__global__ __launch_bounds__(64) void ln_router(const float* __restrict__ r1,
    const float* __restrict__ g, const float* __restrict__ bta, const float* __restrict__ rw,
    float* __restrict__ h, float* __restrict__ rlog, float* __restrict__ probs, int* __restrict__ am) {
  const int t = blockIdx.x, tid = threadIdx.x;
  const size_t base = (size_t)t * DM + tid * 8;
  float4 v0 = *reinterpret_cast<const float4*>(r1 + base);
  float4 v1 = *reinterpret_cast<const float4*>(r1 + base + 4);
  float s = v0.x+v0.y+v0.z+v0.w + v1.x+v1.y+v1.z+v1.w;
  float q = v0.x*v0.x+v0.y*v0.y+v0.z*v0.z+v0.w*v0.w + v1.x*v1.x+v1.y*v1.y+v1.z*v1.z+v1.w*v1.w;
#pragma unroll
  for (int m = 1; m < 64; m <<= 1) { s += __shfl_xor(s, m, 64); q += __shfl_xor(q, m, 64); }
  float mean = s * (1.0f/512.0f);
  float var = q * (1.0f/512.0f) - mean * mean;
  float rs = rsqrtf(var + 1e-5f);
  float4 g0 = *reinterpret_cast<const float4*>(g + tid*8);
  float4 g1 = *reinterpret_cast<const float4*>(g + tid*8 + 4);
  float4 b0 = *reinterpret_cast<const float4*>(bta + tid*8);
  float4 b1 = *reinterpret_cast<const float4*>(bta + tid*8 + 4);
  float hv[8];
  hv[0] = (v0.x-mean)*rs*g0.x+b0.x; hv[1] = (v0.y-mean)*rs*g0.y+b0.y;
  hv[2] = (v0.z-mean)*rs*g0.z+b0.z; hv[3] = (v0.w-mean)*rs*g0.w+b0.w;
  hv[4] = (v1.x-mean)*rs*g1.x+b1.x; hv[5] = (v1.y-mean)*rs*g1.y+b1.y;
  hv[6] = (v1.z-mean)*rs*g1.z+b1.z; hv[7] = (v1.w-mean)*rs*g1.w+b1.w;
  *reinterpret_cast<float4*>(h + base)     = make_float4(hv[0], hv[1], hv[2], hv[3]);
  *reinterpret_cast<float4*>(h + base + 4) = make_float4(hv[4], hv[5], hv[6], hv[7]);
  float lg[8] = {0.f,0.f,0.f,0.f,0.f,0.f,0.f,0.f};
  const float* rwp = rw + tid * 64;
#pragma unroll
  for (int r = 0; r < 8; ++r) {
    float4 w0 = *reinterpret_cast<const float4*>(rwp + r * 8);
    float4 w1 = *reinterpret_cast<const float4*>(rwp + r * 8 + 4);
    float hr = hv[r];
    lg[0] += hr * w0.x; lg[1] += hr * w0.y; lg[2] += hr * w0.z; lg[3] += hr * w0.w;
    lg[4] += hr * w1.x; lg[5] += hr * w1.y; lg[6] += hr * w1.z; lg[7] += hr * w1.w;
  }
#pragma unroll
  for (int m = 1; m < 64; m <<= 1) {
#pragma unroll
    for (int e = 0; e < 8; ++e) lg[e] += __shfl_xor(lg[e], m, 64);
  }
  int best = 0; float bv = lg[0];
#pragma unroll
  for (int e = 1; e < 8; ++e) if (lg[e] > bv) { bv = lg[e]; best = e; }
  float se = 0.f;
#pragma unroll
  for (int e = 0; e < 8; ++e) se += expf(lg[e] - bv);
  float inv = 1.f / se;
  if (tid < 8) {
    rlog[t * 8 + tid] = lg[tid];
    probs[t * 8 + tid] = expf(lg[tid] - bv) * inv;
  }
  if (tid == 0) am[t] = best;
}

// LN2 with capacity-guarded MoE add
__global__ __launch_bounds__(64) void ln2_kernel(const float* __restrict__ x, const float* __restrict__ add,
    const int* __restrict__ pos, const int* __restrict__ capp,
    const float* __restrict__ g, const float* __restrict__ bta, float* __restrict__ y) {
  const int t = blockIdx.x, tid = threadIdx.x;
  const size_t base = (size_t)t * DM + tid * 8;
  float4 v0 = *reinterpret_cast<const float4*>(x + base);
  float4 v1 = *reinterpret_cast<const float4*>(x + base + 4);
  if (pos[t] <= *capp) {
    float4 a0 = *reinterpret_cast<const float4*>(add + base);
    float4 a1 = *reinterpret_cast<const float4*>(add + base + 4);
    v0.x += a0.x; v0.y += a0.y; v0.z += a0.z; v0.w += a0.w;
    v1.x += a1.x; v1.y += a1.y; v1.z += a1.z; v1.w += a1.w;
  }
  float s = v0.x+v0.y+v0.z+v0.w + v1.x+v1.y+v1.z+v1.w;
  float q = v0.x*v0.x+v0.y*v0.y+v0.z*v0.z+v0.w*v0.w + v1.x*v1.x+v1.y*v1.y+v1.z*v1.z+v1.w*v1.w;
#pragma unroll
  for (int m = 1; m < 64; m <<= 1) { s += __shfl_xor(s, m, 64); q += __shfl_xor(q, m, 64); }
  float mean = s * (1.0f/512.0f);
  float var = q * (1.0f/512.0f) - mean * mean;
  float rs = rsqrtf(var + 1e-5f);
  float4 g0 = *reinterpret_cast<const float4*>(g + tid*8);
  float4 g1 = *reinterpret_cast<const float4*>(g + tid*8 + 4);
  float4 b0 = *reinterpret_cast<const float4*>(bta + tid*8);
  float4 b1 = *reinterpret_cast<const float4*>(bta + tid*8 + 4);
  float4 o0 = make_float4((v0.x-mean)*rs*g0.x+b0.x, (v0.y-mean)*rs*g0.y+b0.y,
                          (v0.z-mean)*rs*g0.z+b0.z, (v0.w-mean)*rs*g0.w+b0.w);
  float4 o1 = make_float4((v1.x-mean)*rs*g1.x+b1.x, (v1.y-mean)*rs*g1.y+b1.y,
                          (v1.z-mean)*rs*g1.z+b1.z, (v1.w-mean)*rs*g1.w+b1.w);
  *reinterpret_cast<float4*>(y + base) = o0;
  *reinterpret_cast<float4*>(y + base + 4) = o1;
}

__global__ __launch_bounds__(256) void scan_kernel(const int* __restrict__ am, const float* __restrict__ probs,
    const int* __restrict__ capp, float* __restrict__ emask, int* __restrict__ pos, int* __restrict__ cnt) {
  const int bx = blockIdx.x;
  const int b = bx >> 3, e = bx & 7;
  const int tid = threadIdx.x;
  const int cap = *capp;
  __shared__ int arr[256];
  const int s_base = tid * 4;
  int f[4], incl[4];
  int c = 0;
#pragma unroll
  for (int i = 0; i < 4; ++i) {
    f[i] = (am[b * SEQ + s_base + i] == e) ? 1 : 0;
    c += f[i]; incl[i] = c;
  }
  arr[tid] = c;
  __syncthreads();
  for (int off = 1; off < 256; off <<= 1) {
    int v = (tid >= off) ? arr[tid - off] : 0;
    __syncthreads();
    arr[tid] += v;
    __syncthreads();
  }
  int excl = arr[tid] - c;
  int tot = arr[255];
#pragma unroll
  for (int i = 0; i < 4; ++i) {
    int token = b * SEQ + s_base + i;
    int p = excl + incl[i];
    bool kept = f[i] && (p <= cap);
    emask[(size_t)token * NE + e] = kept ? probs[token * NE + e] : 0.f;
    if (f[i]) pos[token] = p;
  }
  if (tid == 0) cnt[bx] = (tot < cap) ? tot : cap;
}

// ---------- fused weight transpose (wi + wo) ----------
__global__ __launch_bounds__(256) void transpose2_bf16(const float* __restrict__ wi, short* __restrict__ wi_t,
    const float* __restrict__ wo, short* __restrict__ wo_t) {
  __shared__ float T[32][33];
  const int z = blockIdx.z;
  const float* W; short* Wt; int K, N, k0, n0;
  if (z < 8) { W = wi + (size_t)z * DM * FF;      Wt = wi_t + (size_t)z * DM * FF;
               K = DM; N = FF; k0 = blockIdx.y * 32; n0 = blockIdx.x * 32; }
  else       { W = wo + (size_t)(z - 8) * FF * DM; Wt = wo_t + (size_t)(z - 8) * FF * DM;
               K = FF; N = DM; k0 = blockIdx.x * 32; n0 = blockIdx.y * 32; }
  const int r = threadIdx.x >> 3, c4 = (threadIdx.x & 7) * 4;
  float4 v = *reinterpret_cast<const float4*>(&W[(size_t)(k0 + r) * N + n0 + c4]);
  T[r][c4+0] = v.x; T[r][c4+1] = v.y; T[r][c4+2] = v.z; T[r][c4+3] = v.w;
  __syncthreads();
  short4 o;
  o.x = f2bf(T[c4+0][r]); o.y = f2bf(T[c4+1][r]); o.z = f2bf(T[c4+2][r]); o.w = f2bf(T[c4+3][r]);
  *reinterpret_cast<short4*>(&Wt[(size_t)(n0 + r) * K + k0 + c4]) = o;
}

// gather kept tokens (computes per-(b,e) offset from cnt inline)
__global__ __launch_bounds__(128) void gather_kernel(const float* __restrict__ h, const int* __restrict__ am,
    const int* __restrict__ pos, const int* __restrict__ capp, const int* __restrict__ cnt,
    const float* __restrict__ probs, short* __restrict__ Gb, int* __restrict__ tok, float* __restrict__ mscale) {
  const int t = blockIdx.x;
  const int b = t >> 10;
  const int e = am[t];
  const int p = pos[t];
  if (p > *capp) return;
  int off = 0;
  for (int b2 = 0; b2 < b; ++b2) off += cnt[b2 * 8 + e];
  const int slot = off + p - 1;
  const int idx = e * 1024 + slot;
  if (threadIdx.x == 0) { tok[idx] = t; mscale[idx] = probs[t * NE + e]; }
  float4 v = *reinterpret_cast<const float4*>(h + (size_t)t * DM + threadIdx.x * 4);
  short4 o; o.x = f2bf(v.x); o.y = f2bf(v.y); o.z = f2bf(v.z); o.w = f2bf(v.w);
  *reinterpret_cast<short4*>(Gb + (size_t)idx * DM + threadIdx.x * 4) = o;
}

__global__ __launch_bounds__(256) void ffn1_mfma(const short* __restrict__ Gb, const short* __restrict__ wi_t,
    short* __restrict__ mid, const int* __restrict__ cnt) {
  const int e = blockIdx.z;
  const int tot = cnt[e] + cnt[8 + e] + cnt[16 + e] + cnt[24 + e];
  const int m0 = blockIdx.y * 128;
  if (m0 >= tot) return;
  const int n0 = blockIdx.x * 128;
  __shared__ __align__(16) short As[128 * 32];
  __shared__ __align__(16) short Bs[128 * 32];
  const short* A = Gb + ((size_t)e * 1024 + m0) * DM;
  const short* B = wi_t + (size_t)e * FF * DM + (size_t)n0 * DM;
  const int tid = threadIdx.x;
  const int lane = tid & 63, w = tid >> 6;
  const int quad = lane >> 4, l15 = lane & 15;
  const int wm = (w & 1) * 64, wn = (w >> 1) * 64;
  const int sr = tid >> 2, sc = (tid & 3) * 8;
  f32x4 acc[4][4];
#pragma unroll
  for (int i = 0; i < 4; ++i)
#pragma unroll
    for (int j = 0; j < 4; ++j) acc[i][j] = (f32x4){0.f, 0.f, 0.f, 0.f};
  for (int kt = 0; kt < DM; kt += 32) {
    GLOAD_LDS16(A + (size_t)sr * DM + kt + sc,        &As[tid * 8]);
    GLOAD_LDS16(A + (size_t)(sr + 64) * DM + kt + sc, &As[2048 + tid * 8]);
    GLOAD_LDS16(B + (size_t)sr * DM + kt + sc,        &Bs[tid * 8]);
    GLOAD_LDS16(B + (size_t)(sr + 64) * DM + kt + sc, &Bs[2048 + tid * 8]);
    __syncthreads();
    bf16x8 a[4], b[4];
#pragma unroll
    for (int i = 0; i < 4; ++i) a[i] = *reinterpret_cast<const bf16x8*>(&As[(wm + i * 16 + l15) * 32 + quad * 8]);
#pragma unroll
    for (int j = 0; j < 4; ++j) b[j] = *reinterpret_cast<const bf16x8*>(&Bs[(wn + j * 16 + l15) * 32 + quad * 8]);
#pragma unroll
    for (int i = 0; i < 4; ++i)
#pragma unroll
      for (int j = 0; j < 4; ++j)
        acc[i][j] = __builtin_amdgcn_mfma_f32_16x16x32_bf16(a[i], b[j], acc[i][j], 0, 0, 0);
    __syncthreads();
  }
#pragma unroll
  for (int i = 0; i < 4; ++i) {
#pragma unroll
    for (int reg = 0; reg < 4; ++reg) {
      int row = m0 + wm + i * 16 + quad * 4 + reg;
      short* outr = mid + ((size_t)e * 1024 + row) * FF;
#pragma unroll
      for (int j = 0; j < 4; ++j) {
        float v = acc[i][j][reg];
        float gl = 0.5f * v * (1.f + erff(v * 0.70710678118654752f));
        outr[n0 + wn + j * 16 + l15] = f2bf(gl);
      }
    }
  }
}

// ffn2: BM=128, BN=64 (grid 8x8x8 = 512 blocks)
__global__ __launch_bounds__(256) void ffn2_mfma(const short* __restrict__ mid, const short* __restrict__ wo_t,
    const int* __restrict__ tok, const float* __restrict__ mscale, const int* __restrict__ cnt,
    float* __restrict__ moebuf) {
  const int e = blockIdx.z;
  const int tot = cnt[e] + cnt[8 + e] + cnt[16 + e] + cnt[24 + e];
  const int m0 = blockIdx.y * 128;
  if (m0 >= tot) return;
  const int n0 = blockIdx.x * 64;
  __shared__ __align__(16) short As[128 * 32];
  __shared__ __align__(16) short Bs[64 * 32];
  const short* A = mid + ((size_t)e * 1024 + m0) * FF;
  const short* B = wo_t + (size_t)e * DM * FF + (size_t)n0 * FF;
  const int tid = threadIdx.x;
  const int lane = tid & 63, w = tid >> 6;
  const int quad = lane >> 4, l15 = lane & 15;
  const int wm = (w & 1) * 64, wn = (w >> 1) * 32;
  const int sr = tid >> 2, sc = (tid & 3) * 8;
  f32x4 acc[4][2];
#pragma unroll
  for (int i = 0; i < 4; ++i)
#pragma unroll
    for (int j = 0; j < 2; ++j) acc[i][j] = (f32x4){0.f, 0.f, 0.f, 0.f};
  for (int kt = 0; kt < FF; kt += 32) {
    GLOAD_LDS16(A + (size_t)sr * FF + kt + sc,        &As[tid * 8]);
    GLOAD_LDS16(A + (size_t)(sr + 64) * FF + kt + sc, &As[2048 + tid * 8]);
    GLOAD_LDS16(B + (size_t)sr * FF + kt + sc,        &Bs[tid * 8]);
    __syncthreads();
    bf16x8 a[4], b[2];
#pragma unroll
    for (int i = 0; i < 4; ++i) a[i] = *reinterpret_cast<const bf16x8*>(&As[(wm + i * 16 + l15) * 32 + quad * 8]);
#pragma unroll
    for (int j = 0; j < 2; ++j) b[j] = *reinterpret_cast<const bf16x8*>(&Bs[(wn + j * 16 + l15) * 32 + quad * 8]);
#pragma unroll
    for (int i = 0; i < 4; ++i)
#pragma unroll
      for (int j = 0; j < 2; ++j)
        acc[i][j] = __builtin_amdgcn_mfma_f32_16x16x32_bf16(a[i], b[j], acc[i][j], 0, 0, 0);
    __syncthreads();
  }
#pragma unroll
  for (int i = 0; i < 4; ++i) {
#pragma unroll
    for (int reg = 0; reg < 4; ++reg) {
      int slot = m0 + wm + i * 16 + quad * 4 + reg;
      if (slot < tot) {
        int idx = e * 1024 + slot;
        int t = tok[idx];
        float scv = mscale[idx];
        float* outr = moebuf + (size_t)t * DM + n0 + wn;
#pragma unroll
        for (int j = 0; j < 2; ++j) outr[j * 16 + l15] = scv * acc[i][j][reg];
      }
    }
  }
}

extern "C" void kernel_launch(void* const* d_in, const int* in_sizes, int n_in,
                              void* d_out, int out_size, void* d_ws, size_t ws_size,
                              hipStream_t stream) {
  const float* x     = (const float*)d_in[0];
  const float* in_w  = (const float*)d_in[1];
  const float* in_b  = (const float*)d_in[2];
  const float* out_w = (const float*)d_in[3];
  const float* out_b = (const float*)d_in[4];
  const float* ln1g  = (const float*)d_in[5];
  const float* ln1b  = (const float*)d_in[6];
  const float* ln2g  = (const float*)d_in[7];
  const float* ln2b  = (const float*)d_in[8];
  const float* rw    = (const float*)d_in[9];
  const float* wi    = (const float*)d_in[10];
  const float* wo    = (const float*)d_in[11];
  const int*   capp  = (const int*)d_in[12];

  float* ws = (float*)d_ws;
  short* qkh  = (short*)ws;                      // [0, 6291456) floats: qk/vt split planes
  short* qkl  = (short*)(ws + 2097152);
  short* vth  = (short*)(ws + 4194304);
  short* vtl  = (short*)(ws + 5242880);
  short* Gb16 = (short*)ws;                      // aliases qkh (post-attn)
  short* wi_t = (short*)(ws + 2097152);          // aliases qkl/vt (post-attn)
  float* moebuf = ws + 6291456;                  // 2,097,152
  float* r1     = ws + 8388608;                  // 2,097,152
  float* h      = ws + 10485760;                 // 2,097,152
  float* probs  = ws + 12582912;                 // 32,768
  short* wo_t   = (short*)(ws + 12615680);       // 8,388,608 shorts
  float* opart  = ws + 16809984;                 // 2 x 2,097,152 fp32 (aliases mid16, pre-FFN)
  float* mlbuf  = ws + 16809984 + 4194304;       // 131,072 fp32
  short* mid16  = (short*)(ws + 16809984);       // FFN phase
  float* mscale = ws + 25198592;
  int* am    = (int*)(ws + 25206784);
  int* pos   = am + NTOK;
  int* cnt   = pos + NTOK;
  int* tok   = cnt + 32;
  short* sAh = (short*)(ws + 25231360);          // 4096x512 shorts
  short* sAl = sAh + 2097152;
  short* sBh = sAl + 2097152;                    // 1536x512 shorts
  short* sBl = sBh + 786432;
  short* sCh = sBl + 786432;                     // 512x512 shorts
  short* sCl = sCh + 262144;

  float* out   = (float*)d_out;
  float* rlog  = out + 2097152;
  float* emask = rlog + 32768;

  // 1. fused split of x, in_proj_w, out_proj_w
  split3_kernel<<<1536, 256, 0, stream>>>(x, sAh, sAl, in_w, sBh, sBl, out_w, sCh, sCl);
  // 2. qkv GEMM -> split planes
  gemm_split_qkv<<<dim3(24, 32), 256, 0, stream>>>(sAh, sAl, sBh, sBl, in_b, qkh, qkl, vth, vtl);
  // 3. split-S MFMA attention (Q in regs, 32 KB LDS)
  attn_mfma<<<dim3(16, 8, 8), 256, 0, stream>>>(qkh, qkl, vth, vtl, opart, mlbuf);
  // 4. combine partials -> split attn_o planes (reuses sAh/sAl; x-split dead)
  combine_attn<<<NTOK, 64, 0, stream>>>(opart, mlbuf, sAh, sAl);
  // 5. r1 = attn_o @ out_w^T + out_b + x  (BNF=1 -> 512 blocks)
  gemm_split<1><<<dim3(16, 32), 256, 0, stream>>>(sAh, sAl, sCh, sCl, out_b, x, r1, DM, DM);
  // 6. fused FFN weight transposes (overwrite qk/vt planes; attn done)
  transpose2_bf16<<<dim3(64, 16, 16), 256, 0, stream>>>(wi, wi_t, wo, wo_t);
  // 7. fused LN1 + router + softmax + argmax
  ln_router<<<NTOK, 64, 0, stream>>>(r1, ln1g, ln1b, rw, h, rlog, probs, am);
  // 8. capacity scan
  scan_kernel<<<32, 256, 0, stream>>>(am, probs, capp, emask, pos, cnt);
  // 9. gather kept tokens -> bf16 (offsets from cnt inline)
  gather_kernel<<<NTOK, 128, 0, stream>>>(h, am, pos, capp, cnt, probs, Gb16, tok, mscale);
  // 10-11. expert FFN
  ffn1_mfma<<<dim3(16, 8, 8), 256, 0, stream>>>(Gb16, wi_t, mid16, cnt);
  ffn2_mfma<<<dim3(8, 8, 8), 256, 0, stream>>>(mid16, wo_t, tok, mscale, cnt, moebuf);
  // 12. out = LN2(h + kept?moebuf:0)
  ln2_kernel<<<NTOK, 64, 0, stream>>>(h, moebuf, pos, capp, ln2g, ln2b, out);
}